// Round 1
// baseline (513.352 us; speedup 1.0000x reference)
//
#include <hip/hip_runtime.h>
#include <cstdint>
#include <cstddef>

using bfr8 = __attribute__((ext_vector_type(8))) short;   // 8 bf16 (4 VGPRs)
using sh4  = __attribute__((ext_vector_type(4))) short;
using fx4  = __attribute__((ext_vector_type(4))) float;

#define DI __device__ __forceinline__
#define MFMA16(a,b,c) __builtin_amdgcn_mfma_f32_16x16x32_bf16((a),(b),(c),0,0,0)

DI short f2bf(float f){
  unsigned u = __float_as_uint(f);
  return (short)((u + 0x7fffu + ((u >> 16) & 1u)) >> 16);
}
DI fx4 fzero(){ fx4 z; z[0]=0.f; z[1]=0.f; z[2]=0.f; z[3]=0.f; return z; }

// ---------------------------------------------------------------------------
// prep: dtype conversions, weight re-layout [co][tap][ci], BN folding,
//       x1 transpose [b][n][c], and the out1 = x2 copy.
// ---------------------------------------------------------------------------
__global__ void prep_kernel(
    const float* __restrict__ x1, const float* __restrict__ x2,
    const float* __restrict__ wsw, const float* __restrict__ bs,
    const float* __restrict__ sg, const float* __restrict__ sbeta,
    const float* __restrict__ smean, const float* __restrict__ svar,
    const float* __restrict__ wq1, const float* __restrict__ wq2,
    const float* __restrict__ v2w, const float* __restrict__ v2bias,
    const float* __restrict__ v2g, const float* __restrict__ v2beta,
    const float* __restrict__ v2mean, const float* __restrict__ v2var,
    short* __restrict__ x2bf, short* __restrict__ x1T,
    short* __restrict__ wsbf, short* __restrict__ wv2a, short* __restrict__ wv2b,
    short* __restrict__ wq1b, short* __restrict__ wq2b,
    float* __restrict__ consts, float* __restrict__ out1copy)
{
  const int gsz = gridDim.x * blockDim.x;
  const int gid = blockIdx.x * blockDim.x + threadIdx.x;

  // x2 -> bf16  AND  copy x2 -> out1 (output 1 is the unmodified input)
  for (int i = gid; i < 1605632; i += gsz){
    float4 v = ((const float4*)x2)[i];
    ((float4*)out1copy)[i] = v;
    sh4 o; o[0]=f2bf(v.x); o[1]=f2bf(v.y); o[2]=f2bf(v.z); o[3]=f2bf(v.w);
    ((sh4*)x2bf)[i] = o;
  }
  // x1 -> x1T [b][n][128] bf16
  for (int t = gid; t < 200704; t += gsz){
    int g = t & 15; int nn = t >> 4;
    int b = nn / 3136, n = nn - b*3136;
    bfr8 o;
    #pragma unroll
    for (int k = 0; k < 8; ++k)
      o[k] = f2bf(x1[(size_t)(b*128 + g*8 + k)*3136 + n]);
    *(bfr8*)&x1T[((size_t)(b*3136) + n)*128 + g*8] = o;
  }
  // conv_s weights: [co][ci][3][3] f32 -> [co][tap][ci] bf16
  for (int i = gid; i < 589824; i += gsz){
    int ci = i & 511; int tap = (i >> 9) % 9; int co = i / 4608;
    wsbf[i] = f2bf(wsw[(size_t)(co*512 + ci)*9 + tap]);
  }
  // v2 conv weights (both stages)
  for (int i = gid; i < 294912; i += gsz){
    int s = i / 147456; int r = i - s*147456;
    int ci = r & 127; int tap = (r >> 7) % 9; int co = r / 1152;
    float v = v2w[(size_t)((s*128 + co)*128 + ci)*9 + tap];
    (s ? wv2b : wv2a)[r] = f2bf(v);
  }
  // 1x1 q weights (already [co][ci] flat)
  for (int i = gid; i < 16384; i += gsz){
    wq1b[i] = f2bf(wq1[i]); wq2b[i] = f2bf(wq2[i]);
  }
  // folded BN constants: y = relu(conv*alpha + bc)
  for (int c = gid; c < 128; c += gsz){
    float a = sg[c] * rsqrtf(svar[c] + 1e-5f);
    consts[c]       = a;
    consts[128 + c] = (bs[c] - smean[c]) * a + sbeta[c];
    float a0 = v2g[c] * rsqrtf(v2var[c] + 1e-5f);
    consts[256 + c] = a0;
    consts[384 + c] = (v2bias[c] - v2mean[c]) * a0 + v2beta[c];
    float a1 = v2g[128+c] * rsqrtf(v2var[128+c] + 1e-5f);
    consts[512 + c] = a1;
    consts[640 + c] = (v2bias[128+c] - v2mean[128+c]) * a1 + v2beta[128+c];
  }
}

// ---------------------------------------------------------------------------
// conv3x3 (pad=1) + BN + ReLU, implicit GEMM with MFMA bf16.
// Block tile: 64 out-channels x 112 pixels (2 full image rows).
// Grid: b(4) * cog(2) * row-tiles(28) = 224 blocks, 4 waves each.
// ---------------------------------------------------------------------------
template<int CIN, bool TSTORE>
__global__ __launch_bounds__(256, 2) void conv3x3_kernel(
    const short* __restrict__ xin,   // [4][CIN][3136] bf16
    const short* __restrict__ wt,    // [128][9][CIN] bf16
    const float* __restrict__ alpha, const float* __restrict__ bconst,
    short* __restrict__ yout,        // [4][128][3136] bf16
    short* __restrict__ youtT)       // [4][3136][128] bf16 (optional)
{
  __shared__ short xs[4*58*40];      // input tile: 4 rows x 58 cols x 32ci(pad40)
  __shared__ short wsh[9*64*40];     // weights: 9 taps x 64 co x 32ci(pad40)

  const int tid = threadIdx.x;
  const int w = tid >> 6, lane = tid & 63, l15 = lane & 15, blk = lane >> 4;
  const int bid = blockIdx.x;
  const int rt = bid % 28, cog = (bid / 28) & 1, b = bid / 56;
  const int r0 = rt * 2;

  int pixoff[7];
  #pragma unroll
  for (int pf = 0; pf < 7; ++pf){
    int p = pf*16 + l15;
    int pr = (p >= 56) ? 1 : 0;
    int pc = p - pr*56;
    pixoff[pf] = (pr*58 + pc)*40 + 8*blk;
  }
  const int wlo = (w*16 + l15)*40 + 8*blk;

  fx4 acc[7];
  #pragma unroll
  for (int pf = 0; pf < 7; ++pf) acc[pf] = fzero();

  for (int cib = 0; cib < CIN/32; ++cib){
    __syncthreads();
    // stage input tile: chunks = r(4) x cigrp(4) x col(58) = 928
    #pragma unroll
    for (int it = 0; it < 4; ++it){
      int q = it*256 + tid;
      if (q < 928){
        int col = q % 58; int cg8 = (q/58) & 3; int r = q / 232;
        int grow = r0 - 1 + r;
        int gcol = col - 1;
        bfr8 v;
        if (grow >= 0 && grow < 56 && gcol >= 0 && gcol < 56){
          #pragma unroll
          for (int k = 0; k < 8; ++k)
            v[k] = xin[(size_t)(b*CIN + cib*32 + cg8*8 + k)*3136 + grow*56 + gcol];
        } else {
          #pragma unroll
          for (int k = 0; k < 8; ++k) v[k] = 0;
        }
        *(bfr8*)&xs[(r*58 + col)*40 + cg8*8] = v;
      }
    }
    // stage weights: chunks = 64co x 9tap x 4cigrp = 2304 = 9*256
    #pragma unroll
    for (int it = 0; it < 9; ++it){
      int q = it*256 + tid;
      int jj = q & 3; int tap = (q >> 2) % 9; int co = q / 36;
      bfr8 wv = *(const bfr8*)&wt[(size_t)((cog*64 + co)*9 + tap)*CIN + cib*32 + jj*8];
      *(bfr8*)&wsh[(tap*64 + co)*40 + jj*8] = wv;
    }
    __syncthreads();
    #pragma unroll
    for (int tap = 0; tap < 9; ++tap){
      bfr8 af = *(const bfr8*)&wsh[tap*64*40 + wlo];
      const int toff = ((tap/3)*58 + (tap%3))*40;
      #pragma unroll
      for (int pf = 0; pf < 7; ++pf){
        bfr8 bf = *(const bfr8*)&xs[pixoff[pf] + toff];
        acc[pf] = MFMA16(af, bf, acc[pf]);
      }
    }
  }
  // epilogue: BN + ReLU, store bf16 (and optional transposed copy)
  #pragma unroll
  for (int rr = 0; rr < 4; ++rr){
    int co = cog*64 + w*16 + 4*blk + rr;
    float al = alpha[co], bc = bconst[co];
    #pragma unroll
    for (int pf = 0; pf < 7; ++pf){
      float v = fmaxf(acc[pf][rr]*al + bc, 0.f);
      short sv = f2bf(v);
      int n = r0*56 + pf*16 + l15;
      yout[(size_t)(b*128 + co)*3136 + n] = sv;
      if (TSTORE) youtT[((size_t)(b*3136) + n)*128 + co] = sv;
    }
  }
}

// ---------------------------------------------------------------------------
// 1x1 conv: qt[b][n][co] = sum_ci wq[co][ci] * xT[b][n][ci]
// ---------------------------------------------------------------------------
__global__ __launch_bounds__(256, 4) void qproj_kernel(
    const short* __restrict__ xT, const short* __restrict__ wq,
    short* __restrict__ qt)
{
  const int tid = threadIdx.x, w = tid >> 6, lane = tid & 63;
  const int l15 = lane & 15, blk = lane >> 4;
  const int b = blockIdx.x / 49, n0 = (blockIdx.x % 49) * 64;
  const int nb = n0 + w*16;

  fx4 acc[8];
  #pragma unroll
  for (int cf = 0; cf < 8; ++cf) acc[cf] = fzero();

  #pragma unroll
  for (int ks = 0; ks < 4; ++ks){
    bfr8 af = *(const bfr8*)&xT[((size_t)(b*3136) + nb + l15)*128 + ks*32 + 8*blk];
    #pragma unroll
    for (int cf = 0; cf < 8; ++cf){
      bfr8 bf = *(const bfr8*)&wq[(size_t)(cf*16 + l15)*128 + ks*32 + 8*blk];
      acc[cf] = MFMA16(af, bf, acc[cf]);
    }
  }
  #pragma unroll
  for (int cf = 0; cf < 8; ++cf){
    #pragma unroll
    for (int rr = 0; rr < 4; ++rr){
      int n = nb + 4*blk + rr;
      qt[((size_t)(b*3136) + n)*128 + cf*16 + l15] = f2bf(acc[cf][rr]);
    }
  }
}

// ---------------------------------------------------------------------------
// pass 1: per-column (m) logsumexp over n of A[n,m] = q1[:,n].q2[:,m]
// Lm = max_n + log(sum_n exp(a - max))
// ---------------------------------------------------------------------------
__global__ __launch_bounds__(256, 2) void colstats_kernel(
    const short* __restrict__ q1t, const short* __restrict__ q2t,
    float* __restrict__ Lm)
{
  __shared__ float smax[4][64];
  __shared__ float ssum[4][64];
  const int tid = threadIdx.x, w = tid >> 6, lane = tid & 63;
  const int l15 = lane & 15, blk = lane >> 4;
  const int b = blockIdx.x / 49, m0 = (blockIdx.x % 49) * 64;

  bfr8 bfr[4][4];   // [mf][ks]
  #pragma unroll
  for (int mf = 0; mf < 4; ++mf)
    #pragma unroll
    for (int ks = 0; ks < 4; ++ks)
      bfr[mf][ks] = *(const bfr8*)&q2t[((size_t)(b*3136) + m0 + mf*16 + l15)*128 + ks*32 + 8*blk];

  float vmax[4], vsum[4];
  #pragma unroll
  for (int mf = 0; mf < 4; ++mf){ vmax[mf] = -1e30f; vsum[mf] = 0.f; }

  for (int nc = w; nc < 196; nc += 4){
    fx4 acc[4];
    #pragma unroll
    for (int mf = 0; mf < 4; ++mf) acc[mf] = fzero();
    #pragma unroll
    for (int ks = 0; ks < 4; ++ks){
      bfr8 af = *(const bfr8*)&q1t[((size_t)(b*3136) + nc*16 + l15)*128 + ks*32 + 8*blk];
      #pragma unroll
      for (int mf = 0; mf < 4; ++mf) acc[mf] = MFMA16(af, bfr[mf][ks], acc[mf]);
    }
    #pragma unroll
    for (int mf = 0; mf < 4; ++mf){
      float cm = fmaxf(fmaxf(acc[mf][0], acc[mf][1]), fmaxf(acc[mf][2], acc[mf][3]));
      cm = fmaxf(cm, __shfl_xor(cm, 16));
      cm = fmaxf(cm, __shfl_xor(cm, 32));
      float nm = fmaxf(vmax[mf], cm);
      float cs = __expf(acc[mf][0]-nm) + __expf(acc[mf][1]-nm)
               + __expf(acc[mf][2]-nm) + __expf(acc[mf][3]-nm);
      cs += __shfl_xor(cs, 16);
      cs += __shfl_xor(cs, 32);
      vsum[mf] = vsum[mf]*__expf(vmax[mf]-nm) + cs;
      vmax[mf] = nm;
    }
  }
  if (blk == 0){
    #pragma unroll
    for (int mf = 0; mf < 4; ++mf){
      smax[w][mf*16 + l15] = vmax[mf];
      ssum[w][mf*16 + l15] = vsum[mf];
    }
  }
  __syncthreads();
  if (tid < 64){
    float M = -1e30f;
    #pragma unroll
    for (int ww = 0; ww < 4; ++ww) M = fmaxf(M, smax[ww][tid]);
    float S = 0.f;
    #pragma unroll
    for (int ww = 0; ww < 4; ++ww) S += ssum[ww][tid]*__expf(smax[ww][tid]-M);
    Lm[b*3136 + m0 + tid] = M + __logf(S);
  }
}

// ---------------------------------------------------------------------------
// pass 2: recompute A tiles, P = exp(exp(a - Lm)), accumulate PV + rowsum
// online; out0[b][c][n] = PV/rowsum + x1
// ---------------------------------------------------------------------------
__global__ __launch_bounds__(256, 2) void attn_kernel(
    const short* __restrict__ q1t, const short* __restrict__ q2t,
    const short* __restrict__ x2v, const float* __restrict__ Lm,
    const float* __restrict__ x1, float* __restrict__ out0)
{
  __shared__ short plds[4][16][72];
  __shared__ float rl[4][16];
  const int tid = threadIdx.x, w = tid >> 6, lane = tid & 63;
  const int l15 = lane & 15, blk = lane >> 4;
  const int b = blockIdx.x / 49, n0 = (blockIdx.x % 49) * 64;
  const int nb = n0 + w*16;

  bfr8 qa[4];
  #pragma unroll
  for (int ks = 0; ks < 4; ++ks)
    qa[ks] = *(const bfr8*)&q1t[((size_t)(b*3136) + nb + l15)*128 + ks*32 + 8*blk];

  fx4 pacc[8];
  #pragma unroll
  for (int cf = 0; cf < 8; ++cf) pacc[cf] = fzero();
  float rsum[4] = {0.f, 0.f, 0.f, 0.f};

  for (int m0m = 0; m0m < 3136; m0m += 64){
    fx4 s4[4];
    #pragma unroll
    for (int mf = 0; mf < 4; ++mf) s4[mf] = fzero();
    #pragma unroll
    for (int ks = 0; ks < 4; ++ks){
      #pragma unroll
      for (int mf = 0; mf < 4; ++mf){
        bfr8 bq = *(const bfr8*)&q2t[((size_t)(b*3136) + m0m + mf*16 + l15)*128 + ks*32 + 8*blk];
        s4[mf] = MFMA16(qa[ks], bq, s4[mf]);
      }
    }
    #pragma unroll
    for (int mf = 0; mf < 4; ++mf){
      float Lv = Lm[b*3136 + m0m + mf*16 + l15];
      #pragma unroll
      for (int rr = 0; rr < 4; ++rr){
        float a1 = __expf(s4[mf][rr] - Lv);   // in (0,1]
        float p  = __expf(a1);                // in (1,e]
        rsum[rr] += p;
        plds[w][4*blk + rr][mf*16 + l15] = f2bf(p);
      }
    }
    #pragma unroll
    for (int ks2 = 0; ks2 < 2; ++ks2){
      bfr8 pb = *(const bfr8*)&plds[w][l15][ks2*32 + 8*blk];
      #pragma unroll
      for (int cf = 0; cf < 8; ++cf){
        bfr8 av = *(const bfr8*)&x2v[((size_t)(b*128) + cf*16 + l15)*3136 + m0m + ks2*32 + 8*blk];
        pacc[cf] = MFMA16(av, pb, pacc[cf]);
      }
    }
  }
  // reduce rowsums over the 16 column-lanes
  #pragma unroll
  for (int d = 1; d < 16; d <<= 1){
    #pragma unroll
    for (int rr = 0; rr < 4; ++rr) rsum[rr] += __shfl_xor(rsum[rr], d);
  }
  if (l15 == 0){
    #pragma unroll
    for (int rr = 0; rr < 4; ++rr) rl[w][4*blk + rr] = rsum[rr];
  }
  __syncthreads();
  float rinv = 1.0f / rl[w][l15];
  #pragma unroll
  for (int cf = 0; cf < 8; ++cf){
    #pragma unroll
    for (int rr = 0; rr < 4; ++rr){
      int c = cf*16 + 4*blk + rr;
      int n = nb + l15;
      size_t idx = (size_t)(b*128 + c)*3136 + n;
      out0[idx] = pacc[cf][rr]*rinv + x1[idx];
    }
  }
}

// ---------------------------------------------------------------------------
extern "C" void kernel_launch(void* const* d_in, const int* in_sizes, int n_in,
                              void* d_out, int out_size, void* d_ws, size_t ws_size,
                              hipStream_t stream)
{
  (void)in_sizes; (void)n_in; (void)out_size; (void)ws_size;
  const float* x1     = (const float*)d_in[0];
  const float* x2     = (const float*)d_in[1];
  const float* wsw    = (const float*)d_in[2];
  const float* bs     = (const float*)d_in[3];
  const float* sg     = (const float*)d_in[4];
  const float* sbeta  = (const float*)d_in[5];
  const float* smean  = (const float*)d_in[6];
  const float* svar   = (const float*)d_in[7];
  const float* wq1    = (const float*)d_in[8];
  const float* wq2    = (const float*)d_in[9];
  // d_in[10..15]: v1w/v1b/v1g/v1beta/v1mean/v1var -> dead code, unused
  const float* v2w    = (const float*)d_in[16];
  const float* v2bias = (const float*)d_in[17];
  const float* v2g    = (const float*)d_in[18];
  const float* v2beta = (const float*)d_in[19];
  const float* v2mean = (const float*)d_in[20];
  const float* v2var  = (const float*)d_in[21];

  char* ws = (char*)d_ws;
  size_t off = 0;
  auto alloc = [&](size_t bytes)->char*{
    char* p = ws + off;
    off = (off + bytes + 255) & ~(size_t)255;
    return p;
  };
  short* x2bf   = (short*)alloc(6422528u*2);
  short* x1T    = (short*)alloc(1605632u*2);
  short* wsbf   = (short*)alloc(589824u*2);
  short* wv2a   = (short*)alloc(147456u*2);
  short* wv2b   = (short*)alloc(147456u*2);
  short* wq1b   = (short*)alloc(16384u*2);
  short* wq2b   = (short*)alloc(16384u*2);
  float* consts = (float*)alloc(768u*4);
  short* x2s    = (short*)alloc(1605632u*2);
  short* x2sT   = (short*)alloc(1605632u*2);
  short* q1t    = (short*)alloc(1605632u*2);
  short* q2t    = (short*)alloc(1605632u*2);
  short* v2t    = (short*)alloc(1605632u*2);
  short* x2v    = (short*)alloc(1605632u*2);
  float* Lm     = (float*)alloc(12544u*4);

  float* out0 = (float*)d_out;
  float* out1 = out0 + 1605632;

  prep_kernel<<<2048, 256, 0, stream>>>(x1, x2, wsw, bs, sg, sbeta, smean, svar,
      wq1, wq2, v2w, v2bias, v2g, v2beta, v2mean, v2var,
      x2bf, x1T, wsbf, wv2a, wv2b, wq1b, wq2b, consts, out1);

  conv3x3_kernel<512, true ><<<224, 256, 0, stream>>>(x2bf, wsbf, consts,       consts + 128, x2s, x2sT);
  qproj_kernel<<<196, 256, 0, stream>>>(x1T,  wq1b, q1t);
  qproj_kernel<<<196, 256, 0, stream>>>(x2sT, wq2b, q2t);
  conv3x3_kernel<128, false><<<224, 256, 0, stream>>>(x2s, wv2a, consts + 256, consts + 384, v2t, nullptr);
  conv3x3_kernel<128, false><<<224, 256, 0, stream>>>(v2t, wv2b, consts + 512, consts + 640, x2v, nullptr);
  colstats_kernel<<<196, 256, 0, stream>>>(q1t, q2t, Lm);
  attn_kernel<<<196, 256, 0, stream>>>(q1t, q2t, x2v, Lm, x1, out0);
}

// Round 2
// 391.082 us; speedup vs baseline: 1.3126x; 1.3126x over previous
//
#include <hip/hip_runtime.h>
#include <cstdint>
#include <cstddef>

using bfr8 = __attribute__((ext_vector_type(8))) short;   // 8 bf16 (4 VGPRs)
using sh4  = __attribute__((ext_vector_type(4))) short;
using fx4  = __attribute__((ext_vector_type(4))) float;

#define DI __device__ __forceinline__
#define MFMA16(a,b,c) __builtin_amdgcn_mfma_f32_16x16x32_bf16((a),(b),(c),0,0,0)

DI short f2bf(float f){
  unsigned u = __float_as_uint(f);
  return (short)((u + 0x7fffu + ((u >> 16) & 1u)) >> 16);
}
DI fx4 fzero(){ fx4 z; z[0]=0.f; z[1]=0.f; z[2]=0.f; z[3]=0.f; return z; }

// ---------------------------------------------------------------------------
// prep: dtype conversions, weight re-layout [co][tap][ci], BN folding,
//       x1 transpose [b][n][c], and the out1 = x2 copy.
// ---------------------------------------------------------------------------
__global__ void prep_kernel(
    const float* __restrict__ x1, const float* __restrict__ x2,
    const float* __restrict__ wsw, const float* __restrict__ bs,
    const float* __restrict__ sg, const float* __restrict__ sbeta,
    const float* __restrict__ smean, const float* __restrict__ svar,
    const float* __restrict__ wq1, const float* __restrict__ wq2,
    const float* __restrict__ v2w, const float* __restrict__ v2bias,
    const float* __restrict__ v2g, const float* __restrict__ v2beta,
    const float* __restrict__ v2mean, const float* __restrict__ v2var,
    short* __restrict__ x2bf, short* __restrict__ x1T,
    short* __restrict__ wsbf, short* __restrict__ wv2a, short* __restrict__ wv2b,
    short* __restrict__ wq1b, short* __restrict__ wq2b,
    float* __restrict__ consts, float* __restrict__ out1copy)
{
  const int gsz = gridDim.x * blockDim.x;
  const int gid = blockIdx.x * blockDim.x + threadIdx.x;

  // x2 -> bf16  AND  copy x2 -> out1 (output 1 is the unmodified input)
  for (int i = gid; i < 1605632; i += gsz){
    float4 v = ((const float4*)x2)[i];
    ((float4*)out1copy)[i] = v;
    sh4 o; o[0]=f2bf(v.x); o[1]=f2bf(v.y); o[2]=f2bf(v.z); o[3]=f2bf(v.w);
    ((sh4*)x2bf)[i] = o;
  }
  // x1 -> x1T [b][n][128] bf16
  for (int t = gid; t < 200704; t += gsz){
    int g = t & 15; int nn = t >> 4;
    int b = nn / 3136, n = nn - b*3136;
    bfr8 o;
    #pragma unroll
    for (int k = 0; k < 8; ++k)
      o[k] = f2bf(x1[(size_t)(b*128 + g*8 + k)*3136 + n]);
    *(bfr8*)&x1T[((size_t)(b*3136) + n)*128 + g*8] = o;
  }
  // conv_s weights: [co][ci][3][3] f32 -> [co][tap][ci] bf16
  for (int i = gid; i < 589824; i += gsz){
    int ci = i & 511; int tap = (i >> 9) % 9; int co = i / 4608;
    wsbf[i] = f2bf(wsw[(size_t)(co*512 + ci)*9 + tap]);
  }
  // v2 conv weights (both stages)
  for (int i = gid; i < 294912; i += gsz){
    int s = i / 147456; int r = i - s*147456;
    int ci = r & 127; int tap = (r >> 7) % 9; int co = r / 1152;
    float v = v2w[(size_t)((s*128 + co)*128 + ci)*9 + tap];
    (s ? wv2b : wv2a)[r] = f2bf(v);
  }
  // 1x1 q weights (already [co][ci] flat)
  for (int i = gid; i < 16384; i += gsz){
    wq1b[i] = f2bf(wq1[i]); wq2b[i] = f2bf(wq2[i]);
  }
  // folded BN constants: y = relu(conv*alpha + bc)
  for (int c = gid; c < 128; c += gsz){
    float a = sg[c] * rsqrtf(svar[c] + 1e-5f);
    consts[c]       = a;
    consts[128 + c] = (bs[c] - smean[c]) * a + sbeta[c];
    float a0 = v2g[c] * rsqrtf(v2var[c] + 1e-5f);
    consts[256 + c] = a0;
    consts[384 + c] = (v2bias[c] - v2mean[c]) * a0 + v2beta[c];
    float a1 = v2g[128+c] * rsqrtf(v2var[128+c] + 1e-5f);
    consts[512 + c] = a1;
    consts[640 + c] = (v2bias[128+c] - v2mean[128+c]) * a1 + v2beta[128+c];
  }
}

// ---------------------------------------------------------------------------
// conv3x3 (pad=1) + BN + ReLU, implicit GEMM with MFMA bf16.
// Block tile: 64 out-channels x 112 pixels (2 full image rows).
// Grid: b(4) * cog(2) * row-tiles(28) = 224 blocks, 4 waves each.
// ---------------------------------------------------------------------------
template<int CIN, bool TSTORE>
__global__ __launch_bounds__(256, 2) void conv3x3_kernel(
    const short* __restrict__ xin,   // [4][CIN][3136] bf16
    const short* __restrict__ wt,    // [128][9][CIN] bf16
    const float* __restrict__ alpha, const float* __restrict__ bconst,
    short* __restrict__ yout,        // [4][128][3136] bf16
    short* __restrict__ youtT)       // [4][3136][128] bf16 (optional)
{
  __shared__ short xs[4*58*40];      // input tile: 4 rows x 58 cols x 32ci(pad40)
  __shared__ short wsh[9*64*40];     // weights: 9 taps x 64 co x 32ci(pad40)

  const int tid = threadIdx.x;
  const int w = tid >> 6, lane = tid & 63, l15 = lane & 15, blk = lane >> 4;
  const int bid = blockIdx.x;
  const int rt = bid % 28, cog = (bid / 28) & 1, b = bid / 56;
  const int r0 = rt * 2;

  int pixoff[7];
  #pragma unroll
  for (int pf = 0; pf < 7; ++pf){
    int p = pf*16 + l15;
    int pr = (p >= 56) ? 1 : 0;
    int pc = p - pr*56;
    pixoff[pf] = (pr*58 + pc)*40 + 8*blk;
  }
  const int wlo = (w*16 + l15)*40 + 8*blk;

  fx4 acc[7];
  #pragma unroll
  for (int pf = 0; pf < 7; ++pf) acc[pf] = fzero();

  for (int cib = 0; cib < CIN/32; ++cib){
    __syncthreads();
    // stage input tile: chunks = r(4) x cigrp(4) x col(58) = 928
    #pragma unroll
    for (int it = 0; it < 4; ++it){
      int q = it*256 + tid;
      if (q < 928){
        int col = q % 58; int cg8 = (q/58) & 3; int r = q / 232;
        int grow = r0 - 1 + r;
        int gcol = col - 1;
        bfr8 v;
        if (grow >= 0 && grow < 56 && gcol >= 0 && gcol < 56){
          #pragma unroll
          for (int k = 0; k < 8; ++k)
            v[k] = xin[(size_t)(b*CIN + cib*32 + cg8*8 + k)*3136 + grow*56 + gcol];
        } else {
          #pragma unroll
          for (int k = 0; k < 8; ++k) v[k] = 0;
        }
        *(bfr8*)&xs[(r*58 + col)*40 + cg8*8] = v;
      }
    }
    // stage weights: chunks = 64co x 9tap x 4cigrp = 2304 = 9*256
    #pragma unroll
    for (int it = 0; it < 9; ++it){
      int q = it*256 + tid;
      int jj = q & 3; int tap = (q >> 2) % 9; int co = q / 36;
      bfr8 wv = *(const bfr8*)&wt[(size_t)((cog*64 + co)*9 + tap)*CIN + cib*32 + jj*8];
      *(bfr8*)&wsh[(tap*64 + co)*40 + jj*8] = wv;
    }
    __syncthreads();
    #pragma unroll
    for (int tap = 0; tap < 9; ++tap){
      bfr8 af = *(const bfr8*)&wsh[tap*64*40 + wlo];
      const int toff = ((tap/3)*58 + (tap%3))*40;
      #pragma unroll
      for (int pf = 0; pf < 7; ++pf){
        bfr8 bf = *(const bfr8*)&xs[pixoff[pf] + toff];
        acc[pf] = MFMA16(af, bf, acc[pf]);
      }
    }
  }
  // epilogue: BN + ReLU, store bf16 (and optional transposed copy)
  #pragma unroll
  for (int rr = 0; rr < 4; ++rr){
    int co = cog*64 + w*16 + 4*blk + rr;
    float al = alpha[co], bc = bconst[co];
    #pragma unroll
    for (int pf = 0; pf < 7; ++pf){
      float v = fmaxf(acc[pf][rr]*al + bc, 0.f);
      short sv = f2bf(v);
      int n = r0*56 + pf*16 + l15;
      yout[(size_t)(b*128 + co)*3136 + n] = sv;
      if (TSTORE) youtT[((size_t)(b*3136) + n)*128 + co] = sv;
    }
  }
}

// ---------------------------------------------------------------------------
// 1x1 conv: qt[b][n][co] = sum_ci wq[co][ci] * xT[b][n][ci]
// Block: 16 n-rows; 4 waves split the 8 output-channel fragments (2 each).
// ---------------------------------------------------------------------------
__global__ __launch_bounds__(256, 4) void qproj_kernel(
    const short* __restrict__ xT, const short* __restrict__ wq,
    short* __restrict__ qt)
{
  const int tid = threadIdx.x, w = tid >> 6, lane = tid & 63;
  const int l15 = lane & 15, blk = lane >> 4;
  const int b = blockIdx.x / 196, n0 = (blockIdx.x % 196) * 16;

  fx4 acc[2];
  acc[0] = fzero(); acc[1] = fzero();

  #pragma unroll
  for (int ks = 0; ks < 4; ++ks){
    bfr8 af = *(const bfr8*)&xT[((size_t)(b*3136) + n0 + l15)*128 + ks*32 + 8*blk];
    #pragma unroll
    for (int i = 0; i < 2; ++i){
      bfr8 bf = *(const bfr8*)&wq[(size_t)((w*2 + i)*16 + l15)*128 + ks*32 + 8*blk];
      acc[i] = MFMA16(af, bf, acc[i]);
    }
  }
  #pragma unroll
  for (int i = 0; i < 2; ++i){
    #pragma unroll
    for (int rr = 0; rr < 4; ++rr){
      int n = n0 + 4*blk + rr;
      qt[((size_t)(b*3136) + n)*128 + (w*2 + i)*16 + l15] = f2bf(acc[i][rr]);
    }
  }
}

// ---------------------------------------------------------------------------
// pass 1: per-column (m) logsumexp over n of A[n,m] = q1[:,n].q2[:,m]
// Block: 16 m-cols; 4 waves split the 196 n-fragments (49 each, strided).
// Per-lane online (max,sum); blk-reduce via shfl at the end; LDS wave merge.
// ---------------------------------------------------------------------------
__global__ __launch_bounds__(256, 2) void colstats_kernel(
    const short* __restrict__ q1t, const short* __restrict__ q2t,
    float* __restrict__ Lm)
{
  __shared__ float smax[4][16];
  __shared__ float ssum[4][16];
  const int tid = threadIdx.x, w = tid >> 6, lane = tid & 63;
  const int l15 = lane & 15, blk = lane >> 4;
  const int b = blockIdx.x / 196, m0 = (blockIdx.x % 196) * 16;

  bfr8 bfr[4];
  #pragma unroll
  for (int ks = 0; ks < 4; ++ks)
    bfr[ks] = *(const bfr8*)&q2t[((size_t)(b*3136) + m0 + l15)*128 + ks*32 + 8*blk];

  float vmax = -1e30f, vsum = 0.f;

  for (int nc = w; nc < 196; nc += 4){
    fx4 acc = fzero();
    #pragma unroll
    for (int ks = 0; ks < 4; ++ks){
      bfr8 af = *(const bfr8*)&q1t[((size_t)(b*3136) + nc*16 + l15)*128 + ks*32 + 8*blk];
      acc = MFMA16(af, bfr[ks], acc);
    }
    float cm = fmaxf(fmaxf(acc[0], acc[1]), fmaxf(acc[2], acc[3]));
    float nm = fmaxf(vmax, cm);
    float cs = __expf(acc[0]-nm) + __expf(acc[1]-nm)
             + __expf(acc[2]-nm) + __expf(acc[3]-nm);
    vsum = vsum*__expf(vmax-nm) + cs;
    vmax = nm;
  }
  // merge partials across the 4 blk groups (lanes sharing l15)
  #pragma unroll
  for (int d = 16; d < 64; d <<= 1){
    float om = __shfl_xor(vmax, d);
    float os = __shfl_xor(vsum, d);
    float M = fmaxf(vmax, om);
    vsum = vsum*__expf(vmax - M) + os*__expf(om - M);
    vmax = M;
  }
  if (lane < 16){ smax[w][lane] = vmax; ssum[w][lane] = vsum; }
  __syncthreads();
  if (tid < 16){
    float M = fmaxf(fmaxf(smax[0][tid], smax[1][tid]), fmaxf(smax[2][tid], smax[3][tid]));
    float S = ssum[0][tid]*__expf(smax[0][tid]-M) + ssum[1][tid]*__expf(smax[1][tid]-M)
            + ssum[2][tid]*__expf(smax[2][tid]-M) + ssum[3][tid]*__expf(smax[3][tid]-M);
    Lm[b*3136 + m0 + tid] = M + __logf(S);
  }
}

// ---------------------------------------------------------------------------
// pass 2: recompute A tiles, P = exp(exp(a - Lm)), accumulate PV + rowsum.
// Block: 16 n-rows; 4 waves split the 49 m-steps (strided); cross-wave
// combine of PV partials + rowsums via LDS at the end.
// out0[b][c][n] = PV/rowsum + x1
// ---------------------------------------------------------------------------
__global__ __launch_bounds__(256, 2) void attn_kernel(
    const short* __restrict__ q1t, const short* __restrict__ q2t,
    const short* __restrict__ x2v, const float* __restrict__ Lm,
    const float* __restrict__ x1, float* __restrict__ out0)
{
  __shared__ float part[8][4][4][64];   // [cf][rr][w][lane] 32 KB
  __shared__ short plds[4][16][72];     // per-wave P transpose tile
  __shared__ float rl[4][16];           // per-wave rowsum partials
  const int tid = threadIdx.x, w = tid >> 6, lane = tid & 63;
  const int l15 = lane & 15, blk = lane >> 4;
  const int b = blockIdx.x / 196, n0 = (blockIdx.x % 196) * 16;

  bfr8 qa[4];
  #pragma unroll
  for (int ks = 0; ks < 4; ++ks)
    qa[ks] = *(const bfr8*)&q1t[((size_t)(b*3136) + n0 + l15)*128 + ks*32 + 8*blk];

  fx4 pacc[8];
  #pragma unroll
  for (int cf = 0; cf < 8; ++cf) pacc[cf] = fzero();
  float rsum[4] = {0.f, 0.f, 0.f, 0.f};

  for (int s = w; s < 49; s += 4){
    const int m0m = s*64;
    fx4 s4[4];
    #pragma unroll
    for (int mf = 0; mf < 4; ++mf) s4[mf] = fzero();
    #pragma unroll
    for (int ks = 0; ks < 4; ++ks){
      #pragma unroll
      for (int mf = 0; mf < 4; ++mf){
        bfr8 bq = *(const bfr8*)&q2t[((size_t)(b*3136) + m0m + mf*16 + l15)*128 + ks*32 + 8*blk];
        s4[mf] = MFMA16(qa[ks], bq, s4[mf]);
      }
    }
    #pragma unroll
    for (int mf = 0; mf < 4; ++mf){
      float Lv = Lm[b*3136 + m0m + mf*16 + l15];
      #pragma unroll
      for (int rr = 0; rr < 4; ++rr){
        float a1 = __expf(s4[mf][rr] - Lv);   // in (0,1]
        float p  = __expf(a1);                // in (1,e]
        rsum[rr] += p;
        plds[w][4*blk + rr][mf*16 + l15] = f2bf(p);
      }
    }
    #pragma unroll
    for (int ks2 = 0; ks2 < 2; ++ks2){
      bfr8 pb = *(const bfr8*)&plds[w][l15][ks2*32 + 8*blk];
      #pragma unroll
      for (int cf = 0; cf < 8; ++cf){
        bfr8 av = *(const bfr8*)&x2v[((size_t)(b*128) + cf*16 + l15)*3136 + m0m + ks2*32 + 8*blk];
        pacc[cf] = MFMA16(av, pb, pacc[cf]);
      }
    }
  }
  // rowsum: reduce over the 16 m-lanes within each blk group
  #pragma unroll
  for (int d = 1; d < 16; d <<= 1){
    #pragma unroll
    for (int rr = 0; rr < 4; ++rr) rsum[rr] += __shfl_xor(rsum[rr], d);
  }
  if (l15 == 0){
    #pragma unroll
    for (int rr = 0; rr < 4; ++rr) rl[w][4*blk + rr] = rsum[rr];
  }
  // PV partials to LDS (conflict-free scalar layout)
  #pragma unroll
  for (int cf = 0; cf < 8; ++cf)
    #pragma unroll
    for (int rr = 0; rr < 4; ++rr)
      part[cf][rr][w][lane] = pacc[cf][rr];
  __syncthreads();

  // combine: wave w handles cf = 2w, 2w+1
  float rtot = rl[0][l15] + rl[1][l15] + rl[2][l15] + rl[3][l15];
  float rinv = 1.0f / rtot;
  const int n = n0 + l15;
  #pragma unroll
  for (int i = 0; i < 2; ++i){
    int cf = 2*w + i;
    #pragma unroll
    for (int rr = 0; rr < 4; ++rr){
      float v = part[cf][rr][0][lane] + part[cf][rr][1][lane]
              + part[cf][rr][2][lane] + part[cf][rr][3][lane];
      int c = cf*16 + 4*blk + rr;
      size_t idx = (size_t)(b*128 + c)*3136 + n;
      out0[idx] = v*rinv + x1[idx];
    }
  }
}

// ---------------------------------------------------------------------------
extern "C" void kernel_launch(void* const* d_in, const int* in_sizes, int n_in,
                              void* d_out, int out_size, void* d_ws, size_t ws_size,
                              hipStream_t stream)
{
  (void)in_sizes; (void)n_in; (void)out_size; (void)ws_size;
  const float* x1     = (const float*)d_in[0];
  const float* x2     = (const float*)d_in[1];
  const float* wsw    = (const float*)d_in[2];
  const float* bs     = (const float*)d_in[3];
  const float* sg     = (const float*)d_in[4];
  const float* sbeta  = (const float*)d_in[5];
  const float* smean  = (const float*)d_in[6];
  const float* svar   = (const float*)d_in[7];
  const float* wq1    = (const float*)d_in[8];
  const float* wq2    = (const float*)d_in[9];
  // d_in[10..15]: v1w/v1b/v1g/v1beta/v1mean/v1var -> dead code, unused
  const float* v2w    = (const float*)d_in[16];
  const float* v2bias = (const float*)d_in[17];
  const float* v2g    = (const float*)d_in[18];
  const float* v2beta = (const float*)d_in[19];
  const float* v2mean = (const float*)d_in[20];
  const float* v2var  = (const float*)d_in[21];

  char* ws = (char*)d_ws;
  size_t off = 0;
  auto alloc = [&](size_t bytes)->char*{
    char* p = ws + off;
    off = (off + bytes + 255) & ~(size_t)255;
    return p;
  };
  short* x2bf   = (short*)alloc(6422528u*2);
  short* x1T    = (short*)alloc(1605632u*2);
  short* wsbf   = (short*)alloc(589824u*2);
  short* wv2a   = (short*)alloc(147456u*2);
  short* wv2b   = (short*)alloc(147456u*2);
  short* wq1b   = (short*)alloc(16384u*2);
  short* wq2b   = (short*)alloc(16384u*2);
  float* consts = (float*)alloc(768u*4);
  short* x2s    = (short*)alloc(1605632u*2);
  short* x2sT   = (short*)alloc(1605632u*2);
  short* q1t    = (short*)alloc(1605632u*2);
  short* q2t    = (short*)alloc(1605632u*2);
  short* v2t    = (short*)alloc(1605632u*2);
  short* x2v    = (short*)alloc(1605632u*2);
  float* Lm     = (float*)alloc(12544u*4);

  float* out0 = (float*)d_out;
  float* out1 = out0 + 1605632;

  prep_kernel<<<2048, 256, 0, stream>>>(x1, x2, wsw, bs, sg, sbeta, smean, svar,
      wq1, wq2, v2w, v2bias, v2g, v2beta, v2mean, v2var,
      x2bf, x1T, wsbf, wv2a, wv2b, wq1b, wq2b, consts, out1);

  conv3x3_kernel<512, true ><<<224, 256, 0, stream>>>(x2bf, wsbf, consts,       consts + 128, x2s, x2sT);
  qproj_kernel<<<784, 256, 0, stream>>>(x1T,  wq1b, q1t);
  qproj_kernel<<<784, 256, 0, stream>>>(x2sT, wq2b, q2t);
  conv3x3_kernel<128, false><<<224, 256, 0, stream>>>(x2s, wv2a, consts + 256, consts + 384, v2t, nullptr);
  conv3x3_kernel<128, false><<<224, 256, 0, stream>>>(v2t, wv2b, consts + 512, consts + 640, x2v, nullptr);
  colstats_kernel<<<784, 256, 0, stream>>>(q1t, q2t, Lm);
  attn_kernel<<<784, 256, 0, stream>>>(q1t, q2t, x2v, Lm, x1, out0);
}

// Round 3
// 303.387 us; speedup vs baseline: 1.6921x; 1.2891x over previous
//
#include <hip/hip_runtime.h>
#include <cstdint>
#include <cstddef>

using bfr8 = __attribute__((ext_vector_type(8))) short;   // 8 bf16 (4 VGPRs)
using sh4  = __attribute__((ext_vector_type(4))) short;
using fx4  = __attribute__((ext_vector_type(4))) float;

#define DI __device__ __forceinline__
#define MFMA16(a,b,c) __builtin_amdgcn_mfma_f32_16x16x32_bf16((a),(b),(c),0,0,0)

DI short f2bf(float f){
  unsigned u = __float_as_uint(f);
  return (short)((u + 0x7fffu + ((u >> 16) & 1u)) >> 16);
}
DI float bf2f(short s){
  return __uint_as_float(((unsigned)(unsigned short)s) << 16);
}
DI fx4 fzero(){ fx4 z; z[0]=0.f; z[1]=0.f; z[2]=0.f; z[3]=0.f; return z; }

// ---------------------------------------------------------------------------
// prep: dtype conversions, weight re-layout [co][tap][ci], BN folding,
//       x1 transpose [b][n][c], and the out1 = x2 copy.
// ---------------------------------------------------------------------------
__global__ void prep_kernel(
    const float* __restrict__ x1, const float* __restrict__ x2,
    const float* __restrict__ wsw, const float* __restrict__ bs,
    const float* __restrict__ sg, const float* __restrict__ sbeta,
    const float* __restrict__ smean, const float* __restrict__ svar,
    const float* __restrict__ wq1, const float* __restrict__ wq2,
    const float* __restrict__ v2w, const float* __restrict__ v2bias,
    const float* __restrict__ v2g, const float* __restrict__ v2beta,
    const float* __restrict__ v2mean, const float* __restrict__ v2var,
    short* __restrict__ x2bf, short* __restrict__ x1T,
    short* __restrict__ wsbf, short* __restrict__ wv2a, short* __restrict__ wv2b,
    short* __restrict__ wq1b, short* __restrict__ wq2b,
    float* __restrict__ consts, float* __restrict__ out1copy)
{
  const int gsz = gridDim.x * blockDim.x;
  const int gid = blockIdx.x * blockDim.x + threadIdx.x;

  for (int i = gid; i < 1605632; i += gsz){
    float4 v = ((const float4*)x2)[i];
    ((float4*)out1copy)[i] = v;
    sh4 o; o[0]=f2bf(v.x); o[1]=f2bf(v.y); o[2]=f2bf(v.z); o[3]=f2bf(v.w);
    ((sh4*)x2bf)[i] = o;
  }
  for (int t = gid; t < 200704; t += gsz){
    int g = t & 15; int nn = t >> 4;
    int b = nn / 3136, n = nn - b*3136;
    bfr8 o;
    #pragma unroll
    for (int k = 0; k < 8; ++k)
      o[k] = f2bf(x1[(size_t)(b*128 + g*8 + k)*3136 + n]);
    *(bfr8*)&x1T[((size_t)(b*3136) + n)*128 + g*8] = o;
  }
  for (int i = gid; i < 589824; i += gsz){
    int ci = i & 511; int tap = (i >> 9) % 9; int co = i / 4608;
    wsbf[i] = f2bf(wsw[(size_t)(co*512 + ci)*9 + tap]);
  }
  for (int i = gid; i < 294912; i += gsz){
    int s = i / 147456; int r = i - s*147456;
    int ci = r & 127; int tap = (r >> 7) % 9; int co = r / 1152;
    float v = v2w[(size_t)((s*128 + co)*128 + ci)*9 + tap];
    (s ? wv2b : wv2a)[r] = f2bf(v);
  }
  for (int i = gid; i < 16384; i += gsz){
    wq1b[i] = f2bf(wq1[i]); wq2b[i] = f2bf(wq2[i]);
  }
  for (int c = gid; c < 128; c += gsz){
    float a = sg[c] * rsqrtf(svar[c] + 1e-5f);
    consts[c]       = a;
    consts[128 + c] = (bs[c] - smean[c]) * a + sbeta[c];
    float a0 = v2g[c] * rsqrtf(v2var[c] + 1e-5f);
    consts[256 + c] = a0;
    consts[384 + c] = (v2bias[c] - v2mean[c]) * a0 + v2beta[c];
    float a1 = v2g[128+c] * rsqrtf(v2var[128+c] + 1e-5f);
    consts[512 + c] = a1;
    consts[640 + c] = (v2bias[128+c] - v2mean[128+c]) * a1 + v2beta[128+c];
  }
}

// ---------------------------------------------------------------------------
// conv3x3 (pad=1) + BN + ReLU, implicit GEMM with MFMA bf16.
// ---------------------------------------------------------------------------
template<int CIN, bool TSTORE>
__global__ __launch_bounds__(256, 2) void conv3x3_kernel(
    const short* __restrict__ xin,   // [4][CIN][3136] bf16
    const short* __restrict__ wt,    // [128][9][CIN] bf16
    const float* __restrict__ alpha, const float* __restrict__ bconst,
    short* __restrict__ yout,        // [4][128][3136] bf16
    short* __restrict__ youtT)       // [4][3136][128] bf16 (optional)
{
  __shared__ short xs[4*58*40];
  __shared__ short wsh[9*64*40];

  const int tid = threadIdx.x;
  const int w = tid >> 6, lane = tid & 63, l15 = lane & 15, blk = lane >> 4;
  const int bid = blockIdx.x;
  const int rt = bid % 28, cog = (bid / 28) & 1, b = bid / 56;
  const int r0 = rt * 2;

  int pixoff[7];
  #pragma unroll
  for (int pf = 0; pf < 7; ++pf){
    int p = pf*16 + l15;
    int pr = (p >= 56) ? 1 : 0;
    int pc = p - pr*56;
    pixoff[pf] = (pr*58 + pc)*40 + 8*blk;
  }
  const int wlo = (w*16 + l15)*40 + 8*blk;

  fx4 acc[7];
  #pragma unroll
  for (int pf = 0; pf < 7; ++pf) acc[pf] = fzero();

  for (int cib = 0; cib < CIN/32; ++cib){
    __syncthreads();
    #pragma unroll
    for (int it = 0; it < 4; ++it){
      int q = it*256 + tid;
      if (q < 928){
        int col = q % 58; int cg8 = (q/58) & 3; int r = q / 232;
        int grow = r0 - 1 + r;
        int gcol = col - 1;
        bfr8 v;
        if (grow >= 0 && grow < 56 && gcol >= 0 && gcol < 56){
          #pragma unroll
          for (int k = 0; k < 8; ++k)
            v[k] = xin[(size_t)(b*CIN + cib*32 + cg8*8 + k)*3136 + grow*56 + gcol];
        } else {
          #pragma unroll
          for (int k = 0; k < 8; ++k) v[k] = 0;
        }
        *(bfr8*)&xs[(r*58 + col)*40 + cg8*8] = v;
      }
    }
    #pragma unroll
    for (int it = 0; it < 9; ++it){
      int q = it*256 + tid;
      int jj = q & 3; int tap = (q >> 2) % 9; int co = q / 36;
      bfr8 wv = *(const bfr8*)&wt[(size_t)((cog*64 + co)*9 + tap)*CIN + cib*32 + jj*8];
      *(bfr8*)&wsh[(tap*64 + co)*40 + jj*8] = wv;
    }
    __syncthreads();
    #pragma unroll
    for (int tap = 0; tap < 9; ++tap){
      bfr8 af = *(const bfr8*)&wsh[tap*64*40 + wlo];
      const int toff = ((tap/3)*58 + (tap%3))*40;
      #pragma unroll
      for (int pf = 0; pf < 7; ++pf){
        bfr8 bf = *(const bfr8*)&xs[pixoff[pf] + toff];
        acc[pf] = MFMA16(af, bf, acc[pf]);
      }
    }
  }
  #pragma unroll
  for (int rr = 0; rr < 4; ++rr){
    int co = cog*64 + w*16 + 4*blk + rr;
    float al = alpha[co], bc = bconst[co];
    #pragma unroll
    for (int pf = 0; pf < 7; ++pf){
      float v = fmaxf(acc[pf][rr]*al + bc, 0.f);
      short sv = f2bf(v);
      int n = r0*56 + pf*16 + l15;
      yout[(size_t)(b*128 + co)*3136 + n] = sv;
      if (TSTORE) youtT[((size_t)(b*3136) + n)*128 + co] = sv;
    }
  }
}

// ---------------------------------------------------------------------------
// 1x1 conv: qt[b][n][co] = sum_ci wq[co][ci] * xT[b][n][ci]
// ---------------------------------------------------------------------------
__global__ __launch_bounds__(256, 4) void qproj_kernel(
    const short* __restrict__ xT, const short* __restrict__ wq,
    short* __restrict__ qt)
{
  const int tid = threadIdx.x, w = tid >> 6, lane = tid & 63;
  const int l15 = lane & 15, blk = lane >> 4;
  const int b = blockIdx.x / 196, n0 = (blockIdx.x % 196) * 16;

  fx4 acc[2];
  acc[0] = fzero(); acc[1] = fzero();

  #pragma unroll
  for (int ks = 0; ks < 4; ++ks){
    bfr8 af = *(const bfr8*)&xT[((size_t)(b*3136) + n0 + l15)*128 + ks*32 + 8*blk];
    #pragma unroll
    for (int i = 0; i < 2; ++i){
      bfr8 bf = *(const bfr8*)&wq[(size_t)((w*2 + i)*16 + l15)*128 + ks*32 + 8*blk];
      acc[i] = MFMA16(af, bf, acc[i]);
    }
  }
  #pragma unroll
  for (int i = 0; i < 2; ++i){
    #pragma unroll
    for (int rr = 0; rr < 4; ++rr){
      int n = n0 + 4*blk + rr;
      qt[((size_t)(b*3136) + n)*128 + (w*2 + i)*16 + l15] = f2bf(acc[i][rr]);
    }
  }
}

// ---------------------------------------------------------------------------
// FAST PATH: full QK GEMM. S[b][n][m] bf16 (rounded), plus per-(64n-range, m)
// logsumexp partials computed from the ROUNDED values (bitwise-consistent
// with what attn2 will read back).
// Grid: b(4) x bn(25) x bm(25) = 2500 blocks; 4 waves as 2x2 of 64x64 tiles.
// ---------------------------------------------------------------------------
__global__ __launch_bounds__(256, 2) void qk_kernel(
    const short* __restrict__ q1t, const short* __restrict__ q2t,
    short* __restrict__ S, float* __restrict__ pmax, float* __restrict__ psum)
{
  const int tid = threadIdx.x, w = tid >> 6, lane = tid & 63;
  const int l15 = lane & 15, blk = lane >> 4;
  const int bid = blockIdx.x;
  const int bm = bid % 25, bn = (bid / 25) % 25, b = bid / 625;
  const int n0w = bn*128 + (w >> 1)*64;
  const int m0w = bm*128 + (w & 1)*64;
  if (n0w >= 3136 || m0w >= 3136) return;   // 3136 = 49*64: surviving waves fully in-bounds

  fx4 acc[4][4];
  #pragma unroll
  for (int nf = 0; nf < 4; ++nf)
    #pragma unroll
    for (int mf = 0; mf < 4; ++mf) acc[nf][mf] = fzero();

  #pragma unroll
  for (int ks = 0; ks < 4; ++ks){
    bfr8 af[4], bv[4];
    #pragma unroll
    for (int nf = 0; nf < 4; ++nf)
      af[nf] = *(const bfr8*)&q1t[((size_t)(b*3136) + n0w + nf*16 + l15)*128 + ks*32 + 8*blk];
    #pragma unroll
    for (int mf = 0; mf < 4; ++mf)
      bv[mf] = *(const bfr8*)&q2t[((size_t)(b*3136) + m0w + mf*16 + l15)*128 + ks*32 + 8*blk];
    #pragma unroll
    for (int nf = 0; nf < 4; ++nf)
      #pragma unroll
      for (int mf = 0; mf < 4; ++mf)
        acc[nf][mf] = MFMA16(af[nf], bv[mf], acc[nf][mf]);
  }

  #pragma unroll
  for (int mf = 0; mf < 4; ++mf){
    const int m = m0w + mf*16 + l15;
    float rnd[4][4];
    float mx = -1e30f;
    #pragma unroll
    for (int nf = 0; nf < 4; ++nf){
      #pragma unroll
      for (int rr = 0; rr < 4; ++rr){
        short sv = f2bf(acc[nf][mf][rr]);
        S[((size_t)(b*3136) + n0w + nf*16 + 4*blk + rr)*3136 + m] = sv;
        rnd[nf][rr] = bf2f(sv);
        mx = fmaxf(mx, rnd[nf][rr]);
      }
    }
    float se = 0.f;
    #pragma unroll
    for (int nf = 0; nf < 4; ++nf)
      #pragma unroll
      for (int rr = 0; rr < 4; ++rr) se += __expf(rnd[nf][rr] - mx);
    // merge across the 4 blk groups (different n rows)
    #pragma unroll
    for (int d = 16; d < 64; d <<= 1){
      float om = __shfl_xor(mx, d);
      float os = __shfl_xor(se, d);
      float M = fmaxf(mx, om);
      se = se*__expf(mx - M) + os*__expf(om - M);
      mx = M;
    }
    if (blk == 0){
      size_t pidx = ((size_t)(b*49) + (n0w >> 6))*3136 + m;
      pmax[pidx] = mx; psum[pidx] = se;
    }
  }
}

// ---------------------------------------------------------------------------
// FAST PATH: merge the 49 per-n-range lse partials -> Lm[b][m]
// ---------------------------------------------------------------------------
__global__ void lse_merge_kernel(
    const float* __restrict__ pmax, const float* __restrict__ psum,
    float* __restrict__ Lm)
{
  int t = blockIdx.x*256 + threadIdx.x;
  if (t >= 12544) return;
  int b = t / 3136, m = t - b*3136;
  float M = -1e30f;
  for (int nr = 0; nr < 49; ++nr)
    M = fmaxf(M, pmax[((size_t)(b*49) + nr)*3136 + m]);
  float Ssum = 0.f;
  for (int nr = 0; nr < 49; ++nr){
    size_t i = ((size_t)(b*49) + nr)*3136 + m;
    Ssum += psum[i]*__expf(pmax[i] - M);
  }
  Lm[t] = M + __logf(Ssum);
}

// ---------------------------------------------------------------------------
// FAST PATH pass 2: read S tiles (no QK recompute), P = exp(exp(s - Lm)),
// PV + rowsum online; waves split m 4-way, LDS combine; out = PV/rsum + x1.
// The [n][m] S layout makes the PV B-fragment = one contiguous 16B load/lane.
// ---------------------------------------------------------------------------
__global__ __launch_bounds__(256, 2) void attn2_kernel(
    const short* __restrict__ S, const short* __restrict__ x2v,
    const float* __restrict__ Lm, const float* __restrict__ x1,
    float* __restrict__ out0)
{
  __shared__ float part[8][4][4][64];   // [cf][rr][w][lane] 32 KB
  __shared__ float rl[4][16];
  const int tid = threadIdx.x, w = tid >> 6, lane = tid & 63;
  const int l15 = lane & 15, blk = lane >> 4;
  const int b = blockIdx.x / 196, n0 = (blockIdx.x % 196) * 16;
  const int n = n0 + l15;
  const size_t srow = ((size_t)(b*3136) + n)*3136;

  fx4 pacc[8];
  #pragma unroll
  for (int cf = 0; cf < 8; ++cf) pacc[cf] = fzero();
  float rsum = 0.f;

  for (int s = w; s < 49; s += 4){
    const int m0 = s*64;
    #pragma unroll
    for (int ks2 = 0; ks2 < 2; ++ks2){
      const int mb = m0 + ks2*32 + 8*blk;
      bfr8 sv = *(const bfr8*)&S[srow + mb];
      float4 L0 = *(const float4*)&Lm[b*3136 + mb];
      float4 L1 = *(const float4*)&Lm[b*3136 + mb + 4];
      float lmv[8] = {L0.x, L0.y, L0.z, L0.w, L1.x, L1.y, L1.z, L1.w};
      bfr8 pb;
      #pragma unroll
      for (int j = 0; j < 8; ++j){
        float a1 = __expf(bf2f(sv[j]) - lmv[j]);   // in (0, ~1]
        float p  = __expf(a1);
        rsum += p;
        pb[j] = f2bf(p);
      }
      #pragma unroll
      for (int cf = 0; cf < 8; ++cf){
        bfr8 av = *(const bfr8*)&x2v[((size_t)(b*128) + cf*16 + l15)*3136 + mb];
        pacc[cf] = MFMA16(av, pb, pacc[cf]);
      }
    }
  }
  // rowsum: all p of a lane belong to n=l15; reduce across blk groups
  rsum += __shfl_xor(rsum, 16);
  rsum += __shfl_xor(rsum, 32);
  if (lane < 16) rl[w][lane] = rsum;
  #pragma unroll
  for (int cf = 0; cf < 8; ++cf)
    #pragma unroll
    for (int rr = 0; rr < 4; ++rr)
      part[cf][rr][w][lane] = pacc[cf][rr];
  __syncthreads();

  float rtot = rl[0][l15] + rl[1][l15] + rl[2][l15] + rl[3][l15];
  float rinv = 1.0f / rtot;
  #pragma unroll
  for (int i = 0; i < 2; ++i){
    int cf = 2*w + i;
    #pragma unroll
    for (int rr = 0; rr < 4; ++rr){
      float v = part[cf][rr][0][lane] + part[cf][rr][1][lane]
              + part[cf][rr][2][lane] + part[cf][rr][3][lane];
      int c = cf*16 + 4*blk + rr;
      size_t idx = ((size_t)(b*128) + c)*3136 + n;
      out0[idx] = v*rinv + x1[idx];
    }
  }
}

// ---------------------------------------------------------------------------
// FALLBACK PATH (ws too small): R2 colstats + attn
// ---------------------------------------------------------------------------
__global__ __launch_bounds__(256, 2) void colstats_kernel(
    const short* __restrict__ q1t, const short* __restrict__ q2t,
    float* __restrict__ Lm)
{
  __shared__ float smax[4][16];
  __shared__ float ssum[4][16];
  const int tid = threadIdx.x, w = tid >> 6, lane = tid & 63;
  const int l15 = lane & 15, blk = lane >> 4;
  const int b = blockIdx.x / 196, m0 = (blockIdx.x % 196) * 16;

  bfr8 bfr[4];
  #pragma unroll
  for (int ks = 0; ks < 4; ++ks)
    bfr[ks] = *(const bfr8*)&q2t[((size_t)(b*3136) + m0 + l15)*128 + ks*32 + 8*blk];

  float vmax = -1e30f, vsum = 0.f;

  for (int nc = w; nc < 196; nc += 4){
    fx4 acc = fzero();
    #pragma unroll
    for (int ks = 0; ks < 4; ++ks){
      bfr8 af = *(const bfr8*)&q1t[((size_t)(b*3136) + nc*16 + l15)*128 + ks*32 + 8*blk];
      acc = MFMA16(af, bfr[ks], acc);
    }
    float cm = fmaxf(fmaxf(acc[0], acc[1]), fmaxf(acc[2], acc[3]));
    float nm = fmaxf(vmax, cm);
    float cs = __expf(acc[0]-nm) + __expf(acc[1]-nm)
             + __expf(acc[2]-nm) + __expf(acc[3]-nm);
    vsum = vsum*__expf(vmax-nm) + cs;
    vmax = nm;
  }
  #pragma unroll
  for (int d = 16; d < 64; d <<= 1){
    float om = __shfl_xor(vmax, d);
    float os = __shfl_xor(vsum, d);
    float M = fmaxf(vmax, om);
    vsum = vsum*__expf(vmax - M) + os*__expf(om - M);
    vmax = M;
  }
  if (lane < 16){ smax[w][lane] = vmax; ssum[w][lane] = vsum; }
  __syncthreads();
  if (tid < 16){
    float M = fmaxf(fmaxf(smax[0][tid], smax[1][tid]), fmaxf(smax[2][tid], smax[3][tid]));
    float S = ssum[0][tid]*__expf(smax[0][tid]-M) + ssum[1][tid]*__expf(smax[1][tid]-M)
            + ssum[2][tid]*__expf(smax[2][tid]-M) + ssum[3][tid]*__expf(smax[3][tid]-M);
    Lm[b*3136 + m0 + tid] = M + __logf(S);
  }
}

__global__ __launch_bounds__(256, 2) void attn_kernel(
    const short* __restrict__ q1t, const short* __restrict__ q2t,
    const short* __restrict__ x2v, const float* __restrict__ Lm,
    const float* __restrict__ x1, float* __restrict__ out0)
{
  __shared__ float part[8][4][4][64];
  __shared__ short plds[4][16][72];
  __shared__ float rl[4][16];
  const int tid = threadIdx.x, w = tid >> 6, lane = tid & 63;
  const int l15 = lane & 15, blk = lane >> 4;
  const int b = blockIdx.x / 196, n0 = (blockIdx.x % 196) * 16;

  bfr8 qa[4];
  #pragma unroll
  for (int ks = 0; ks < 4; ++ks)
    qa[ks] = *(const bfr8*)&q1t[((size_t)(b*3136) + n0 + l15)*128 + ks*32 + 8*blk];

  fx4 pacc[8];
  #pragma unroll
  for (int cf = 0; cf < 8; ++cf) pacc[cf] = fzero();
  float rsum[4] = {0.f, 0.f, 0.f, 0.f};

  for (int s = w; s < 49; s += 4){
    const int m0m = s*64;
    fx4 s4[4];
    #pragma unroll
    for (int mf = 0; mf < 4; ++mf) s4[mf] = fzero();
    #pragma unroll
    for (int ks = 0; ks < 4; ++ks){
      #pragma unroll
      for (int mf = 0; mf < 4; ++mf){
        bfr8 bq = *(const bfr8*)&q2t[((size_t)(b*3136) + m0m + mf*16 + l15)*128 + ks*32 + 8*blk];
        s4[mf] = MFMA16(qa[ks], bq, s4[mf]);
      }
    }
    #pragma unroll
    for (int mf = 0; mf < 4; ++mf){
      float Lv = Lm[b*3136 + m0m + mf*16 + l15];
      #pragma unroll
      for (int rr = 0; rr < 4; ++rr){
        float a1 = __expf(s4[mf][rr] - Lv);
        float p  = __expf(a1);
        rsum[rr] += p;
        plds[w][4*blk + rr][mf*16 + l15] = f2bf(p);
      }
    }
    #pragma unroll
    for (int ks2 = 0; ks2 < 2; ++ks2){
      bfr8 pb = *(const bfr8*)&plds[w][l15][ks2*32 + 8*blk];
      #pragma unroll
      for (int cf = 0; cf < 8; ++cf){
        bfr8 av = *(const bfr8*)&x2v[((size_t)(b*128) + cf*16 + l15)*3136 + m0m + ks2*32 + 8*blk];
        pacc[cf] = MFMA16(av, pb, pacc[cf]);
      }
    }
  }
  #pragma unroll
  for (int d = 1; d < 16; d <<= 1){
    #pragma unroll
    for (int rr = 0; rr < 4; ++rr) rsum[rr] += __shfl_xor(rsum[rr], d);
  }
  if (l15 == 0){
    #pragma unroll
    for (int rr = 0; rr < 4; ++rr) rl[w][4*blk + rr] = rsum[rr];
  }
  #pragma unroll
  for (int cf = 0; cf < 8; ++cf)
    #pragma unroll
    for (int rr = 0; rr < 4; ++rr)
      part[cf][rr][w][lane] = pacc[cf][rr];
  __syncthreads();

  float rtot = rl[0][l15] + rl[1][l15] + rl[2][l15] + rl[3][l15];
  float rinv = 1.0f / rtot;
  const int n = n0 + l15;
  #pragma unroll
  for (int i = 0; i < 2; ++i){
    int cf = 2*w + i;
    #pragma unroll
    for (int rr = 0; rr < 4; ++rr){
      float v = part[cf][rr][0][lane] + part[cf][rr][1][lane]
              + part[cf][rr][2][lane] + part[cf][rr][3][lane];
      int c = cf*16 + 4*blk + rr;
      size_t idx = (size_t)(b*128 + c)*3136 + n;
      out0[idx] = v*rinv + x1[idx];
    }
  }
}

// ---------------------------------------------------------------------------
extern "C" void kernel_launch(void* const* d_in, const int* in_sizes, int n_in,
                              void* d_out, int out_size, void* d_ws, size_t ws_size,
                              hipStream_t stream)
{
  (void)in_sizes; (void)n_in; (void)out_size;
  const float* x1     = (const float*)d_in[0];
  const float* x2     = (const float*)d_in[1];
  const float* wsw    = (const float*)d_in[2];
  const float* bs     = (const float*)d_in[3];
  const float* sg     = (const float*)d_in[4];
  const float* sbeta  = (const float*)d_in[5];
  const float* smean  = (const float*)d_in[6];
  const float* svar   = (const float*)d_in[7];
  const float* wq1    = (const float*)d_in[8];
  const float* wq2    = (const float*)d_in[9];
  // d_in[10..15]: v1 conv_block params -> dead code, unused
  const float* v2w    = (const float*)d_in[16];
  const float* v2bias = (const float*)d_in[17];
  const float* v2g    = (const float*)d_in[18];
  const float* v2beta = (const float*)d_in[19];
  const float* v2mean = (const float*)d_in[20];
  const float* v2var  = (const float*)d_in[21];

  char* ws = (char*)d_ws;
  auto al = [](size_t x){ return (x + 255) & ~(size_t)255; };

  const size_t sz_nc    = al((size_t)1605632*2);          // [4][3136][128] bf16
  const size_t sz_x2bf  = al((size_t)6422528*2);
  const size_t sz_Lm    = al((size_t)12544*4);
  const size_t sz_part  = al((size_t)4*49*3136*4);
  const size_t sz_cst   = al((size_t)768*4);
  const size_t sz_S     = al((size_t)4*3136*3136*2);
  const size_t sz_wsbf  = al((size_t)589824*2);
  const size_t sz_wv2   = al((size_t)147456*2);
  const size_t sz_wq    = al((size_t)16384*2);

  short *x2bf, *x1T, *wsbf, *wv2a, *wv2b, *wq1b, *wq2b;
  short *x2s, *x2sT, *q1t, *q2t, *v2t, *x2v, *Sbuf = nullptr;
  float *consts, *Lm, *pmax = nullptr, *psum = nullptr;

  // fast layout: persistent buffers first, S last; transients overlaid on S
  size_t off = 0;
  const size_t o_x2v = off;  off += sz_nc;
  const size_t o_q1t = off;  off += sz_nc;
  const size_t o_q2t = off;  off += sz_nc;
  const size_t o_Lm  = off;  off += sz_Lm;
  const size_t o_pmx = off;  off += sz_part;
  const size_t o_psm = off;  off += sz_part;
  const size_t o_cst = off;  off += sz_cst;
  const size_t o_S   = off;  off += sz_S;
  const size_t fast_need = off;
  const bool fast = (ws_size >= fast_need);

  if (fast){
    x2v    = (short*)(ws + o_x2v);
    q1t    = (short*)(ws + o_q1t);
    q2t    = (short*)(ws + o_q2t);
    Lm     = (float*)(ws + o_Lm);
    pmax   = (float*)(ws + o_pmx);
    psum   = (float*)(ws + o_psm);
    consts = (float*)(ws + o_cst);
    Sbuf   = (short*)(ws + o_S);
    size_t t = o_S;  // transients are dead before qk_kernel writes S
    x2bf = (short*)(ws + t); t += sz_x2bf;
    x1T  = (short*)(ws + t); t += sz_nc;
    x2sT = (short*)(ws + t); t += sz_nc;
    x2s  = (short*)(ws + t); t += sz_nc;
    v2t  = (short*)(ws + t); t += sz_nc;
    wsbf = (short*)(ws + t); t += sz_wsbf;
    wv2a = (short*)(ws + t); t += sz_wv2;
    wv2b = (short*)(ws + t); t += sz_wv2;
    wq1b = (short*)(ws + t); t += sz_wq;
    wq2b = (short*)(ws + t); t += sz_wq;
  } else {
    size_t o = 0;
    auto bump = [&](size_t bytes)->char*{ char* p = ws + o; o += al(bytes); return p; };
    x2bf   = (short*)bump((size_t)6422528*2);
    x1T    = (short*)bump((size_t)1605632*2);
    wsbf   = (short*)bump((size_t)589824*2);
    wv2a   = (short*)bump((size_t)147456*2);
    wv2b   = (short*)bump((size_t)147456*2);
    wq1b   = (short*)bump((size_t)16384*2);
    wq2b   = (short*)bump((size_t)16384*2);
    consts = (float*)bump((size_t)768*4);
    x2s    = (short*)bump((size_t)1605632*2);
    x2sT   = (short*)bump((size_t)1605632*2);
    q1t    = (short*)bump((size_t)1605632*2);
    q2t    = (short*)bump((size_t)1605632*2);
    v2t    = (short*)bump((size_t)1605632*2);
    x2v    = (short*)bump((size_t)1605632*2);
    Lm     = (float*)bump((size_t)12544*4);
  }

  float* out0 = (float*)d_out;
  float* out1 = out0 + 1605632;

  prep_kernel<<<2048, 256, 0, stream>>>(x1, x2, wsw, bs, sg, sbeta, smean, svar,
      wq1, wq2, v2w, v2bias, v2g, v2beta, v2mean, v2var,
      x2bf, x1T, wsbf, wv2a, wv2b, wq1b, wq2b, consts, out1);

  conv3x3_kernel<512, true ><<<224, 256, 0, stream>>>(x2bf, wsbf, consts, consts + 128, x2s, x2sT);
  qproj_kernel<<<784, 256, 0, stream>>>(x1T,  wq1b, q1t);
  qproj_kernel<<<784, 256, 0, stream>>>(x2sT, wq2b, q2t);
  conv3x3_kernel<128, false><<<224, 256, 0, stream>>>(x2s, wv2a, consts + 256, consts + 384, v2t, nullptr);
  conv3x3_kernel<128, false><<<224, 256, 0, stream>>>(v2t, wv2b, consts + 512, consts + 640, x2v, nullptr);

  if (fast){
    qk_kernel<<<2500, 256, 0, stream>>>(q1t, q2t, Sbuf, pmax, psum);
    lse_merge_kernel<<<49, 256, 0, stream>>>(pmax, psum, Lm);
    attn2_kernel<<<784, 256, 0, stream>>>(Sbuf, x2v, Lm, x1, out0);
  } else {
    colstats_kernel<<<784, 256, 0, stream>>>(q1t, q2t, Lm);
    attn_kernel<<<784, 256, 0, stream>>>(q1t, q2t, x2v, Lm, x1, out0);
  }
}

// Round 4
// 290.384 us; speedup vs baseline: 1.7678x; 1.0448x over previous
//
#include <hip/hip_runtime.h>
#include <cstdint>
#include <cstddef>

using bfr8 = __attribute__((ext_vector_type(8))) short;   // 8 bf16 (4 VGPRs)
using sh4  = __attribute__((ext_vector_type(4))) short;
using fx4  = __attribute__((ext_vector_type(4))) float;

#define DI __device__ __forceinline__
#define MFMA16(a,b,c) __builtin_amdgcn_mfma_f32_16x16x32_bf16((a),(b),(c),0,0,0)

DI short f2bf(float f){
  unsigned u = __float_as_uint(f);
  return (short)((u + 0x7fffu + ((u >> 16) & 1u)) >> 16);
}
DI float bf2f(short s){
  return __uint_as_float(((unsigned)(unsigned short)s) << 16);
}
DI fx4 fzero(){ fx4 z; z[0]=0.f; z[1]=0.f; z[2]=0.f; z[3]=0.f; return z; }

// ---------------------------------------------------------------------------
// prep: dtype conversions, weight re-layout [co][tap][ci], BN folding,
//       x1 transpose [b][n][c], and the out1 = x2 copy.
// ---------------------------------------------------------------------------
__global__ void prep_kernel(
    const float* __restrict__ x1, const float* __restrict__ x2,
    const float* __restrict__ wsw, const float* __restrict__ bs,
    const float* __restrict__ sg, const float* __restrict__ sbeta,
    const float* __restrict__ smean, const float* __restrict__ svar,
    const float* __restrict__ wq1, const float* __restrict__ wq2,
    const float* __restrict__ v2w, const float* __restrict__ v2bias,
    const float* __restrict__ v2g, const float* __restrict__ v2beta,
    const float* __restrict__ v2mean, const float* __restrict__ v2var,
    short* __restrict__ x2bf, short* __restrict__ x1T,
    short* __restrict__ wsbf, short* __restrict__ wv2a, short* __restrict__ wv2b,
    short* __restrict__ wq1b, short* __restrict__ wq2b,
    float* __restrict__ consts, float* __restrict__ out1copy)
{
  const int gsz = gridDim.x * blockDim.x;
  const int gid = blockIdx.x * blockDim.x + threadIdx.x;

  for (int i = gid; i < 1605632; i += gsz){
    float4 v = ((const float4*)x2)[i];
    ((float4*)out1copy)[i] = v;
    sh4 o; o[0]=f2bf(v.x); o[1]=f2bf(v.y); o[2]=f2bf(v.z); o[3]=f2bf(v.w);
    ((sh4*)x2bf)[i] = o;
  }
  for (int t = gid; t < 200704; t += gsz){
    int g = t & 15; int nn = t >> 4;
    int b = nn / 3136, n = nn - b*3136;
    bfr8 o;
    #pragma unroll
    for (int k = 0; k < 8; ++k)
      o[k] = f2bf(x1[(size_t)(b*128 + g*8 + k)*3136 + n]);
    *(bfr8*)&x1T[((size_t)(b*3136) + n)*128 + g*8] = o;
  }
  for (int i = gid; i < 589824; i += gsz){
    int ci = i & 511; int tap = (i >> 9) % 9; int co = i / 4608;
    wsbf[i] = f2bf(wsw[(size_t)(co*512 + ci)*9 + tap]);
  }
  for (int i = gid; i < 294912; i += gsz){
    int s = i / 147456; int r = i - s*147456;
    int ci = r & 127; int tap = (r >> 7) % 9; int co = r / 1152;
    float v = v2w[(size_t)((s*128 + co)*128 + ci)*9 + tap];
    (s ? wv2b : wv2a)[r] = f2bf(v);
  }
  for (int i = gid; i < 16384; i += gsz){
    wq1b[i] = f2bf(wq1[i]); wq2b[i] = f2bf(wq2[i]);
  }
  for (int c = gid; c < 128; c += gsz){
    float a = sg[c] * rsqrtf(svar[c] + 1e-5f);
    consts[c]       = a;
    consts[128 + c] = (bs[c] - smean[c]) * a + sbeta[c];
    float a0 = v2g[c] * rsqrtf(v2var[c] + 1e-5f);
    consts[256 + c] = a0;
    consts[384 + c] = (v2bias[c] - v2mean[c]) * a0 + v2beta[c];
    float a1 = v2g[128+c] * rsqrtf(v2var[128+c] + 1e-5f);
    consts[512 + c] = a1;
    consts[640 + c] = (v2bias[128+c] - v2mean[128+c]) * a1 + v2beta[128+c];
  }
}

// ---------------------------------------------------------------------------
// FAST PATH conv: split-K conv3x3 (pad=1), raw f32 partials (no BN).
// Grid: (224, 2): blockIdx.y = ci-split. pout[split][b][co][n] f32.
// ---------------------------------------------------------------------------
template<int CIN, int NCIB>
__global__ __launch_bounds__(256, 2) void conv3x3_split_kernel(
    const short* __restrict__ xin,   // [4][CIN][3136] bf16
    const short* __restrict__ wt,    // [128][9][CIN] bf16
    float* __restrict__ pout)        // [2][4][128][3136] f32
{
  __shared__ short xs[4*58*40];
  __shared__ short wsh[9*64*40];

  const int tid = threadIdx.x;
  const int w = tid >> 6, lane = tid & 63, l15 = lane & 15, blk = lane >> 4;
  const int bid = blockIdx.x;
  const int rt = bid % 28, cog = (bid / 28) & 1, b = bid / 56;
  const int r0 = rt * 2;
  const int split = blockIdx.y;
  const int cib0 = split * NCIB;
  float* pbase = pout + (size_t)split * 1605632;

  int pixoff[7];
  #pragma unroll
  for (int pf = 0; pf < 7; ++pf){
    int p = pf*16 + l15;
    int pr = (p >= 56) ? 1 : 0;
    int pc = p - pr*56;
    pixoff[pf] = (pr*58 + pc)*40 + 8*blk;
  }
  const int wlo = (w*16 + l15)*40 + 8*blk;

  fx4 acc[7];
  #pragma unroll
  for (int pf = 0; pf < 7; ++pf) acc[pf] = fzero();

  for (int ci = 0; ci < NCIB; ++ci){
    const int cib = cib0 + ci;
    __syncthreads();
    #pragma unroll
    for (int it = 0; it < 4; ++it){
      int q = it*256 + tid;
      if (q < 928){
        int col = q % 58; int cg8 = (q/58) & 3; int r = q / 232;
        int grow = r0 - 1 + r;
        int gcol = col - 1;
        bfr8 v;
        if (grow >= 0 && grow < 56 && gcol >= 0 && gcol < 56){
          #pragma unroll
          for (int k = 0; k < 8; ++k)
            v[k] = xin[(size_t)(b*CIN + cib*32 + cg8*8 + k)*3136 + grow*56 + gcol];
        } else {
          #pragma unroll
          for (int k = 0; k < 8; ++k) v[k] = 0;
        }
        *(bfr8*)&xs[(r*58 + col)*40 + cg8*8] = v;
      }
    }
    #pragma unroll
    for (int it = 0; it < 9; ++it){
      int q = it*256 + tid;
      int jj = q & 3; int tap = (q >> 2) % 9; int co = q / 36;
      bfr8 wv = *(const bfr8*)&wt[(size_t)((cog*64 + co)*9 + tap)*CIN + cib*32 + jj*8];
      *(bfr8*)&wsh[(tap*64 + co)*40 + jj*8] = wv;
    }
    __syncthreads();
    #pragma unroll
    for (int tap = 0; tap < 9; ++tap){
      bfr8 af = *(const bfr8*)&wsh[tap*64*40 + wlo];
      const int toff = ((tap/3)*58 + (tap%3))*40;
      #pragma unroll
      for (int pf = 0; pf < 7; ++pf){
        bfr8 bf = *(const bfr8*)&xs[pixoff[pf] + toff];
        acc[pf] = MFMA16(af, bf, acc[pf]);
      }
    }
  }
  #pragma unroll
  for (int rr = 0; rr < 4; ++rr){
    int co = cog*64 + w*16 + 4*blk + rr;
    #pragma unroll
    for (int pf = 0; pf < 7; ++pf){
      int n = r0*56 + pf*16 + l15;
      pbase[(size_t)(b*128 + co)*3136 + n] = acc[pf][rr];
    }
  }
}

// ---------------------------------------------------------------------------
// combine: y = relu((p0+p1)*alpha + bc) -> bf16, plus optional transpose.
// Grid: 392 = 4b x 2cog x 49 n-tiles(64). Tile 64co x 64n.
// ---------------------------------------------------------------------------
template<bool TSTORE>
__global__ __launch_bounds__(256, 4) void conv_combine_kernel(
    const float* __restrict__ p, const float* __restrict__ alpha,
    const float* __restrict__ bconst,
    short* __restrict__ yout, short* __restrict__ youtT)
{
  __shared__ short lt[64][66];
  const int t = threadIdx.x;
  const int bid = blockIdx.x;
  const int nt = bid % 49, cog = (bid / 49) & 1, b = bid / 98;
  const int co0 = cog*64, n0 = nt*64;
  const int coL = t >> 4, ncL = (t & 15) * 4;

  #pragma unroll
  for (int rep = 0; rep < 4; ++rep){
    int co = co0 + rep*16 + coL;
    size_t base = ((size_t)(b*128) + co)*3136 + n0 + ncL;
    float4 a0 = *(const float4*)&p[base];
    float4 a1 = *(const float4*)&p[1605632 + base];
    float al = alpha[co], bc = bconst[co];
    sh4 o;
    o[0] = f2bf(fmaxf((a0.x+a1.x)*al + bc, 0.f));
    o[1] = f2bf(fmaxf((a0.y+a1.y)*al + bc, 0.f));
    o[2] = f2bf(fmaxf((a0.z+a1.z)*al + bc, 0.f));
    o[3] = f2bf(fmaxf((a0.w+a1.w)*al + bc, 0.f));
    *(sh4*)&yout[base] = o;
    if (TSTORE) *(sh4*)&lt[rep*16 + coL][ncL] = o;
  }
  if (TSTORE){
    __syncthreads();
    #pragma unroll
    for (int rep = 0; rep < 4; ++rep){
      int nn = rep*16 + (t >> 4);
      int coc = (t & 15) * 4;
      sh4 v;
      #pragma unroll
      for (int j = 0; j < 4; ++j) v[j] = lt[coc + j][nn];
      *(sh4*)&youtT[((size_t)(b*3136) + n0 + nn)*128 + co0 + coc] = v;
    }
  }
}

// ---------------------------------------------------------------------------
// FALLBACK conv: conv3x3 + BN + ReLU fused (original).
// ---------------------------------------------------------------------------
template<int CIN, bool TSTORE>
__global__ __launch_bounds__(256, 2) void conv3x3_kernel(
    const short* __restrict__ xin, const short* __restrict__ wt,
    const float* __restrict__ alpha, const float* __restrict__ bconst,
    short* __restrict__ yout, short* __restrict__ youtT)
{
  __shared__ short xs[4*58*40];
  __shared__ short wsh[9*64*40];

  const int tid = threadIdx.x;
  const int w = tid >> 6, lane = tid & 63, l15 = lane & 15, blk = lane >> 4;
  const int bid = blockIdx.x;
  const int rt = bid % 28, cog = (bid / 28) & 1, b = bid / 56;
  const int r0 = rt * 2;

  int pixoff[7];
  #pragma unroll
  for (int pf = 0; pf < 7; ++pf){
    int p = pf*16 + l15;
    int pr = (p >= 56) ? 1 : 0;
    int pc = p - pr*56;
    pixoff[pf] = (pr*58 + pc)*40 + 8*blk;
  }
  const int wlo = (w*16 + l15)*40 + 8*blk;

  fx4 acc[7];
  #pragma unroll
  for (int pf = 0; pf < 7; ++pf) acc[pf] = fzero();

  for (int cib = 0; cib < CIN/32; ++cib){
    __syncthreads();
    #pragma unroll
    for (int it = 0; it < 4; ++it){
      int q = it*256 + tid;
      if (q < 928){
        int col = q % 58; int cg8 = (q/58) & 3; int r = q / 232;
        int grow = r0 - 1 + r;
        int gcol = col - 1;
        bfr8 v;
        if (grow >= 0 && grow < 56 && gcol >= 0 && gcol < 56){
          #pragma unroll
          for (int k = 0; k < 8; ++k)
            v[k] = xin[(size_t)(b*CIN + cib*32 + cg8*8 + k)*3136 + grow*56 + gcol];
        } else {
          #pragma unroll
          for (int k = 0; k < 8; ++k) v[k] = 0;
        }
        *(bfr8*)&xs[(r*58 + col)*40 + cg8*8] = v;
      }
    }
    #pragma unroll
    for (int it = 0; it < 9; ++it){
      int q = it*256 + tid;
      int jj = q & 3; int tap = (q >> 2) % 9; int co = q / 36;
      bfr8 wv = *(const bfr8*)&wt[(size_t)((cog*64 + co)*9 + tap)*CIN + cib*32 + jj*8];
      *(bfr8*)&wsh[(tap*64 + co)*40 + jj*8] = wv;
    }
    __syncthreads();
    #pragma unroll
    for (int tap = 0; tap < 9; ++tap){
      bfr8 af = *(const bfr8*)&wsh[tap*64*40 + wlo];
      const int toff = ((tap/3)*58 + (tap%3))*40;
      #pragma unroll
      for (int pf = 0; pf < 7; ++pf){
        bfr8 bf = *(const bfr8*)&xs[pixoff[pf] + toff];
        acc[pf] = MFMA16(af, bf, acc[pf]);
      }
    }
  }
  #pragma unroll
  for (int rr = 0; rr < 4; ++rr){
    int co = cog*64 + w*16 + 4*blk + rr;
    float al = alpha[co], bc = bconst[co];
    #pragma unroll
    for (int pf = 0; pf < 7; ++pf){
      float v = fmaxf(acc[pf][rr]*al + bc, 0.f);
      short sv = f2bf(v);
      int n = r0*56 + pf*16 + l15;
      yout[(size_t)(b*128 + co)*3136 + n] = sv;
      if (TSTORE) youtT[((size_t)(b*3136) + n)*128 + co] = sv;
    }
  }
}

// ---------------------------------------------------------------------------
// 1x1 conv: qt[b][n][co] = sum_ci wq[co][ci] * xT[b][n][ci]
// ---------------------------------------------------------------------------
__global__ __launch_bounds__(256, 4) void qproj_kernel(
    const short* __restrict__ xT, const short* __restrict__ wq,
    short* __restrict__ qt)
{
  const int tid = threadIdx.x, w = tid >> 6, lane = tid & 63;
  const int l15 = lane & 15, blk = lane >> 4;
  const int b = blockIdx.x / 196, n0 = (blockIdx.x % 196) * 16;

  fx4 acc[2];
  acc[0] = fzero(); acc[1] = fzero();

  #pragma unroll
  for (int ks = 0; ks < 4; ++ks){
    bfr8 af = *(const bfr8*)&xT[((size_t)(b*3136) + n0 + l15)*128 + ks*32 + 8*blk];
    #pragma unroll
    for (int i = 0; i < 2; ++i){
      bfr8 bf = *(const bfr8*)&wq[(size_t)((w*2 + i)*16 + l15)*128 + ks*32 + 8*blk];
      acc[i] = MFMA16(af, bf, acc[i]);
    }
  }
  #pragma unroll
  for (int i = 0; i < 2; ++i){
    #pragma unroll
    for (int rr = 0; rr < 4; ++rr){
      int n = n0 + 4*blk + rr;
      qt[((size_t)(b*3136) + n)*128 + (w*2 + i)*16 + l15] = f2bf(acc[i][rr]);
    }
  }
}

// ---------------------------------------------------------------------------
// FAST PATH: full QK GEMM -> S bf16 + per-(64n, m) lse partials.
// ---------------------------------------------------------------------------
__global__ __launch_bounds__(256, 2) void qk_kernel(
    const short* __restrict__ q1t, const short* __restrict__ q2t,
    short* __restrict__ S, float* __restrict__ pmax, float* __restrict__ psum)
{
  const int tid = threadIdx.x, w = tid >> 6, lane = tid & 63;
  const int l15 = lane & 15, blk = lane >> 4;
  const int bid = blockIdx.x;
  const int bm = bid % 25, bn = (bid / 25) % 25, b = bid / 625;
  const int n0w = bn*128 + (w >> 1)*64;
  const int m0w = bm*128 + (w & 1)*64;
  if (n0w >= 3136 || m0w >= 3136) return;

  fx4 acc[4][4];
  #pragma unroll
  for (int nf = 0; nf < 4; ++nf)
    #pragma unroll
    for (int mf = 0; mf < 4; ++mf) acc[nf][mf] = fzero();

  #pragma unroll
  for (int ks = 0; ks < 4; ++ks){
    bfr8 af[4], bv[4];
    #pragma unroll
    for (int nf = 0; nf < 4; ++nf)
      af[nf] = *(const bfr8*)&q1t[((size_t)(b*3136) + n0w + nf*16 + l15)*128 + ks*32 + 8*blk];
    #pragma unroll
    for (int mf = 0; mf < 4; ++mf)
      bv[mf] = *(const bfr8*)&q2t[((size_t)(b*3136) + m0w + mf*16 + l15)*128 + ks*32 + 8*blk];
    #pragma unroll
    for (int nf = 0; nf < 4; ++nf)
      #pragma unroll
      for (int mf = 0; mf < 4; ++mf)
        acc[nf][mf] = MFMA16(af[nf], bv[mf], acc[nf][mf]);
  }

  #pragma unroll
  for (int mf = 0; mf < 4; ++mf){
    const int m = m0w + mf*16 + l15;
    float rnd[4][4];
    float mx = -1e30f;
    #pragma unroll
    for (int nf = 0; nf < 4; ++nf){
      #pragma unroll
      for (int rr = 0; rr < 4; ++rr){
        short sv = f2bf(acc[nf][mf][rr]);
        S[((size_t)(b*3136) + n0w + nf*16 + 4*blk + rr)*3136 + m] = sv;
        rnd[nf][rr] = bf2f(sv);
        mx = fmaxf(mx, rnd[nf][rr]);
      }
    }
    float se = 0.f;
    #pragma unroll
    for (int nf = 0; nf < 4; ++nf)
      #pragma unroll
      for (int rr = 0; rr < 4; ++rr) se += __expf(rnd[nf][rr] - mx);
    #pragma unroll
    for (int d = 16; d < 64; d <<= 1){
      float om = __shfl_xor(mx, d);
      float os = __shfl_xor(se, d);
      float M = fmaxf(mx, om);
      se = se*__expf(mx - M) + os*__expf(om - M);
      mx = M;
    }
    if (blk == 0){
      size_t pidx = ((size_t)(b*49) + (n0w >> 6))*3136 + m;
      pmax[pidx] = mx; psum[pidx] = se;
    }
  }
}

// ---------------------------------------------------------------------------
__global__ void lse_merge_kernel(
    const float* __restrict__ pmax, const float* __restrict__ psum,
    float* __restrict__ Lm)
{
  int t = blockIdx.x*256 + threadIdx.x;
  if (t >= 12544) return;
  int b = t / 3136, m = t - b*3136;
  float M = -1e30f;
  for (int nr = 0; nr < 49; ++nr)
    M = fmaxf(M, pmax[((size_t)(b*49) + nr)*3136 + m]);
  float Ssum = 0.f;
  for (int nr = 0; nr < 49; ++nr){
    size_t i = ((size_t)(b*49) + nr)*3136 + m;
    Ssum += psum[i]*__expf(pmax[i] - M);
  }
  Lm[t] = M + __logf(Ssum);
}

// ---------------------------------------------------------------------------
// FAST PATH pass 2: depth-2 S prefetch, Lm staged in LDS, P=exp(exp(s-Lm)),
// PV + rowsum online, chunked cross-wave combine, out = PV/rsum + x1.
// ---------------------------------------------------------------------------
__global__ __launch_bounds__(256, 2) void attn2_kernel(
    const short* __restrict__ S, const short* __restrict__ x2v,
    const float* __restrict__ Lm, const float* __restrict__ x1,
    float* __restrict__ out0)
{
  __shared__ float lmsh[3136];          // 12.5 KB: Lm row for this batch
  __shared__ float part[4][4][4][64];   // 16 KB: chunked combine (4 cf/round)
  __shared__ float rl[4][16];
  const int tid = threadIdx.x, w = tid >> 6, lane = tid & 63;
  const int l15 = lane & 15, blk = lane >> 4;
  const int b = blockIdx.x / 196, n0 = (blockIdx.x % 196) * 16;
  const int n = n0 + l15;
  const size_t srow = ((size_t)(b*3136) + n)*3136;
  const int moff = 8*blk;

  for (int i = tid; i < 784; i += 256)
    ((float4*)lmsh)[i] = ((const float4*)(Lm + b*3136))[i];
  __syncthreads();

  fx4 pacc[8];
  #pragma unroll
  for (int cf = 0; cf < 8; ++cf) pacc[cf] = fzero();
  float rsum = 0.f;

  auto process = [&](bfr8 sv, int mb){
    bfr8 av[8];
    #pragma unroll
    for (int cf = 0; cf < 8; ++cf)
      av[cf] = *(const bfr8*)&x2v[((size_t)(b*128) + cf*16 + l15)*3136 + mb];
    bfr8 pb;
    #pragma unroll
    for (int j = 0; j < 8; ++j){
      float a1 = __expf(bf2f(sv[j]) - lmsh[mb + j]);   // in (0, ~1]
      float p  = __expf(a1);                            // in (1, e]
      rsum += p;
      pb[j] = f2bf(p);
    }
    #pragma unroll
    for (int cf = 0; cf < 8; ++cf)
      pacc[cf] = MFMA16(av[cf], pb, pacc[cf]);
  };

  // depth-2 prefetch over this wave's m-steps (s = w, w+4, ..., <49)
  bfr8 c0 = *(const bfr8*)&S[srow + (size_t)w*64 + moff];
  bfr8 c1 = *(const bfr8*)&S[srow + (size_t)w*64 + 32 + moff];
  bfr8 d0 = *(const bfr8*)&S[srow + (size_t)(w+4)*64 + moff];
  bfr8 d1 = *(const bfr8*)&S[srow + (size_t)(w+4)*64 + 32 + moff];

  for (int s = w; s < 49; s += 4){
    const int sp = s + 8;
    bfr8 e0 = c0, e1 = c1;
    if (sp < 49){
      e0 = *(const bfr8*)&S[srow + (size_t)sp*64 + moff];
      e1 = *(const bfr8*)&S[srow + (size_t)sp*64 + 32 + moff];
    }
    process(c0, s*64 + moff);
    process(c1, s*64 + 32 + moff);
    c0 = d0; c1 = d1; d0 = e0; d1 = e1;
  }

  // rowsum: reduce across blk groups (all p of a lane belong to n=l15)
  rsum += __shfl_xor(rsum, 16);
  rsum += __shfl_xor(rsum, 32);
  if (lane < 16) rl[w][lane] = rsum;

  // round 0: cf 0..3
  #pragma unroll
  for (int i = 0; i < 4; ++i)
    #pragma unroll
    for (int rr = 0; rr < 4; ++rr)
      part[i][rr][w][lane] = pacc[i][rr];
  __syncthreads();
  float rtot = rl[0][l15] + rl[1][l15] + rl[2][l15] + rl[3][l15];
  float rinv = 1.0f / rtot;
  {
    int cf = w;
    #pragma unroll
    for (int rr = 0; rr < 4; ++rr){
      float v = part[cf][rr][0][lane] + part[cf][rr][1][lane]
              + part[cf][rr][2][lane] + part[cf][rr][3][lane];
      int c = cf*16 + 4*blk + rr;
      size_t idx = ((size_t)(b*128) + c)*3136 + n;
      out0[idx] = v*rinv + x1[idx];
    }
  }
  __syncthreads();
  // round 1: cf 4..7
  #pragma unroll
  for (int i = 0; i < 4; ++i)
    #pragma unroll
    for (int rr = 0; rr < 4; ++rr)
      part[i][rr][w][lane] = pacc[4 + i][rr];
  __syncthreads();
  {
    int cf = 4 + w;
    #pragma unroll
    for (int rr = 0; rr < 4; ++rr){
      float v = part[cf-4][rr][0][lane] + part[cf-4][rr][1][lane]
              + part[cf-4][rr][2][lane] + part[cf-4][rr][3][lane];
      int c = cf*16 + 4*blk + rr;
      size_t idx = ((size_t)(b*128) + c)*3136 + n;
      out0[idx] = v*rinv + x1[idx];
    }
  }
}

// ---------------------------------------------------------------------------
// FALLBACK PATH (ws too small): R2 colstats + attn
// ---------------------------------------------------------------------------
__global__ __launch_bounds__(256, 2) void colstats_kernel(
    const short* __restrict__ q1t, const short* __restrict__ q2t,
    float* __restrict__ Lm)
{
  __shared__ float smax[4][16];
  __shared__ float ssum[4][16];
  const int tid = threadIdx.x, w = tid >> 6, lane = tid & 63;
  const int l15 = lane & 15, blk = lane >> 4;
  const int b = blockIdx.x / 196, m0 = (blockIdx.x % 196) * 16;

  bfr8 bfr[4];
  #pragma unroll
  for (int ks = 0; ks < 4; ++ks)
    bfr[ks] = *(const bfr8*)&q2t[((size_t)(b*3136) + m0 + l15)*128 + ks*32 + 8*blk];

  float vmax = -1e30f, vsum = 0.f;

  for (int nc = w; nc < 196; nc += 4){
    fx4 acc = fzero();
    #pragma unroll
    for (int ks = 0; ks < 4; ++ks){
      bfr8 af = *(const bfr8*)&q1t[((size_t)(b*3136) + nc*16 + l15)*128 + ks*32 + 8*blk];
      acc = MFMA16(af, bfr[ks], acc);
    }
    float cm = fmaxf(fmaxf(acc[0], acc[1]), fmaxf(acc[2], acc[3]));
    float nm = fmaxf(vmax, cm);
    float cs = __expf(acc[0]-nm) + __expf(acc[1]-nm)
             + __expf(acc[2]-nm) + __expf(acc[3]-nm);
    vsum = vsum*__expf(vmax-nm) + cs;
    vmax = nm;
  }
  #pragma unroll
  for (int d = 16; d < 64; d <<= 1){
    float om = __shfl_xor(vmax, d);
    float os = __shfl_xor(vsum, d);
    float M = fmaxf(vmax, om);
    vsum = vsum*__expf(vmax - M) + os*__expf(om - M);
    vmax = M;
  }
  if (lane < 16){ smax[w][lane] = vmax; ssum[w][lane] = vsum; }
  __syncthreads();
  if (tid < 16){
    float M = fmaxf(fmaxf(smax[0][tid], smax[1][tid]), fmaxf(smax[2][tid], smax[3][tid]));
    float S = ssum[0][tid]*__expf(smax[0][tid]-M) + ssum[1][tid]*__expf(smax[1][tid]-M)
            + ssum[2][tid]*__expf(smax[2][tid]-M) + ssum[3][tid]*__expf(smax[3][tid]-M);
    Lm[b*3136 + m0 + tid] = M + __logf(S);
  }
}

__global__ __launch_bounds__(256, 2) void attn_kernel(
    const short* __restrict__ q1t, const short* __restrict__ q2t,
    const short* __restrict__ x2v, const float* __restrict__ Lm,
    const float* __restrict__ x1, float* __restrict__ out0)
{
  __shared__ float part[8][4][4][64];
  __shared__ short plds[4][16][72];
  __shared__ float rl[4][16];
  const int tid = threadIdx.x, w = tid >> 6, lane = tid & 63;
  const int l15 = lane & 15, blk = lane >> 4;
  const int b = blockIdx.x / 196, n0 = (blockIdx.x % 196) * 16;

  bfr8 qa[4];
  #pragma unroll
  for (int ks = 0; ks < 4; ++ks)
    qa[ks] = *(const bfr8*)&q1t[((size_t)(b*3136) + n0 + l15)*128 + ks*32 + 8*blk];

  fx4 pacc[8];
  #pragma unroll
  for (int cf = 0; cf < 8; ++cf) pacc[cf] = fzero();
  float rsum[4] = {0.f, 0.f, 0.f, 0.f};

  for (int s = w; s < 49; s += 4){
    const int m0m = s*64;
    fx4 s4[4];
    #pragma unroll
    for (int mf = 0; mf < 4; ++mf) s4[mf] = fzero();
    #pragma unroll
    for (int ks = 0; ks < 4; ++ks){
      #pragma unroll
      for (int mf = 0; mf < 4; ++mf){
        bfr8 bq = *(const bfr8*)&q2t[((size_t)(b*3136) + m0m + mf*16 + l15)*128 + ks*32 + 8*blk];
        s4[mf] = MFMA16(qa[ks], bq, s4[mf]);
      }
    }
    #pragma unroll
    for (int mf = 0; mf < 4; ++mf){
      float Lv = Lm[b*3136 + m0m + mf*16 + l15];
      #pragma unroll
      for (int rr = 0; rr < 4; ++rr){
        float a1 = __expf(s4[mf][rr] - Lv);
        float p  = __expf(a1);
        rsum[rr] += p;
        plds[w][4*blk + rr][mf*16 + l15] = f2bf(p);
      }
    }
    #pragma unroll
    for (int ks2 = 0; ks2 < 2; ++ks2){
      bfr8 pb = *(const bfr8*)&plds[w][l15][ks2*32 + 8*blk];
      #pragma unroll
      for (int cf = 0; cf < 8; ++cf){
        bfr8 av = *(const bfr8*)&x2v[((size_t)(b*128) + cf*16 + l15)*3136 + m0m + ks2*32 + 8*blk];
        pacc[cf] = MFMA16(av, pb, pacc[cf]);
      }
    }
  }
  #pragma unroll
  for (int d = 1; d < 16; d <<= 1){
    #pragma unroll
    for (int rr = 0; rr < 4; ++rr) rsum[rr] += __shfl_xor(rsum[rr], d);
  }
  if (l15 == 0){
    #pragma unroll
    for (int rr = 0; rr < 4; ++rr) rl[w][4*blk + rr] = rsum[rr];
  }
  #pragma unroll
  for (int cf = 0; cf < 8; ++cf)
    #pragma unroll
    for (int rr = 0; rr < 4; ++rr)
      part[cf][rr][w][lane] = pacc[cf][rr];
  __syncthreads();

  float rtot = rl[0][l15] + rl[1][l15] + rl[2][l15] + rl[3][l15];
  float rinv = 1.0f / rtot;
  const int n = n0 + l15;
  #pragma unroll
  for (int i = 0; i < 2; ++i){
    int cf = 2*w + i;
    #pragma unroll
    for (int rr = 0; rr < 4; ++rr){
      float v = part[cf][rr][0][lane] + part[cf][rr][1][lane]
              + part[cf][rr][2][lane] + part[cf][rr][3][lane];
      int c = cf*16 + 4*blk + rr;
      size_t idx = (size_t)(b*128 + c)*3136 + n;
      out0[idx] = v*rinv + x1[idx];
    }
  }
}

// ---------------------------------------------------------------------------
extern "C" void kernel_launch(void* const* d_in, const int* in_sizes, int n_in,
                              void* d_out, int out_size, void* d_ws, size_t ws_size,
                              hipStream_t stream)
{
  (void)in_sizes; (void)n_in; (void)out_size;
  const float* x1     = (const float*)d_in[0];
  const float* x2     = (const float*)d_in[1];
  const float* wsw    = (const float*)d_in[2];
  const float* bs     = (const float*)d_in[3];
  const float* sg     = (const float*)d_in[4];
  const float* sbeta  = (const float*)d_in[5];
  const float* smean  = (const float*)d_in[6];
  const float* svar   = (const float*)d_in[7];
  const float* wq1    = (const float*)d_in[8];
  const float* wq2    = (const float*)d_in[9];
  // d_in[10..15]: v1 conv_block params -> dead code, unused
  const float* v2w    = (const float*)d_in[16];
  const float* v2bias = (const float*)d_in[17];
  const float* v2g    = (const float*)d_in[18];
  const float* v2beta = (const float*)d_in[19];
  const float* v2mean = (const float*)d_in[20];
  const float* v2var  = (const float*)d_in[21];

  char* ws = (char*)d_ws;
  auto al = [](size_t x){ return (x + 255) & ~(size_t)255; };

  const size_t sz_nc    = al((size_t)1605632*2);
  const size_t sz_x2bf  = al((size_t)6422528*2);
  const size_t sz_Lm    = al((size_t)12544*4);
  const size_t sz_part  = al((size_t)4*49*3136*4);
  const size_t sz_cst   = al((size_t)768*4);
  const size_t sz_S     = al((size_t)4*3136*3136*2);
  const size_t sz_wsbf  = al((size_t)589824*2);
  const size_t sz_wv2   = al((size_t)147456*2);
  const size_t sz_wq    = al((size_t)16384*2);
  const size_t sz_pbuf  = al((size_t)2*1605632*4);

  short *x2bf, *x1T, *wsbf, *wv2a, *wv2b, *wq1b, *wq2b;
  short *x2s, *x2sT, *q1t, *q2t, *v2t, *x2v, *Sbuf = nullptr;
  float *consts, *Lm, *pmax = nullptr, *psum = nullptr, *pbuf = nullptr;

  size_t off = 0;
  const size_t o_x2v = off;  off += sz_nc;
  const size_t o_q1t = off;  off += sz_nc;
  const size_t o_q2t = off;  off += sz_nc;
  const size_t o_Lm  = off;  off += sz_Lm;
  const size_t o_pmx = off;  off += sz_part;
  const size_t o_psm = off;  off += sz_part;
  const size_t o_cst = off;  off += sz_cst;
  const size_t o_S   = off;  off += sz_S;
  const size_t fast_need = off;
  const bool fast = (ws_size >= fast_need);

  if (fast){
    x2v    = (short*)(ws + o_x2v);
    q1t    = (short*)(ws + o_q1t);
    q2t    = (short*)(ws + o_q2t);
    Lm     = (float*)(ws + o_Lm);
    pmax   = (float*)(ws + o_pmx);
    psum   = (float*)(ws + o_psm);
    consts = (float*)(ws + o_cst);
    Sbuf   = (short*)(ws + o_S);
    size_t t = o_S;  // transients are dead before qk_kernel writes S
    x2bf = (short*)(ws + t); t += sz_x2bf;
    x1T  = (short*)(ws + t); t += sz_nc;
    x2sT = (short*)(ws + t); t += sz_nc;
    x2s  = (short*)(ws + t); t += sz_nc;
    v2t  = (short*)(ws + t); t += sz_nc;
    wsbf = (short*)(ws + t); t += sz_wsbf;
    wv2a = (short*)(ws + t); t += sz_wv2;
    wv2b = (short*)(ws + t); t += sz_wv2;
    wq1b = (short*)(ws + t); t += sz_wq;
    wq2b = (short*)(ws + t); t += sz_wq;
    pbuf = (float*)(ws + t); t += sz_pbuf;
  } else {
    size_t o = 0;
    auto bump = [&](size_t bytes)->char*{ char* p = ws + o; o += al(bytes); return p; };
    x2bf   = (short*)bump((size_t)6422528*2);
    x1T    = (short*)bump((size_t)1605632*2);
    wsbf   = (short*)bump((size_t)589824*2);
    wv2a   = (short*)bump((size_t)147456*2);
    wv2b   = (short*)bump((size_t)147456*2);
    wq1b   = (short*)bump((size_t)16384*2);
    wq2b   = (short*)bump((size_t)16384*2);
    consts = (float*)bump((size_t)768*4);
    x2s    = (short*)bump((size_t)1605632*2);
    x2sT   = (short*)bump((size_t)1605632*2);
    q1t    = (short*)bump((size_t)1605632*2);
    q2t    = (short*)bump((size_t)1605632*2);
    v2t    = (short*)bump((size_t)1605632*2);
    x2v    = (short*)bump((size_t)1605632*2);
    Lm     = (float*)bump((size_t)12544*4);
  }

  float* out0 = (float*)d_out;
  float* out1 = out0 + 1605632;

  prep_kernel<<<2048, 256, 0, stream>>>(x1, x2, wsw, bs, sg, sbeta, smean, svar,
      wq1, wq2, v2w, v2bias, v2g, v2beta, v2mean, v2var,
      x2bf, x1T, wsbf, wv2a, wv2b, wq1b, wq2b, consts, out1);

  if (fast){
    conv3x3_split_kernel<512, 8><<<dim3(224,2), 256, 0, stream>>>(x2bf, wsbf, pbuf);
    conv_combine_kernel<true ><<<392, 256, 0, stream>>>(pbuf, consts,       consts + 128, x2s, x2sT);
    qproj_kernel<<<784, 256, 0, stream>>>(x1T,  wq1b, q1t);
    qproj_kernel<<<784, 256, 0, stream>>>(x2sT, wq2b, q2t);
    conv3x3_split_kernel<128, 2><<<dim3(224,2), 256, 0, stream>>>(x2s, wv2a, pbuf);
    conv_combine_kernel<false><<<392, 256, 0, stream>>>(pbuf, consts + 256, consts + 384, v2t, nullptr);
    conv3x3_split_kernel<128, 2><<<dim3(224,2), 256, 0, stream>>>(v2t, wv2b, pbuf);
    conv_combine_kernel<false><<<392, 256, 0, stream>>>(pbuf, consts + 512, consts + 640, x2v, nullptr);
    qk_kernel<<<2500, 256, 0, stream>>>(q1t, q2t, Sbuf, pmax, psum);
    lse_merge_kernel<<<49, 256, 0, stream>>>(pmax, psum, Lm);
    attn2_kernel<<<784, 256, 0, stream>>>(Sbuf, x2v, Lm, x1, out0);
  } else {
    conv3x3_kernel<512, true ><<<224, 256, 0, stream>>>(x2bf, wsbf, consts, consts + 128, x2s, x2sT);
    qproj_kernel<<<784, 256, 0, stream>>>(x1T,  wq1b, q1t);
    qproj_kernel<<<784, 256, 0, stream>>>(x2sT, wq2b, q2t);
    conv3x3_kernel<128, false><<<224, 256, 0, stream>>>(x2s, wv2a, consts + 256, consts + 384, v2t, nullptr);
    conv3x3_kernel<128, false><<<224, 256, 0, stream>>>(v2t, wv2b, consts + 512, consts + 640, x2v, nullptr);
    colstats_kernel<<<784, 256, 0, stream>>>(q1t, q2t, Lm);
    attn_kernel<<<784, 256, 0, stream>>>(q1t, q2t, x2v, Lm, x1, out0);
  }
}

// Round 5
// 264.659 us; speedup vs baseline: 1.9397x; 1.0972x over previous
//
#include <hip/hip_runtime.h>
#include <cstdint>
#include <cstddef>

using bfr8 = __attribute__((ext_vector_type(8))) short;   // 8 bf16 (4 VGPRs)
using sh4  = __attribute__((ext_vector_type(4))) short;
using fx4  = __attribute__((ext_vector_type(4))) float;

#define DI __device__ __forceinline__
#define MFMA16(a,b,c) __builtin_amdgcn_mfma_f32_16x16x32_bf16((a),(b),(c),0,0,0)

DI short f2bf(float f){
  unsigned u = __float_as_uint(f);
  return (short)((u + 0x7fffu + ((u >> 16) & 1u)) >> 16);
}
DI float bf2f(short s){
  return __uint_as_float(((unsigned)(unsigned short)s) << 16);
}
DI fx4 fzero(){ fx4 z; z[0]=0.f; z[1]=0.f; z[2]=0.f; z[3]=0.f; return z; }

// ---------------------------------------------------------------------------
// prep: dtype conversions, weight re-layout [co][tap][ci], BN folding,
//       x1 transpose [b][n][c], and the out1 = x2 copy.
// ---------------------------------------------------------------------------
__global__ void prep_kernel(
    const float* __restrict__ x1, const float* __restrict__ x2,
    const float* __restrict__ wsw, const float* __restrict__ bs,
    const float* __restrict__ sg, const float* __restrict__ sbeta,
    const float* __restrict__ smean, const float* __restrict__ svar,
    const float* __restrict__ wq1, const float* __restrict__ wq2,
    const float* __restrict__ v2w, const float* __restrict__ v2bias,
    const float* __restrict__ v2g, const float* __restrict__ v2beta,
    const float* __restrict__ v2mean, const float* __restrict__ v2var,
    short* __restrict__ x2bf, short* __restrict__ x1T,
    short* __restrict__ wsbf, short* __restrict__ wv2a, short* __restrict__ wv2b,
    short* __restrict__ wq1b, short* __restrict__ wq2b,
    float* __restrict__ consts, float* __restrict__ out1copy)
{
  const int gsz = gridDim.x * blockDim.x;
  const int gid = blockIdx.x * blockDim.x + threadIdx.x;

  for (int i = gid; i < 1605632; i += gsz){
    float4 v = ((const float4*)x2)[i];
    ((float4*)out1copy)[i] = v;
    sh4 o; o[0]=f2bf(v.x); o[1]=f2bf(v.y); o[2]=f2bf(v.z); o[3]=f2bf(v.w);
    ((sh4*)x2bf)[i] = o;
  }
  for (int t = gid; t < 200704; t += gsz){
    int g = t & 15; int nn = t >> 4;
    int b = nn / 3136, n = nn - b*3136;
    bfr8 o;
    #pragma unroll
    for (int k = 0; k < 8; ++k)
      o[k] = f2bf(x1[(size_t)(b*128 + g*8 + k)*3136 + n]);
    *(bfr8*)&x1T[((size_t)(b*3136) + n)*128 + g*8] = o;
  }
  for (int i = gid; i < 589824; i += gsz){
    int ci = i & 511; int tap = (i >> 9) % 9; int co = i / 4608;
    wsbf[i] = f2bf(wsw[(size_t)(co*512 + ci)*9 + tap]);
  }
  for (int i = gid; i < 294912; i += gsz){
    int s = i / 147456; int r = i - s*147456;
    int ci = r & 127; int tap = (r >> 7) % 9; int co = r / 1152;
    float v = v2w[(size_t)((s*128 + co)*128 + ci)*9 + tap];
    (s ? wv2b : wv2a)[r] = f2bf(v);
  }
  for (int i = gid; i < 16384; i += gsz){
    wq1b[i] = f2bf(wq1[i]); wq2b[i] = f2bf(wq2[i]);
  }
  for (int c = gid; c < 128; c += gsz){
    float a = sg[c] * rsqrtf(svar[c] + 1e-5f);
    consts[c]       = a;
    consts[128 + c] = (bs[c] - smean[c]) * a + sbeta[c];
    float a0 = v2g[c] * rsqrtf(v2var[c] + 1e-5f);
    consts[256 + c] = a0;
    consts[384 + c] = (v2bias[c] - v2mean[c]) * a0 + v2beta[c];
    float a1 = v2g[128+c] * rsqrtf(v2var[128+c] + 1e-5f);
    consts[512 + c] = a1;
    consts[640 + c] = (v2bias[128+c] - v2mean[128+c]) * a1 + v2beta[128+c];
  }
}

// ---------------------------------------------------------------------------
// FAST PATH conv: split-K conv3x3 (pad=1), raw f32 partials (no BN).
// ---------------------------------------------------------------------------
template<int CIN, int NCIB>
__global__ __launch_bounds__(256, 2) void conv3x3_split_kernel(
    const short* __restrict__ xin, const short* __restrict__ wt,
    float* __restrict__ pout)
{
  __shared__ short xs[4*58*40];
  __shared__ short wsh[9*64*40];

  const int tid = threadIdx.x;
  const int w = tid >> 6, lane = tid & 63, l15 = lane & 15, blk = lane >> 4;
  const int bid = blockIdx.x;
  const int rt = bid % 28, cog = (bid / 28) & 1, b = bid / 56;
  const int r0 = rt * 2;
  const int split = blockIdx.y;
  const int cib0 = split * NCIB;
  float* pbase = pout + (size_t)split * 1605632;

  int pixoff[7];
  #pragma unroll
  for (int pf = 0; pf < 7; ++pf){
    int p = pf*16 + l15;
    int pr = (p >= 56) ? 1 : 0;
    int pc = p - pr*56;
    pixoff[pf] = (pr*58 + pc)*40 + 8*blk;
  }
  const int wlo = (w*16 + l15)*40 + 8*blk;

  fx4 acc[7];
  #pragma unroll
  for (int pf = 0; pf < 7; ++pf) acc[pf] = fzero();

  for (int ci = 0; ci < NCIB; ++ci){
    const int cib = cib0 + ci;
    __syncthreads();
    #pragma unroll
    for (int it = 0; it < 4; ++it){
      int q = it*256 + tid;
      if (q < 928){
        int col = q % 58; int cg8 = (q/58) & 3; int r = q / 232;
        int grow = r0 - 1 + r;
        int gcol = col - 1;
        bfr8 v;
        if (grow >= 0 && grow < 56 && gcol >= 0 && gcol < 56){
          #pragma unroll
          for (int k = 0; k < 8; ++k)
            v[k] = xin[(size_t)(b*CIN + cib*32 + cg8*8 + k)*3136 + grow*56 + gcol];
        } else {
          #pragma unroll
          for (int k = 0; k < 8; ++k) v[k] = 0;
        }
        *(bfr8*)&xs[(r*58 + col)*40 + cg8*8] = v;
      }
    }
    #pragma unroll
    for (int it = 0; it < 9; ++it){
      int q = it*256 + tid;
      int jj = q & 3; int tap = (q >> 2) % 9; int co = q / 36;
      bfr8 wv = *(const bfr8*)&wt[(size_t)((cog*64 + co)*9 + tap)*CIN + cib*32 + jj*8];
      *(bfr8*)&wsh[(tap*64 + co)*40 + jj*8] = wv;
    }
    __syncthreads();
    #pragma unroll
    for (int tap = 0; tap < 9; ++tap){
      bfr8 af = *(const bfr8*)&wsh[tap*64*40 + wlo];
      const int toff = ((tap/3)*58 + (tap%3))*40;
      #pragma unroll
      for (int pf = 0; pf < 7; ++pf){
        bfr8 bf = *(const bfr8*)&xs[pixoff[pf] + toff];
        acc[pf] = MFMA16(af, bf, acc[pf]);
      }
    }
  }
  #pragma unroll
  for (int rr = 0; rr < 4; ++rr){
    int co = cog*64 + w*16 + 4*blk + rr;
    #pragma unroll
    for (int pf = 0; pf < 7; ++pf){
      int n = r0*56 + pf*16 + l15;
      pbase[(size_t)(b*128 + co)*3136 + n] = acc[pf][rr];
    }
  }
}

// ---------------------------------------------------------------------------
// combine: y = relu((p0+p1)*alpha + bc) -> bf16, plus optional transpose.
// ---------------------------------------------------------------------------
template<bool TSTORE>
__global__ __launch_bounds__(256, 4) void conv_combine_kernel(
    const float* __restrict__ p, const float* __restrict__ alpha,
    const float* __restrict__ bconst,
    short* __restrict__ yout, short* __restrict__ youtT)
{
  __shared__ short lt[64][66];
  const int t = threadIdx.x;
  const int bid = blockIdx.x;
  const int nt = bid % 49, cog = (bid / 49) & 1, b = bid / 98;
  const int co0 = cog*64, n0 = nt*64;
  const int coL = t >> 4, ncL = (t & 15) * 4;

  #pragma unroll
  for (int rep = 0; rep < 4; ++rep){
    int co = co0 + rep*16 + coL;
    size_t base = ((size_t)(b*128) + co)*3136 + n0 + ncL;
    float4 a0 = *(const float4*)&p[base];
    float4 a1 = *(const float4*)&p[1605632 + base];
    float al = alpha[co], bc = bconst[co];
    sh4 o;
    o[0] = f2bf(fmaxf((a0.x+a1.x)*al + bc, 0.f));
    o[1] = f2bf(fmaxf((a0.y+a1.y)*al + bc, 0.f));
    o[2] = f2bf(fmaxf((a0.z+a1.z)*al + bc, 0.f));
    o[3] = f2bf(fmaxf((a0.w+a1.w)*al + bc, 0.f));
    *(sh4*)&yout[base] = o;
    if (TSTORE) *(sh4*)&lt[rep*16 + coL][ncL] = o;
  }
  if (TSTORE){
    __syncthreads();
    #pragma unroll
    for (int rep = 0; rep < 4; ++rep){
      int nn = rep*16 + (t >> 4);
      int coc = (t & 15) * 4;
      sh4 v;
      #pragma unroll
      for (int j = 0; j < 4; ++j) v[j] = lt[coc + j][nn];
      *(sh4*)&youtT[((size_t)(b*3136) + n0 + nn)*128 + co0 + coc] = v;
    }
  }
}

// ---------------------------------------------------------------------------
// FALLBACK conv: conv3x3 + BN + ReLU fused.
// ---------------------------------------------------------------------------
template<int CIN, bool TSTORE>
__global__ __launch_bounds__(256, 2) void conv3x3_kernel(
    const short* __restrict__ xin, const short* __restrict__ wt,
    const float* __restrict__ alpha, const float* __restrict__ bconst,
    short* __restrict__ yout, short* __restrict__ youtT)
{
  __shared__ short xs[4*58*40];
  __shared__ short wsh[9*64*40];

  const int tid = threadIdx.x;
  const int w = tid >> 6, lane = tid & 63, l15 = lane & 15, blk = lane >> 4;
  const int bid = blockIdx.x;
  const int rt = bid % 28, cog = (bid / 28) & 1, b = bid / 56;
  const int r0 = rt * 2;

  int pixoff[7];
  #pragma unroll
  for (int pf = 0; pf < 7; ++pf){
    int p = pf*16 + l15;
    int pr = (p >= 56) ? 1 : 0;
    int pc = p - pr*56;
    pixoff[pf] = (pr*58 + pc)*40 + 8*blk;
  }
  const int wlo = (w*16 + l15)*40 + 8*blk;

  fx4 acc[7];
  #pragma unroll
  for (int pf = 0; pf < 7; ++pf) acc[pf] = fzero();

  for (int cib = 0; cib < CIN/32; ++cib){
    __syncthreads();
    #pragma unroll
    for (int it = 0; it < 4; ++it){
      int q = it*256 + tid;
      if (q < 928){
        int col = q % 58; int cg8 = (q/58) & 3; int r = q / 232;
        int grow = r0 - 1 + r;
        int gcol = col - 1;
        bfr8 v;
        if (grow >= 0 && grow < 56 && gcol >= 0 && gcol < 56){
          #pragma unroll
          for (int k = 0; k < 8; ++k)
            v[k] = xin[(size_t)(b*CIN + cib*32 + cg8*8 + k)*3136 + grow*56 + gcol];
        } else {
          #pragma unroll
          for (int k = 0; k < 8; ++k) v[k] = 0;
        }
        *(bfr8*)&xs[(r*58 + col)*40 + cg8*8] = v;
      }
    }
    #pragma unroll
    for (int it = 0; it < 9; ++it){
      int q = it*256 + tid;
      int jj = q & 3; int tap = (q >> 2) % 9; int co = q / 36;
      bfr8 wv = *(const bfr8*)&wt[(size_t)((cog*64 + co)*9 + tap)*CIN + cib*32 + jj*8];
      *(bfr8*)&wsh[(tap*64 + co)*40 + jj*8] = wv;
    }
    __syncthreads();
    #pragma unroll
    for (int tap = 0; tap < 9; ++tap){
      bfr8 af = *(const bfr8*)&wsh[tap*64*40 + wlo];
      const int toff = ((tap/3)*58 + (tap%3))*40;
      #pragma unroll
      for (int pf = 0; pf < 7; ++pf){
        bfr8 bf = *(const bfr8*)&xs[pixoff[pf] + toff];
        acc[pf] = MFMA16(af, bf, acc[pf]);
      }
    }
  }
  #pragma unroll
  for (int rr = 0; rr < 4; ++rr){
    int co = cog*64 + w*16 + 4*blk + rr;
    float al = alpha[co], bc = bconst[co];
    #pragma unroll
    for (int pf = 0; pf < 7; ++pf){
      float v = fmaxf(acc[pf][rr]*al + bc, 0.f);
      short sv = f2bf(v);
      int n = r0*56 + pf*16 + l15;
      yout[(size_t)(b*128 + co)*3136 + n] = sv;
      if (TSTORE) youtT[((size_t)(b*3136) + n)*128 + co] = sv;
    }
  }
}

// ---------------------------------------------------------------------------
// 1x1 conv: qt[b][n][co] = sum_ci wq[co][ci] * xT[b][n][ci]
// ---------------------------------------------------------------------------
__global__ __launch_bounds__(256, 4) void qproj_kernel(
    const short* __restrict__ xT, const short* __restrict__ wq,
    short* __restrict__ qt)
{
  const int tid = threadIdx.x, w = tid >> 6, lane = tid & 63;
  const int l15 = lane & 15, blk = lane >> 4;
  const int b = blockIdx.x / 196, n0 = (blockIdx.x % 196) * 16;

  fx4 acc[2];
  acc[0] = fzero(); acc[1] = fzero();

  #pragma unroll
  for (int ks = 0; ks < 4; ++ks){
    bfr8 af = *(const bfr8*)&xT[((size_t)(b*3136) + n0 + l15)*128 + ks*32 + 8*blk];
    #pragma unroll
    for (int i = 0; i < 2; ++i){
      bfr8 bf = *(const bfr8*)&wq[(size_t)((w*2 + i)*16 + l15)*128 + ks*32 + 8*blk];
      acc[i] = MFMA16(af, bf, acc[i]);
    }
  }
  #pragma unroll
  for (int i = 0; i < 2; ++i){
    #pragma unroll
    for (int rr = 0; rr < 4; ++rr){
      int n = n0 + 4*blk + rr;
      qt[((size_t)(b*3136) + n)*128 + (w*2 + i)*16 + l15] = f2bf(acc[i][rr]);
    }
  }
}

// ---------------------------------------------------------------------------
// FAST pass 1: per-(m, ns-range, wave) online lse of s[m][n]=q2[m,:].q1[n,:].
// A=q2 (m rows), B=q1 (n cols): s col = l15 = n.
// Grid: 4b x 49mt x 4ns = 784. Partials [b][ns][w] = [b*16+r][3136].
// ---------------------------------------------------------------------------
__global__ __launch_bounds__(256, 3) void lse_kernel(
    const short* __restrict__ q1t, const short* __restrict__ q2t,
    float* __restrict__ pmax, float* __restrict__ psum)
{
  const int tid = threadIdx.x, w = tid >> 6, lane = tid & 63;
  const int l15 = lane & 15, blk = lane >> 4;
  const int bid = blockIdx.x;
  const int ns = bid & 3, mt = (bid >> 2) % 49, b = bid / 196;
  const int m0 = mt*64;

  bfr8 qa[4][4];
  #pragma unroll
  for (int mf = 0; mf < 4; ++mf)
    #pragma unroll
    for (int ks = 0; ks < 4; ++ks)
      qa[mf][ks] = *(const bfr8*)&q2t[((size_t)(b*3136) + m0 + mf*16 + l15)*128 + ks*32 + 8*blk];

  float vmax[4][4], vsum[4][4];
  #pragma unroll
  for (int mf = 0; mf < 4; ++mf)
    #pragma unroll
    for (int rr = 0; rr < 4; ++rr){ vmax[mf][rr] = -1e30f; vsum[mf][rr] = 0.f; }

  bfr8 qb[4], qbn[4];
  #pragma unroll
  for (int ks = 0; ks < 4; ++ks)
    qb[ks] = *(const bfr8*)&q1t[((size_t)(b*3136) + ns*784 + w*16 + l15)*128 + ks*32 + 8*blk];

  for (int c = w; c < 49; c += 4){
    const int cn = c + 4;
    if (cn < 49){
      #pragma unroll
      for (int ks = 0; ks < 4; ++ks)
        qbn[ks] = *(const bfr8*)&q1t[((size_t)(b*3136) + ns*784 + cn*16 + l15)*128 + ks*32 + 8*blk];
    }
    fx4 acc[4];
    #pragma unroll
    for (int mf = 0; mf < 4; ++mf) acc[mf] = fzero();
    #pragma unroll
    for (int ks = 0; ks < 4; ++ks)
      #pragma unroll
      for (int mf = 0; mf < 4; ++mf)
        acc[mf] = MFMA16(qa[mf][ks], qb[ks], acc[mf]);
    #pragma unroll
    for (int mf = 0; mf < 4; ++mf)
      #pragma unroll
      for (int rr = 0; rr < 4; ++rr){
        float s = acc[mf][rr];
        float nm = fmaxf(vmax[mf][rr], s);
        vsum[mf][rr] = vsum[mf][rr]*__expf(vmax[mf][rr]-nm) + __expf(s-nm);
        vmax[mf][rr] = nm;
      }
    #pragma unroll
    for (int ks = 0; ks < 4; ++ks) qb[ks] = qbn[ks];
  }
  // merge across the 16 n-lanes (l15)
  #pragma unroll
  for (int d = 1; d < 16; d <<= 1){
    #pragma unroll
    for (int mf = 0; mf < 4; ++mf)
      #pragma unroll
      for (int rr = 0; rr < 4; ++rr){
        float om = __shfl_xor(vmax[mf][rr], d);
        float os = __shfl_xor(vsum[mf][rr], d);
        float M = fmaxf(vmax[mf][rr], om);
        vsum[mf][rr] = vsum[mf][rr]*__expf(vmax[mf][rr]-M) + os*__expf(om-M);
        vmax[mf][rr] = M;
      }
  }
  if (l15 == 0){
    const size_t base = ((size_t)(b*16 + ns*4 + w))*3136 + m0;
    #pragma unroll
    for (int mf = 0; mf < 4; ++mf)
      #pragma unroll
      for (int rr = 0; rr < 4; ++rr){
        pmax[base + mf*16 + 4*blk + rr] = vmax[mf][rr];
        psum[base + mf*16 + 4*blk + rr] = vsum[mf][rr];
      }
  }
}

// ---------------------------------------------------------------------------
// merge the 16 lse partials per (b,m) -> Lm
// ---------------------------------------------------------------------------
__global__ void lse_merge_kernel(
    const float* __restrict__ pmax, const float* __restrict__ psum,
    float* __restrict__ Lm)
{
  int t = blockIdx.x*256 + threadIdx.x;
  if (t >= 12544) return;
  int b = t / 3136, m = t - b*3136;
  float M = -1e30f;
  #pragma unroll
  for (int r = 0; r < 16; ++r)
    M = fmaxf(M, pmax[((size_t)(b*16 + r))*3136 + m]);
  float S = 0.f;
  #pragma unroll
  for (int r = 0; r < 16; ++r){
    size_t i = ((size_t)(b*16 + r))*3136 + m;
    S += psum[i]*__expf(pmax[i] - M);
  }
  Lm[t] = M + __logf(S);
}

// ---------------------------------------------------------------------------
// FAST pass 2: fused QK recompute + softmax + PV, m-split across blocks.
// Grid: 4b x 49nt x 7ms = 1372. Each wave owns 16 n; x2v chunk staged into
// padded LDS (T14 issue-early/write-late); per-wave plds P-transpose.
// Writes f32 PV partials + rowsum partials.
// ---------------------------------------------------------------------------
__global__ __launch_bounds__(256, 3) void attn3_kernel(
    const short* __restrict__ q1t, const short* __restrict__ q2t,
    const short* __restrict__ x2v, const float* __restrict__ Lm,
    float* __restrict__ part, float* __restrict__ rpart)
{
  __shared__ short xsh[128*72];       // x2v chunk [128c][64m +8 pad]
  __shared__ short plds[4*16*72];     // per-wave P tile [16n][64m +8 pad]
  __shared__ float lmsh[448];         // Lm for this m-range
  const int tid = threadIdx.x, w = tid >> 6, lane = tid & 63;
  const int l15 = lane & 15, blk = lane >> 4;
  const int bid = blockIdx.x;
  const int ms = bid % 7, nt = (bid / 7) % 49, b = bid / 343;
  const int m0 = ms*448;
  const int n0w = nt*64 + w*16;

  if (tid < 112)
    ((float4*)lmsh)[tid] = ((const float4*)(Lm + b*3136 + m0))[tid];

  // q1 fragments for this wave's 16 n (hoisted)
  bfr8 qb[4];
  #pragma unroll
  for (int ks = 0; ks < 4; ++ks)
    qb[ks] = *(const bfr8*)&q1t[((size_t)(b*3136) + n0w + l15)*128 + ks*32 + 8*blk];

  // issue x2v stage loads for chunk 0
  bfr8 st[4];
  #pragma unroll
  for (int u = 0; u < 4; ++u){
    int unit = tid + 256*u;
    int row = unit >> 3, ch = unit & 7;
    st[u] = *(const bfr8*)&x2v[((size_t)(b*128) + row)*3136 + m0 + ch*8];
  }

  fx4 pacc[8];
  #pragma unroll
  for (int cf = 0; cf < 8; ++cf) pacc[cf] = fzero();
  float rsum = 0.f;

  for (int c = 0; c < 7; ++c){
    __syncthreads();                 // prev chunk fully consumed
    #pragma unroll
    for (int u = 0; u < 4; ++u){
      int unit = tid + 256*u;
      int row = unit >> 3, ch = unit & 7;
      *(bfr8*)&xsh[row*72 + ch*8] = st[u];
    }
    if (c < 6){
      const int m0n = m0 + (c+1)*64;
      #pragma unroll
      for (int u = 0; u < 4; ++u){
        int unit = tid + 256*u;
        int row = unit >> 3, ch = unit & 7;
        st[u] = *(const bfr8*)&x2v[((size_t)(b*128) + row)*3136 + m0n + ch*8];
      }
    }
    __syncthreads();                 // xsh ready

    const int m0c = m0 + c*64;
    // QK: A = q2 (64 m), B = q1 (16 n)
    bfr8 qv[4][4];
    #pragma unroll
    for (int mf = 0; mf < 4; ++mf)
      #pragma unroll
      for (int ks = 0; ks < 4; ++ks)
        qv[mf][ks] = *(const bfr8*)&q2t[((size_t)(b*3136) + m0c + mf*16 + l15)*128 + ks*32 + 8*blk];
    fx4 acc[4];
    #pragma unroll
    for (int mf = 0; mf < 4; ++mf) acc[mf] = fzero();
    #pragma unroll
    for (int ks = 0; ks < 4; ++ks)
      #pragma unroll
      for (int mf = 0; mf < 4; ++mf)
        acc[mf] = MFMA16(qv[mf][ks], qb[ks], acc[mf]);

    // softmax: p = exp(exp(s - Lm[m])), write P^T tile to per-wave plds
    #pragma unroll
    for (int mf = 0; mf < 4; ++mf){
      sh4 pk;
      #pragma unroll
      for (int rr = 0; rr < 4; ++rr){
        float lmv = lmsh[c*64 + mf*16 + 4*blk + rr];
        float a1 = __expf(acc[mf][rr] - lmv);   // in (0,1]
        float p  = __expf(a1);                  // in (1,e]
        rsum += p;
        pk[rr] = f2bf(p);
      }
      *(sh4*)&plds[(w*16 + l15)*72 + mf*16 + 4*blk] = pk;
    }
    // PV: A = x2v rows c (LDS), B = P rows n (plds)
    #pragma unroll
    for (int ks2 = 0; ks2 < 2; ++ks2){
      bfr8 pb = *(const bfr8*)&plds[(w*16 + l15)*72 + ks2*32 + 8*blk];
      #pragma unroll
      for (int cf = 0; cf < 8; ++cf){
        bfr8 av = *(const bfr8*)&xsh[(cf*16 + l15)*72 + ks2*32 + 8*blk];
        pacc[cf] = MFMA16(av, pb, pacc[cf]);
      }
    }
  }

  // rowsum partial: all p of a lane belong to n = n0w + l15
  rsum += __shfl_xor(rsum, 16);
  rsum += __shfl_xor(rsum, 32);
  if (lane < 16)
    rpart[((size_t)(ms*4 + b))*3136 + n0w + l15] = rsum;

  // PV partial write
  #pragma unroll
  for (int cf = 0; cf < 8; ++cf)
    #pragma unroll
    for (int rr = 0; rr < 4; ++rr){
      int cc = cf*16 + 4*blk + rr;
      part[(((size_t)(ms*4 + b))*128 + cc)*3136 + n0w + l15] = pacc[cf][rr];
    }
}

// ---------------------------------------------------------------------------
// rtot: rinv[b][n] = 1 / sum_ms rpart
// ---------------------------------------------------------------------------
__global__ void rtot_kernel(const float* __restrict__ rpart,
                            float* __restrict__ rinv)
{
  int t = blockIdx.x*256 + threadIdx.x;
  if (t >= 12544) return;
  int b = t / 3136, n = t - b*3136;
  float s = 0.f;
  #pragma unroll
  for (int ms = 0; ms < 7; ++ms)
    s += rpart[((size_t)(ms*4 + b))*3136 + n];
  rinv[t] = 1.0f / s;
}

// ---------------------------------------------------------------------------
// attn combine: out0 = (sum_ms part)*rinv + x1
// ---------------------------------------------------------------------------
__global__ __launch_bounds__(256, 8) void attn_combine_kernel(
    const float* __restrict__ part, const float* __restrict__ rinv,
    const float* __restrict__ x1, float* __restrict__ out0)
{
  int t = blockIdx.x*256 + threadIdx.x;     // < 401408 float4 units
  int n4 = t % 784; int rest = t / 784;
  int cc = rest & 127; int b = rest >> 7;
  const float4* p4 = (const float4*)part;
  float4 s = {0.f,0.f,0.f,0.f};
  #pragma unroll
  for (int ms = 0; ms < 7; ++ms){
    float4 v = p4[(((size_t)(ms*4 + b))*128 + cc)*784 + n4];
    s.x += v.x; s.y += v.y; s.z += v.z; s.w += v.w;
  }
  float4 rv = ((const float4*)rinv)[b*784 + n4];
  size_t xi = ((size_t)(b*128) + cc)*784 + n4;
  float4 xv = ((const float4*)x1)[xi];
  float4 o;
  o.x = s.x*rv.x + xv.x; o.y = s.y*rv.y + xv.y;
  o.z = s.z*rv.z + xv.z; o.w = s.w*rv.w + xv.w;
  ((float4*)out0)[xi] = o;
}

// ---------------------------------------------------------------------------
// FALLBACK PATH (ws too small): R2 colstats + attn
// ---------------------------------------------------------------------------
__global__ __launch_bounds__(256, 2) void colstats_kernel(
    const short* __restrict__ q1t, const short* __restrict__ q2t,
    float* __restrict__ Lm)
{
  __shared__ float smax[4][16];
  __shared__ float ssum[4][16];
  const int tid = threadIdx.x, w = tid >> 6, lane = tid & 63;
  const int l15 = lane & 15, blk = lane >> 4;
  const int b = blockIdx.x / 196, m0 = (blockIdx.x % 196) * 16;

  bfr8 bfr[4];
  #pragma unroll
  for (int ks = 0; ks < 4; ++ks)
    bfr[ks] = *(const bfr8*)&q2t[((size_t)(b*3136) + m0 + l15)*128 + ks*32 + 8*blk];

  float vmax = -1e30f, vsum = 0.f;

  for (int nc = w; nc < 196; nc += 4){
    fx4 acc = fzero();
    #pragma unroll
    for (int ks = 0; ks < 4; ++ks){
      bfr8 af = *(const bfr8*)&q1t[((size_t)(b*3136) + nc*16 + l15)*128 + ks*32 + 8*blk];
      acc = MFMA16(af, bfr[ks], acc);
    }
    float cm = fmaxf(fmaxf(acc[0], acc[1]), fmaxf(acc[2], acc[3]));
    float nm = fmaxf(vmax, cm);
    float cs = __expf(acc[0]-nm) + __expf(acc[1]-nm)
             + __expf(acc[2]-nm) + __expf(acc[3]-nm);
    vsum = vsum*__expf(vmax-nm) + cs;
    vmax = nm;
  }
  #pragma unroll
  for (int d = 16; d < 64; d <<= 1){
    float om = __shfl_xor(vmax, d);
    float os = __shfl_xor(vsum, d);
    float M = fmaxf(vmax, om);
    vsum = vsum*__expf(vmax - M) + os*__expf(om - M);
    vmax = M;
  }
  if (lane < 16){ smax[w][lane] = vmax; ssum[w][lane] = vsum; }
  __syncthreads();
  if (tid < 16){
    float M = fmaxf(fmaxf(smax[0][tid], smax[1][tid]), fmaxf(smax[2][tid], smax[3][tid]));
    float S = ssum[0][tid]*__expf(smax[0][tid]-M) + ssum[1][tid]*__expf(smax[1][tid]-M)
            + ssum[2][tid]*__expf(smax[2][tid]-M) + ssum[3][tid]*__expf(smax[3][tid]-M);
    Lm[b*3136 + m0 + tid] = M + __logf(S);
  }
}

__global__ __launch_bounds__(256, 2) void attn_kernel(
    const short* __restrict__ q1t, const short* __restrict__ q2t,
    const short* __restrict__ x2v, const float* __restrict__ Lm,
    const float* __restrict__ x1, float* __restrict__ out0)
{
  __shared__ float part[8][4][4][64];
  __shared__ short plds[4][16][72];
  __shared__ float rl[4][16];
  const int tid = threadIdx.x, w = tid >> 6, lane = tid & 63;
  const int l15 = lane & 15, blk = lane >> 4;
  const int b = blockIdx.x / 196, n0 = (blockIdx.x % 196) * 16;

  bfr8 qa[4];
  #pragma unroll
  for (int ks = 0; ks < 4; ++ks)
    qa[ks] = *(const bfr8*)&q1t[((size_t)(b*3136) + n0 + l15)*128 + ks*32 + 8*blk];

  fx4 pacc[8];
  #pragma unroll
  for (int cf = 0; cf < 8; ++cf) pacc[cf] = fzero();
  float rsum[4] = {0.f, 0.f, 0.f, 0.f};

  for (int s = w; s < 49; s += 4){
    const int m0m = s*64;
    fx4 s4[4];
    #pragma unroll
    for (int mf = 0; mf < 4; ++mf) s4[mf] = fzero();
    #pragma unroll
    for (int ks = 0; ks < 4; ++ks){
      #pragma unroll
      for (int mf = 0; mf < 4; ++mf){
        bfr8 bq = *(const bfr8*)&q2t[((size_t)(b*3136) + m0m + mf*16 + l15)*128 + ks*32 + 8*blk];
        s4[mf] = MFMA16(qa[ks], bq, s4[mf]);
      }
    }
    #pragma unroll
    for (int mf = 0; mf < 4; ++mf){
      float Lv = Lm[b*3136 + m0m + mf*16 + l15];
      #pragma unroll
      for (int rr = 0; rr < 4; ++rr){
        float a1 = __expf(s4[mf][rr] - Lv);
        float p  = __expf(a1);
        rsum[rr] += p;
        plds[w][4*blk + rr][mf*16 + l15] = f2bf(p);
      }
    }
    #pragma unroll
    for (int ks2 = 0; ks2 < 2; ++ks2){
      bfr8 pb = *(const bfr8*)&plds[w][l15][ks2*32 + 8*blk];
      #pragma unroll
      for (int cf = 0; cf < 8; ++cf){
        bfr8 av = *(const bfr8*)&x2v[((size_t)(b*128) + cf*16 + l15)*3136 + m0m + ks2*32 + 8*blk];
        pacc[cf] = MFMA16(av, pb, pacc[cf]);
      }
    }
  }
  #pragma unroll
  for (int d = 1; d < 16; d <<= 1){
    #pragma unroll
    for (int rr = 0; rr < 4; ++rr) rsum[rr] += __shfl_xor(rsum[rr], d);
  }
  if (l15 == 0){
    #pragma unroll
    for (int rr = 0; rr < 4; ++rr) rl[w][4*blk + rr] = rsum[rr];
  }
  #pragma unroll
  for (int cf = 0; cf < 8; ++cf)
    #pragma unroll
    for (int rr = 0; rr < 4; ++rr)
      part[cf][rr][w][lane] = pacc[cf][rr];
  __syncthreads();

  float rtot = rl[0][l15] + rl[1][l15] + rl[2][l15] + rl[3][l15];
  float rinv = 1.0f / rtot;
  const int n = n0 + l15;
  #pragma unroll
  for (int i = 0; i < 2; ++i){
    int cf = 2*w + i;
    #pragma unroll
    for (int rr = 0; rr < 4; ++rr){
      float v = part[cf][rr][0][lane] + part[cf][rr][1][lane]
              + part[cf][rr][2][lane] + part[cf][rr][3][lane];
      int c = cf*16 + 4*blk + rr;
      size_t idx = (size_t)(b*128 + c)*3136 + n;
      out0[idx] = v*rinv + x1[idx];
    }
  }
}

// ---------------------------------------------------------------------------
extern "C" void kernel_launch(void* const* d_in, const int* in_sizes, int n_in,
                              void* d_out, int out_size, void* d_ws, size_t ws_size,
                              hipStream_t stream)
{
  (void)in_sizes; (void)n_in; (void)out_size;
  const float* x1     = (const float*)d_in[0];
  const float* x2     = (const float*)d_in[1];
  const float* wsw    = (const float*)d_in[2];
  const float* bs     = (const float*)d_in[3];
  const float* sg     = (const float*)d_in[4];
  const float* sbeta  = (const float*)d_in[5];
  const float* smean  = (const float*)d_in[6];
  const float* svar   = (const float*)d_in[7];
  const float* wq1    = (const float*)d_in[8];
  const float* wq2    = (const float*)d_in[9];
  // d_in[10..15]: v1 conv_block params -> dead code, unused
  const float* v2w    = (const float*)d_in[16];
  const float* v2bias = (const float*)d_in[17];
  const float* v2g    = (const float*)d_in[18];
  const float* v2beta = (const float*)d_in[19];
  const float* v2mean = (const float*)d_in[20];
  const float* v2var  = (const float*)d_in[21];

  char* ws = (char*)d_ws;
  auto al = [](size_t x){ return (x + 255) & ~(size_t)255; };

  const size_t sz_nc    = al((size_t)1605632*2);
  const size_t sz_x2bf  = al((size_t)6422528*2);
  const size_t sz_Lm    = al((size_t)12544*4);
  const size_t sz_lsep  = al((size_t)16*12544*4);
  const size_t sz_rp    = al((size_t)28*12544*4);
  const size_t sz_cst   = al((size_t)768*4);
  const size_t sz_part  = al((size_t)7*1605632*4);
  const size_t sz_wsbf  = al((size_t)589824*2);
  const size_t sz_wv2   = al((size_t)147456*2);
  const size_t sz_wq    = al((size_t)16384*2);

  short *x2bf, *x1T, *wsbf, *wv2a, *wv2b, *wq1b, *wq2b;
  short *x2s, *x2sT, *q1t, *q2t, *v2t, *x2v;
  float *consts, *Lm;
  float *pmax = nullptr, *psum = nullptr, *part = nullptr;
  float *rpart = nullptr, *rinv = nullptr, *pbuf = nullptr;

  size_t off = 0;
  const size_t o_x2v = off;  off += sz_nc;
  const size_t o_q1t = off;  off += sz_nc;
  const size_t o_q2t = off;  off += sz_nc;
  const size_t o_Lm  = off;  off += sz_Lm;
  const size_t o_pmx = off;  off += sz_lsep;
  const size_t o_psm = off;  off += sz_lsep;
  const size_t o_rp  = off;  off += sz_rp;
  const size_t o_ri  = off;  off += sz_Lm;
  const size_t o_cst = off;  off += sz_cst;
  const size_t o_prt = off;  off += sz_part;   // pbuf overlays part
  const size_t o_x2b = off;  off += sz_x2bf;
  const size_t o_x1T = off;  off += sz_nc;
  const size_t o_xsT = off;  off += sz_nc;
  const size_t o_x2s = off;  off += sz_nc;
  const size_t o_v2t = off;  off += sz_nc;
  const size_t o_wsb = off;  off += sz_wsbf;
  const size_t o_wva = off;  off += sz_wv2;
  const size_t o_wvb = off;  off += sz_wv2;
  const size_t o_wq1 = off;  off += sz_wq;
  const size_t o_wq2 = off;  off += sz_wq;
  const size_t fast_need = off;
  const bool fast = (ws_size >= fast_need);

  if (fast){
    x2v    = (short*)(ws + o_x2v);
    q1t    = (short*)(ws + o_q1t);
    q2t    = (short*)(ws + o_q2t);
    Lm     = (float*)(ws + o_Lm);
    pmax   = (float*)(ws + o_pmx);
    psum   = (float*)(ws + o_psm);
    rpart  = (float*)(ws + o_rp);
    rinv   = (float*)(ws + o_ri);
    consts = (float*)(ws + o_cst);
    part   = (float*)(ws + o_prt);
    pbuf   = (float*)(ws + o_prt);
    x2bf   = (short*)(ws + o_x2b);
    x1T    = (short*)(ws + o_x1T);
    x2sT   = (short*)(ws + o_xsT);
    x2s    = (short*)(ws + o_x2s);
    v2t    = (short*)(ws + o_v2t);
    wsbf   = (short*)(ws + o_wsb);
    wv2a   = (short*)(ws + o_wva);
    wv2b   = (short*)(ws + o_wvb);
    wq1b   = (short*)(ws + o_wq1);
    wq2b   = (short*)(ws + o_wq2);
  } else {
    size_t o = 0;
    auto bump = [&](size_t bytes)->char*{ char* p = ws + o; o += al(bytes); return p; };
    x2bf   = (short*)bump((size_t)6422528*2);
    x1T    = (short*)bump((size_t)1605632*2);
    wsbf   = (short*)bump((size_t)589824*2);
    wv2a   = (short*)bump((size_t)147456*2);
    wv2b   = (short*)bump((size_t)147456*2);
    wq1b   = (short*)bump((size_t)16384*2);
    wq2b   = (short*)bump((size_t)16384*2);
    consts = (float*)bump((size_t)768*4);
    x2s    = (short*)bump((size_t)1605632*2);
    x2sT   = (short*)bump((size_t)1605632*2);
    q1t    = (short*)bump((size_t)1605632*2);
    q2t    = (short*)bump((size_t)1605632*2);
    v2t    = (short*)bump((size_t)1605632*2);
    x2v    = (short*)bump((size_t)1605632*2);
    Lm     = (float*)bump((size_t)12544*4);
  }

  float* out0 = (float*)d_out;
  float* out1 = out0 + 1605632;

  prep_kernel<<<2048, 256, 0, stream>>>(x1, x2, wsw, bs, sg, sbeta, smean, svar,
      wq1, wq2, v2w, v2bias, v2g, v2beta, v2mean, v2var,
      x2bf, x1T, wsbf, wv2a, wv2b, wq1b, wq2b, consts, out1);

  if (fast){
    conv3x3_split_kernel<512, 8><<<dim3(224,2), 256, 0, stream>>>(x2bf, wsbf, pbuf);
    conv_combine_kernel<true ><<<392, 256, 0, stream>>>(pbuf, consts,       consts + 128, x2s, x2sT);
    qproj_kernel<<<784, 256, 0, stream>>>(x1T,  wq1b, q1t);
    qproj_kernel<<<784, 256, 0, stream>>>(x2sT, wq2b, q2t);
    conv3x3_split_kernel<128, 2><<<dim3(224,2), 256, 0, stream>>>(x2s, wv2a, pbuf);
    conv_combine_kernel<false><<<392, 256, 0, stream>>>(pbuf, consts + 256, consts + 384, v2t, nullptr);
    conv3x3_split_kernel<128, 2><<<dim3(224,2), 256, 0, stream>>>(v2t, wv2b, pbuf);
    conv_combine_kernel<false><<<392, 256, 0, stream>>>(pbuf, consts + 512, consts + 640, x2v, nullptr);
    lse_kernel<<<784, 256, 0, stream>>>(q1t, q2t, pmax, psum);
    lse_merge_kernel<<<49, 256, 0, stream>>>(pmax, psum, Lm);
    attn3_kernel<<<1372, 256, 0, stream>>>(q1t, q2t, x2v, Lm, part, rpart);
    rtot_kernel<<<49, 256, 0, stream>>>(rpart, rinv);
    attn_combine_kernel<<<1568, 256, 0, stream>>>(part, rinv, x1, out0);
  } else {
    conv3x3_kernel<512, true ><<<224, 256, 0, stream>>>(x2bf, wsbf, consts, consts + 128, x2s, x2sT);
    qproj_kernel<<<784, 256, 0, stream>>>(x1T,  wq1b, q1t);
    qproj_kernel<<<784, 256, 0, stream>>>(x2sT, wq2b, q2t);
    conv3x3_kernel<128, false><<<224, 256, 0, stream>>>(x2s, wv2a, consts + 256, consts + 384, v2t, nullptr);
    conv3x3_kernel<128, false><<<224, 256, 0, stream>>>(v2t, wv2b, consts + 512, consts + 640, x2v, nullptr);
    colstats_kernel<<<784, 256, 0, stream>>>(q1t, q2t, Lm);
    attn_kernel<<<784, 256, 0, stream>>>(q1t, q2t, x2v, Lm, x1, out0);
  }
}

// Round 6
// 216.136 us; speedup vs baseline: 2.3751x; 1.2245x over previous
//
#include <hip/hip_runtime.h>
#include <cstdint>
#include <cstddef>

using bfr8 = __attribute__((ext_vector_type(8))) short;   // 8 bf16 (4 VGPRs)
using sh4  = __attribute__((ext_vector_type(4))) short;
using fx4  = __attribute__((ext_vector_type(4))) float;

#define DI __device__ __forceinline__
#define MFMA16(a,b,c) __builtin_amdgcn_mfma_f32_16x16x32_bf16((a),(b),(c),0,0,0)

DI short f2bf(float f){
  unsigned u = __float_as_uint(f);
  return (short)((u + 0x7fffu + ((u >> 16) & 1u)) >> 16);
}
DI float bf2f(short s){
  return __uint_as_float(((unsigned)(unsigned short)s) << 16);
}
DI fx4 fzero(){ fx4 z; z[0]=0.f; z[1]=0.f; z[2]=0.f; z[3]=0.f; return z; }

// ---------------------------------------------------------------------------
// prep: dtype conversions, weight re-layout [co][tap][ci], BN folding,
//       x1 transpose [b][n][c], and the out1 = x2 copy.
// ---------------------------------------------------------------------------
__global__ void prep_kernel(
    const float* __restrict__ x1, const float* __restrict__ x2,
    const float* __restrict__ wsw, const float* __restrict__ bs,
    const float* __restrict__ sg, const float* __restrict__ sbeta,
    const float* __restrict__ smean, const float* __restrict__ svar,
    const float* __restrict__ wq1, const float* __restrict__ wq2,
    const float* __restrict__ v2w, const float* __restrict__ v2bias,
    const float* __restrict__ v2g, const float* __restrict__ v2beta,
    const float* __restrict__ v2mean, const float* __restrict__ v2var,
    short* __restrict__ x2bf, short* __restrict__ x1T,
    short* __restrict__ wsbf, short* __restrict__ wv2a, short* __restrict__ wv2b,
    short* __restrict__ wq1b, short* __restrict__ wq2b,
    float* __restrict__ consts, float* __restrict__ out1copy)
{
  const int gsz = gridDim.x * blockDim.x;
  const int gid = blockIdx.x * blockDim.x + threadIdx.x;

  for (int i = gid; i < 1605632; i += gsz){
    float4 v = ((const float4*)x2)[i];
    ((float4*)out1copy)[i] = v;
    sh4 o; o[0]=f2bf(v.x); o[1]=f2bf(v.y); o[2]=f2bf(v.z); o[3]=f2bf(v.w);
    ((sh4*)x2bf)[i] = o;
  }
  for (int t = gid; t < 200704; t += gsz){
    int g = t & 15; int nn = t >> 4;
    int b = nn / 3136, n = nn - b*3136;
    bfr8 o;
    #pragma unroll
    for (int k = 0; k < 8; ++k)
      o[k] = f2bf(x1[(size_t)(b*128 + g*8 + k)*3136 + n]);
    *(bfr8*)&x1T[((size_t)(b*3136) + n)*128 + g*8] = o;
  }
  for (int i = gid; i < 589824; i += gsz){
    int ci = i & 511; int tap = (i >> 9) % 9; int co = i / 4608;
    wsbf[i] = f2bf(wsw[(size_t)(co*512 + ci)*9 + tap]);
  }
  for (int i = gid; i < 294912; i += gsz){
    int s = i / 147456; int r = i - s*147456;
    int ci = r & 127; int tap = (r >> 7) % 9; int co = r / 1152;
    float v = v2w[(size_t)((s*128 + co)*128 + ci)*9 + tap];
    (s ? wv2b : wv2a)[r] = f2bf(v);
  }
  for (int i = gid; i < 16384; i += gsz){
    wq1b[i] = f2bf(wq1[i]); wq2b[i] = f2bf(wq2[i]);
  }
  for (int c = gid; c < 128; c += gsz){
    float a = sg[c] * rsqrtf(svar[c] + 1e-5f);
    consts[c]       = a;
    consts[128 + c] = (bs[c] - smean[c]) * a + sbeta[c];
    float a0 = v2g[c] * rsqrtf(v2var[c] + 1e-5f);
    consts[256 + c] = a0;
    consts[384 + c] = (v2bias[c] - v2mean[c]) * a0 + v2beta[c];
    float a1 = v2g[128+c] * rsqrtf(v2var[128+c] + 1e-5f);
    consts[512 + c] = a1;
    consts[640 + c] = (v2bias[128+c] - v2mean[128+c]) * a1 + v2beta[128+c];
  }
}

// ---------------------------------------------------------------------------
// FAST PATH conv: split-K conv3x3 (pad=1), raw f32 partials (no BN).
// Grid: (224, NSPLIT): blockIdx.y = ci-split.
// ---------------------------------------------------------------------------
template<int CIN, int NCIB>
__global__ __launch_bounds__(256, 2) void conv3x3_split_kernel(
    const short* __restrict__ xin, const short* __restrict__ wt,
    float* __restrict__ pout)
{
  __shared__ short xs[4*58*40];
  __shared__ short wsh[9*64*40];

  const int tid = threadIdx.x;
  const int w = tid >> 6, lane = tid & 63, l15 = lane & 15, blk = lane >> 4;
  const int bid = blockIdx.x;
  const int rt = bid % 28, cog = (bid / 28) & 1, b = bid / 56;
  const int r0 = rt * 2;
  const int split = blockIdx.y;
  const int cib0 = split * NCIB;
  float* pbase = pout + (size_t)split * 1605632;

  int pixoff[7];
  #pragma unroll
  for (int pf = 0; pf < 7; ++pf){
    int p = pf*16 + l15;
    int pr = (p >= 56) ? 1 : 0;
    int pc = p - pr*56;
    pixoff[pf] = (pr*58 + pc)*40 + 8*blk;
  }
  const int wlo = (w*16 + l15)*40 + 8*blk;

  fx4 acc[7];
  #pragma unroll
  for (int pf = 0; pf < 7; ++pf) acc[pf] = fzero();

  for (int ci = 0; ci < NCIB; ++ci){
    const int cib = cib0 + ci;
    __syncthreads();
    #pragma unroll
    for (int it = 0; it < 4; ++it){
      int q = it*256 + tid;
      if (q < 928){
        int col = q % 58; int cg8 = (q/58) & 3; int r = q / 232;
        int grow = r0 - 1 + r;
        int gcol = col - 1;
        bfr8 v;
        if (grow >= 0 && grow < 56 && gcol >= 0 && gcol < 56){
          #pragma unroll
          for (int k = 0; k < 8; ++k)
            v[k] = xin[(size_t)(b*CIN + cib*32 + cg8*8 + k)*3136 + grow*56 + gcol];
        } else {
          #pragma unroll
          for (int k = 0; k < 8; ++k) v[k] = 0;
        }
        *(bfr8*)&xs[(r*58 + col)*40 + cg8*8] = v;
      }
    }
    #pragma unroll
    for (int it = 0; it < 9; ++it){
      int q = it*256 + tid;
      int jj = q & 3; int tap = (q >> 2) % 9; int co = q / 36;
      bfr8 wv = *(const bfr8*)&wt[(size_t)((cog*64 + co)*9 + tap)*CIN + cib*32 + jj*8];
      *(bfr8*)&wsh[(tap*64 + co)*40 + jj*8] = wv;
    }
    __syncthreads();
    #pragma unroll
    for (int tap = 0; tap < 9; ++tap){
      bfr8 af = *(const bfr8*)&wsh[tap*64*40 + wlo];
      const int toff = ((tap/3)*58 + (tap%3))*40;
      #pragma unroll
      for (int pf = 0; pf < 7; ++pf){
        bfr8 bf = *(const bfr8*)&xs[pixoff[pf] + toff];
        acc[pf] = MFMA16(af, bf, acc[pf]);
      }
    }
  }
  #pragma unroll
  for (int rr = 0; rr < 4; ++rr){
    int co = cog*64 + w*16 + 4*blk + rr;
    #pragma unroll
    for (int pf = 0; pf < 7; ++pf){
      int n = r0*56 + pf*16 + l15;
      pbase[(size_t)(b*128 + co)*3136 + n] = acc[pf][rr];
    }
  }
}

// ---------------------------------------------------------------------------
// combine: y = relu((sum_sp p_sp)*alpha + bc) -> bf16, plus optional transpose.
// ---------------------------------------------------------------------------
template<int NS, bool TSTORE>
__global__ __launch_bounds__(256, 4) void conv_combine_kernel(
    const float* __restrict__ p, const float* __restrict__ alpha,
    const float* __restrict__ bconst,
    short* __restrict__ yout, short* __restrict__ youtT)
{
  __shared__ short lt[64][66];
  const int t = threadIdx.x;
  const int bid = blockIdx.x;
  const int nt = bid % 49, cog = (bid / 49) & 1, b = bid / 98;
  const int co0 = cog*64, n0 = nt*64;
  const int coL = t >> 4, ncL = (t & 15) * 4;

  #pragma unroll
  for (int rep = 0; rep < 4; ++rep){
    int co = co0 + rep*16 + coL;
    size_t base = ((size_t)(b*128) + co)*3136 + n0 + ncL;
    float4 s = *(const float4*)&p[base];
    #pragma unroll
    for (int sp = 1; sp < NS; ++sp){
      float4 a = *(const float4*)&p[(size_t)sp*1605632 + base];
      s.x += a.x; s.y += a.y; s.z += a.z; s.w += a.w;
    }
    float al = alpha[co], bc = bconst[co];
    sh4 o;
    o[0] = f2bf(fmaxf(s.x*al + bc, 0.f));
    o[1] = f2bf(fmaxf(s.y*al + bc, 0.f));
    o[2] = f2bf(fmaxf(s.z*al + bc, 0.f));
    o[3] = f2bf(fmaxf(s.w*al + bc, 0.f));
    *(sh4*)&yout[base] = o;
    if (TSTORE) *(sh4*)&lt[rep*16 + coL][ncL] = o;
  }
  if (TSTORE){
    __syncthreads();
    #pragma unroll
    for (int rep = 0; rep < 4; ++rep){
      int nn = rep*16 + (t >> 4);
      int coc = (t & 15) * 4;
      sh4 v;
      #pragma unroll
      for (int j = 0; j < 4; ++j) v[j] = lt[coc + j][nn];
      *(sh4*)&youtT[((size_t)(b*3136) + n0 + nn)*128 + co0 + coc] = v;
    }
  }
}

// ---------------------------------------------------------------------------
// FALLBACK conv: conv3x3 + BN + ReLU fused.
// ---------------------------------------------------------------------------
template<int CIN, bool TSTORE>
__global__ __launch_bounds__(256, 2) void conv3x3_kernel(
    const short* __restrict__ xin, const short* __restrict__ wt,
    const float* __restrict__ alpha, const float* __restrict__ bconst,
    short* __restrict__ yout, short* __restrict__ youtT)
{
  __shared__ short xs[4*58*40];
  __shared__ short wsh[9*64*40];

  const int tid = threadIdx.x;
  const int w = tid >> 6, lane = tid & 63, l15 = lane & 15, blk = lane >> 4;
  const int bid = blockIdx.x;
  const int rt = bid % 28, cog = (bid / 28) & 1, b = bid / 56;
  const int r0 = rt * 2;

  int pixoff[7];
  #pragma unroll
  for (int pf = 0; pf < 7; ++pf){
    int p = pf*16 + l15;
    int pr = (p >= 56) ? 1 : 0;
    int pc = p - pr*56;
    pixoff[pf] = (pr*58 + pc)*40 + 8*blk;
  }
  const int wlo = (w*16 + l15)*40 + 8*blk;

  fx4 acc[7];
  #pragma unroll
  for (int pf = 0; pf < 7; ++pf) acc[pf] = fzero();

  for (int cib = 0; cib < CIN/32; ++cib){
    __syncthreads();
    #pragma unroll
    for (int it = 0; it < 4; ++it){
      int q = it*256 + tid;
      if (q < 928){
        int col = q % 58; int cg8 = (q/58) & 3; int r = q / 232;
        int grow = r0 - 1 + r;
        int gcol = col - 1;
        bfr8 v;
        if (grow >= 0 && grow < 56 && gcol >= 0 && gcol < 56){
          #pragma unroll
          for (int k = 0; k < 8; ++k)
            v[k] = xin[(size_t)(b*CIN + cib*32 + cg8*8 + k)*3136 + grow*56 + gcol];
        } else {
          #pragma unroll
          for (int k = 0; k < 8; ++k) v[k] = 0;
        }
        *(bfr8*)&xs[(r*58 + col)*40 + cg8*8] = v;
      }
    }
    #pragma unroll
    for (int it = 0; it < 9; ++it){
      int q = it*256 + tid;
      int jj = q & 3; int tap = (q >> 2) % 9; int co = q / 36;
      bfr8 wv = *(const bfr8*)&wt[(size_t)((cog*64 + co)*9 + tap)*CIN + cib*32 + jj*8];
      *(bfr8*)&wsh[(tap*64 + co)*40 + jj*8] = wv;
    }
    __syncthreads();
    #pragma unroll
    for (int tap = 0; tap < 9; ++tap){
      bfr8 af = *(const bfr8*)&wsh[tap*64*40 + wlo];
      const int toff = ((tap/3)*58 + (tap%3))*40;
      #pragma unroll
      for (int pf = 0; pf < 7; ++pf){
        bfr8 bf = *(const bfr8*)&xs[pixoff[pf] + toff];
        acc[pf] = MFMA16(af, bf, acc[pf]);
      }
    }
  }
  #pragma unroll
  for (int rr = 0; rr < 4; ++rr){
    int co = cog*64 + w*16 + 4*blk + rr;
    float al = alpha[co], bc = bconst[co];
    #pragma unroll
    for (int pf = 0; pf < 7; ++pf){
      float v = fmaxf(acc[pf][rr]*al + bc, 0.f);
      short sv = f2bf(v);
      int n = r0*56 + pf*16 + l15;
      yout[(size_t)(b*128 + co)*3136 + n] = sv;
      if (TSTORE) youtT[((size_t)(b*3136) + n)*128 + co] = sv;
    }
  }
}

// ---------------------------------------------------------------------------
// 1x1 conv: qt[b][n][co] = sum_ci wq[co][ci] * xT[b][n][ci]
// ---------------------------------------------------------------------------
__global__ __launch_bounds__(256, 4) void qproj_kernel(
    const short* __restrict__ xT, const short* __restrict__ wq,
    short* __restrict__ qt)
{
  const int tid = threadIdx.x, w = tid >> 6, lane = tid & 63;
  const int l15 = lane & 15, blk = lane >> 4;
  const int b = blockIdx.x / 196, n0 = (blockIdx.x % 196) * 16;

  fx4 acc[2];
  acc[0] = fzero(); acc[1] = fzero();

  #pragma unroll
  for (int ks = 0; ks < 4; ++ks){
    bfr8 af = *(const bfr8*)&xT[((size_t)(b*3136) + n0 + l15)*128 + ks*32 + 8*blk];
    #pragma unroll
    for (int i = 0; i < 2; ++i){
      bfr8 bf = *(const bfr8*)&wq[(size_t)((w*2 + i)*16 + l15)*128 + ks*32 + 8*blk];
      acc[i] = MFMA16(af, bf, acc[i]);
    }
  }
  #pragma unroll
  for (int i = 0; i < 2; ++i){
    #pragma unroll
    for (int rr = 0; rr < 4; ++rr){
      int n = n0 + 4*blk + rr;
      qt[((size_t)(b*3136) + n)*128 + (w*2 + i)*16 + l15] = f2bf(acc[i][rr]);
    }
  }
}

// ---------------------------------------------------------------------------
// FAST pass 1: per-(m, ns-range, wave) online lse of s[m][n]=q2[m,:].q1[n,:].
// ---------------------------------------------------------------------------
__global__ __launch_bounds__(256, 3) void lse_kernel(
    const short* __restrict__ q1t, const short* __restrict__ q2t,
    float* __restrict__ pmax, float* __restrict__ psum)
{
  const int tid = threadIdx.x, w = tid >> 6, lane = tid & 63;
  const int l15 = lane & 15, blk = lane >> 4;
  const int bid = blockIdx.x;
  const int ns = bid & 3, mt = (bid >> 2) % 49, b = bid / 196;
  const int m0 = mt*64;

  bfr8 qa[4][4];
  #pragma unroll
  for (int mf = 0; mf < 4; ++mf)
    #pragma unroll
    for (int ks = 0; ks < 4; ++ks)
      qa[mf][ks] = *(const bfr8*)&q2t[((size_t)(b*3136) + m0 + mf*16 + l15)*128 + ks*32 + 8*blk];

  float vmax[4][4], vsum[4][4];
  #pragma unroll
  for (int mf = 0; mf < 4; ++mf)
    #pragma unroll
    for (int rr = 0; rr < 4; ++rr){ vmax[mf][rr] = -1e30f; vsum[mf][rr] = 0.f; }

  bfr8 qb[4], qbn[4];
  #pragma unroll
  for (int ks = 0; ks < 4; ++ks)
    qb[ks] = *(const bfr8*)&q1t[((size_t)(b*3136) + ns*784 + w*16 + l15)*128 + ks*32 + 8*blk];

  for (int c = w; c < 49; c += 4){
    const int cn = c + 4;
    if (cn < 49){
      #pragma unroll
      for (int ks = 0; ks < 4; ++ks)
        qbn[ks] = *(const bfr8*)&q1t[((size_t)(b*3136) + ns*784 + cn*16 + l15)*128 + ks*32 + 8*blk];
    }
    fx4 acc[4];
    #pragma unroll
    for (int mf = 0; mf < 4; ++mf) acc[mf] = fzero();
    #pragma unroll
    for (int ks = 0; ks < 4; ++ks)
      #pragma unroll
      for (int mf = 0; mf < 4; ++mf)
        acc[mf] = MFMA16(qa[mf][ks], qb[ks], acc[mf]);
    #pragma unroll
    for (int mf = 0; mf < 4; ++mf)
      #pragma unroll
      for (int rr = 0; rr < 4; ++rr){
        float s = acc[mf][rr];
        float nm = fmaxf(vmax[mf][rr], s);
        vsum[mf][rr] = vsum[mf][rr]*__expf(vmax[mf][rr]-nm) + __expf(s-nm);
        vmax[mf][rr] = nm;
      }
    #pragma unroll
    for (int ks = 0; ks < 4; ++ks) qb[ks] = qbn[ks];
  }
  #pragma unroll
  for (int d = 1; d < 16; d <<= 1){
    #pragma unroll
    for (int mf = 0; mf < 4; ++mf)
      #pragma unroll
      for (int rr = 0; rr < 4; ++rr){
        float om = __shfl_xor(vmax[mf][rr], d);
        float os = __shfl_xor(vsum[mf][rr], d);
        float M = fmaxf(vmax[mf][rr], om);
        vsum[mf][rr] = vsum[mf][rr]*__expf(vmax[mf][rr]-M) + os*__expf(om-M);
        vmax[mf][rr] = M;
      }
  }
  if (l15 == 0){
    const size_t base = ((size_t)(b*16 + ns*4 + w))*3136 + m0;
    #pragma unroll
    for (int mf = 0; mf < 4; ++mf)
      #pragma unroll
      for (int rr = 0; rr < 4; ++rr){
        pmax[base + mf*16 + 4*blk + rr] = vmax[mf][rr];
        psum[base + mf*16 + 4*blk + rr] = vsum[mf][rr];
      }
  }
}

// ---------------------------------------------------------------------------
// merge the 16 lse partials per (b,m) -> Lm
// ---------------------------------------------------------------------------
__global__ void lse_merge_kernel(
    const float* __restrict__ pmax, const float* __restrict__ psum,
    float* __restrict__ Lm)
{
  int t = blockIdx.x*256 + threadIdx.x;
  if (t >= 12544) return;
  int b = t / 3136, m = t - b*3136;
  float M = -1e30f;
  #pragma unroll
  for (int r = 0; r < 16; ++r)
    M = fmaxf(M, pmax[((size_t)(b*16 + r))*3136 + m]);
  float S = 0.f;
  #pragma unroll
  for (int r = 0; r < 16; ++r){
    size_t i = ((size_t)(b*16 + r))*3136 + m;
    S += psum[i]*__expf(pmax[i] - M);
  }
  Lm[t] = M + __logf(S);
}

// ---------------------------------------------------------------------------
// FAST pass 2 v2: q2 tile AND x2v chunk both staged in XOR-swizzled LDS
// (T14 issue-early/write-late); all MFMA operands from LDS. G4 swizzle:
// byte ^= (row&7)<<4 kills the stride-128B/256B bank conflicts.
// Grid: 4b x 49nt x 7ms = 1372.
// ---------------------------------------------------------------------------
__global__ __launch_bounds__(256, 3) void attn3_kernel(
    const short* __restrict__ q1t, const short* __restrict__ q2t,
    const short* __restrict__ x2v, const float* __restrict__ Lm,
    float* __restrict__ part, float* __restrict__ rpart)
{
  __shared__ short q2sh[64*128];      // 16 KB [64m][128c], swizzled
  __shared__ short xsh[128*64];       // 16 KB [128c][64m], swizzled
  __shared__ short plds[4*16*72];     // per-wave P tile [16n][64m+8]
  __shared__ float lmsh[448];
  const int tid = threadIdx.x, w = tid >> 6, lane = tid & 63;
  const int l15 = lane & 15, blk = lane >> 4;
  const int bid = blockIdx.x;
  const int ms = bid % 7, nt = (bid / 7) % 49, b = bid / 343;
  const int m0 = ms*448;
  const int n0w = nt*64 + w*16;

  if (tid < 112)
    ((float4*)lmsh)[tid] = ((const float4*)(Lm + b*3136 + m0))[tid];

  // q1 fragments for this wave's 16 n (hoisted)
  bfr8 qb[4];
  #pragma unroll
  for (int ks = 0; ks < 4; ++ks)
    qb[ks] = *(const bfr8*)&q1t[((size_t)(b*3136) + n0w + l15)*128 + ks*32 + 8*blk];

  bfr8 stq[4], stx[4];
  auto issue = [&](int m0c){
    #pragma unroll
    for (int j = 0; j < 4; ++j){
      int u = tid + 256*j;
      stq[j] = *(const bfr8*)&q2t[((size_t)(b*3136) + m0c + (u>>4))*128 + (u&15)*8];
      stx[j] = *(const bfr8*)&x2v[((size_t)(b*128) + (u>>3))*3136 + m0c + (u&7)*8];
    }
  };
  auto write_stage = [&](){
    #pragma unroll
    for (int j = 0; j < 4; ++j){
      int u = tid + 256*j;
      int qrow = u >> 4;
      *(bfr8*)((char*)q2sh + ((qrow*256 + (u&15)*16) ^ ((qrow&7)<<4))) = stq[j];
      int xrow = u >> 3;
      *(bfr8*)((char*)xsh + ((xrow*128 + (u&7)*16) ^ ((xrow&7)<<4))) = stx[j];
    }
  };

  fx4 pacc[8];
  #pragma unroll
  for (int cf = 0; cf < 8; ++cf) pacc[cf] = fzero();
  float rsum = 0.f;

  issue(m0);

  for (int c = 0; c < 7; ++c){
    __syncthreads();                 // prev chunk fully consumed
    write_stage();
    if (c < 6) issue(m0 + (c+1)*64);
    __syncthreads();                 // tiles ready

    // QK: A = q2 (64 m rows, from LDS), B = q1 (16 n, regs)
    fx4 acc[4];
    #pragma unroll
    for (int mf = 0; mf < 4; ++mf) acc[mf] = fzero();
    #pragma unroll
    for (int ks = 0; ks < 4; ++ks){
      #pragma unroll
      for (int mf = 0; mf < 4; ++mf){
        const int row = mf*16 + l15;
        bfr8 qv = *(const bfr8*)((const char*)q2sh +
                    ((row*256 + ks*64 + 16*blk) ^ ((row&7)<<4)));
        acc[mf] = MFMA16(qv, qb[ks], acc[mf]);
      }
    }

    // softmax: p = exp(exp(s - Lm[m])), write P^T tile to per-wave plds
    #pragma unroll
    for (int mf = 0; mf < 4; ++mf){
      fx4 lv = *(const fx4*)&lmsh[c*64 + mf*16 + 4*blk];
      sh4 pk;
      #pragma unroll
      for (int rr = 0; rr < 4; ++rr){
        float a1 = __expf(acc[mf][rr] - lv[rr]);   // in (0,1]
        float p  = __expf(a1);                     // in (1,e]
        rsum += p;
        pk[rr] = f2bf(p);
      }
      *(sh4*)&plds[(w*16 + l15)*72 + mf*16 + 4*blk] = pk;
    }
    // PV: A = x2v rows c (LDS, swizzled), B = P rows n (plds)
    #pragma unroll
    for (int ks2 = 0; ks2 < 2; ++ks2){
      bfr8 pb = *(const bfr8*)&plds[(w*16 + l15)*72 + ks2*32 + 8*blk];
      #pragma unroll
      for (int cf = 0; cf < 8; ++cf){
        const int row = cf*16 + l15;
        bfr8 av = *(const bfr8*)((const char*)xsh +
                    ((row*128 + ks2*64 + 16*blk) ^ ((row&7)<<4)));
        pacc[cf] = MFMA16(av, pb, pacc[cf]);
      }
    }
  }

  // rowsum partial: all p of a lane belong to n = n0w + l15
  rsum += __shfl_xor(rsum, 16);
  rsum += __shfl_xor(rsum, 32);
  if (lane < 16)
    rpart[((size_t)(ms*4 + b))*3136 + n0w + l15] = rsum;

  // PV partial write
  #pragma unroll
  for (int cf = 0; cf < 8; ++cf)
    #pragma unroll
    for (int rr = 0; rr < 4; ++rr){
      int cc = cf*16 + 4*blk + rr;
      part[(((size_t)(ms*4 + b))*128 + cc)*3136 + n0w + l15] = pacc[cf][rr];
    }
}

// ---------------------------------------------------------------------------
// rtot: rinv[b][n] = 1 / sum_ms rpart
// ---------------------------------------------------------------------------
__global__ void rtot_kernel(const float* __restrict__ rpart,
                            float* __restrict__ rinv)
{
  int t = blockIdx.x*256 + threadIdx.x;
  if (t >= 12544) return;
  int b = t / 3136, n = t - b*3136;
  float s = 0.f;
  #pragma unroll
  for (int ms = 0; ms < 7; ++ms)
    s += rpart[((size_t)(ms*4 + b))*3136 + n];
  rinv[t] = 1.0f / s;
}

// ---------------------------------------------------------------------------
// attn combine: out0 = (sum_ms part)*rinv + x1
// ---------------------------------------------------------------------------
__global__ __launch_bounds__(256, 8) void attn_combine_kernel(
    const float* __restrict__ part, const float* __restrict__ rinv,
    const float* __restrict__ x1, float* __restrict__ out0)
{
  int t = blockIdx.x*256 + threadIdx.x;     // < 401408 float4 units
  int n4 = t % 784; int rest = t / 784;
  int cc = rest & 127; int b = rest >> 7;
  const float4* p4 = (const float4*)part;
  float4 s = {0.f,0.f,0.f,0.f};
  #pragma unroll
  for (int ms = 0; ms < 7; ++ms){
    float4 v = p4[(((size_t)(ms*4 + b))*128 + cc)*784 + n4];
    s.x += v.x; s.y += v.y; s.z += v.z; s.w += v.w;
  }
  float4 rv = ((const float4*)rinv)[b*784 + n4];
  size_t xi = ((size_t)(b*128) + cc)*784 + n4;
  float4 xv = ((const float4*)x1)[xi];
  float4 o;
  o.x = s.x*rv.x + xv.x; o.y = s.y*rv.y + xv.y;
  o.z = s.z*rv.z + xv.z; o.w = s.w*rv.w + xv.w;
  ((float4*)out0)[xi] = o;
}

// ---------------------------------------------------------------------------
// FALLBACK PATH (ws too small): R2 colstats + attn
// ---------------------------------------------------------------------------
__global__ __launch_bounds__(256, 2) void colstats_kernel(
    const short* __restrict__ q1t, const short* __restrict__ q2t,
    float* __restrict__ Lm)
{
  __shared__ float smax[4][16];
  __shared__ float ssum[4][16];
  const int tid = threadIdx.x, w = tid >> 6, lane = tid & 63;
  const int l15 = lane & 15, blk = lane >> 4;
  const int b = blockIdx.x / 196, m0 = (blockIdx.x % 196) * 16;

  bfr8 bfr[4];
  #pragma unroll
  for (int ks = 0; ks < 4; ++ks)
    bfr[ks] = *(const bfr8*)&q2t[((size_t)(b*3136) + m0 + l15)*128 + ks*32 + 8*blk];

  float vmax = -1e30f, vsum = 0.f;

  for (int nc = w; nc < 196; nc += 4){
    fx4 acc = fzero();
    #pragma unroll
    for (int ks = 0; ks < 4; ++ks){
      bfr8 af = *(const bfr8*)&q1t[((size_t)(b*3136) + nc*16 + l15)*128 + ks*32 + 8*blk];
      acc = MFMA16(af, bfr[ks], acc);
    }
    float cm = fmaxf(fmaxf(acc[0], acc[1]), fmaxf(acc[2], acc[3]));
    float nm = fmaxf(vmax, cm);
    float cs = __expf(acc[0]-nm) + __expf(acc[1]-nm)
             + __expf(acc[2]-nm) + __expf(acc[3]-nm);
    vsum = vsum*__expf(vmax-nm) + cs;
    vmax = nm;
  }
  #pragma unroll
  for (int d = 16; d < 64; d <<= 1){
    float om = __shfl_xor(vmax, d);
    float os = __shfl_xor(vsum, d);
    float M = fmaxf(vmax, om);
    vsum = vsum*__expf(vmax - M) + os*__expf(om - M);
    vmax = M;
  }
  if (lane < 16){ smax[w][lane] = vmax; ssum[w][lane] = vsum; }
  __syncthreads();
  if (tid < 16){
    float M = fmaxf(fmaxf(smax[0][tid], smax[1][tid]), fmaxf(smax[2][tid], smax[3][tid]));
    float S = ssum[0][tid]*__expf(smax[0][tid]-M) + ssum[1][tid]*__expf(smax[1][tid]-M)
            + ssum[2][tid]*__expf(smax[2][tid]-M) + ssum[3][tid]*__expf(smax[3][tid]-M);
    Lm[b*3136 + m0 + tid] = M + __logf(S);
  }
}

__global__ __launch_bounds__(256, 2) void attn_kernel(
    const short* __restrict__ q1t, const short* __restrict__ q2t,
    const short* __restrict__ x2v, const float* __restrict__ Lm,
    const float* __restrict__ x1, float* __restrict__ out0)
{
  __shared__ float part[8][4][4][64];
  __shared__ short plds[4][16][72];
  __shared__ float rl[4][16];
  const int tid = threadIdx.x, w = tid >> 6, lane = tid & 63;
  const int l15 = lane & 15, blk = lane >> 4;
  const int b = blockIdx.x / 196, n0 = (blockIdx.x % 196) * 16;

  bfr8 qa[4];
  #pragma unroll
  for (int ks = 0; ks < 4; ++ks)
    qa[ks] = *(const bfr8*)&q1t[((size_t)(b*3136) + n0 + l15)*128 + ks*32 + 8*blk];

  fx4 pacc[8];
  #pragma unroll
  for (int cf = 0; cf < 8; ++cf) pacc[cf] = fzero();
  float rsum[4] = {0.f, 0.f, 0.f, 0.f};

  for (int s = w; s < 49; s += 4){
    const int m0m = s*64;
    fx4 s4[4];
    #pragma unroll
    for (int mf = 0; mf < 4; ++mf) s4[mf] = fzero();
    #pragma unroll
    for (int ks = 0; ks < 4; ++ks){
      #pragma unroll
      for (int mf = 0; mf < 4; ++mf){
        bfr8 bq = *(const bfr8*)&q2t[((size_t)(b*3136) + m0m + mf*16 + l15)*128 + ks*32 + 8*blk];
        s4[mf] = MFMA16(qa[ks], bq, s4[mf]);
      }
    }
    #pragma unroll
    for (int mf = 0; mf < 4; ++mf){
      float Lv = Lm[b*3136 + m0m + mf*16 + l15];
      #pragma unroll
      for (int rr = 0; rr < 4; ++rr){
        float a1 = __expf(s4[mf][rr] - Lv);
        float p  = __expf(a1);
        rsum[rr] += p;
        plds[w][4*blk + rr][mf*16 + l15] = f2bf(p);
      }
    }
    #pragma unroll
    for (int ks2 = 0; ks2 < 2; ++ks2){
      bfr8 pb = *(const bfr8*)&plds[w][l15][ks2*32 + 8*blk];
      #pragma unroll
      for (int cf = 0; cf < 8; ++cf){
        bfr8 av = *(const bfr8*)&x2v[((size_t)(b*128) + cf*16 + l15)*3136 + m0m + ks2*32 + 8*blk];
        pacc[cf] = MFMA16(av, pb, pacc[cf]);
      }
    }
  }
  #pragma unroll
  for (int d = 1; d < 16; d <<= 1){
    #pragma unroll
    for (int rr = 0; rr < 4; ++rr) rsum[rr] += __shfl_xor(rsum[rr], d);
  }
  if (l15 == 0){
    #pragma unroll
    for (int rr = 0; rr < 4; ++rr) rl[w][4*blk + rr] = rsum[rr];
  }
  #pragma unroll
  for (int cf = 0; cf < 8; ++cf)
    #pragma unroll
    for (int rr = 0; rr < 4; ++rr)
      part[cf][rr][w][lane] = pacc[cf][rr];
  __syncthreads();

  float rtot = rl[0][l15] + rl[1][l15] + rl[2][l15] + rl[3][l15];
  float rinv = 1.0f / rtot;
  const int n = n0 + l15;
  #pragma unroll
  for (int i = 0; i < 2; ++i){
    int cf = 2*w + i;
    #pragma unroll
    for (int rr = 0; rr < 4; ++rr){
      float v = part[cf][rr][0][lane] + part[cf][rr][1][lane]
              + part[cf][rr][2][lane] + part[cf][rr][3][lane];
      int c = cf*16 + 4*blk + rr;
      size_t idx = (size_t)(b*128 + c)*3136 + n;
      out0[idx] = v*rinv + x1[idx];
    }
  }
}

// ---------------------------------------------------------------------------
extern "C" void kernel_launch(void* const* d_in, const int* in_sizes, int n_in,
                              void* d_out, int out_size, void* d_ws, size_t ws_size,
                              hipStream_t stream)
{
  (void)in_sizes; (void)n_in; (void)out_size;
  const float* x1     = (const float*)d_in[0];
  const float* x2     = (const float*)d_in[1];
  const float* wsw    = (const float*)d_in[2];
  const float* bs     = (const float*)d_in[3];
  const float* sg     = (const float*)d_in[4];
  const float* sbeta  = (const float*)d_in[5];
  const float* smean  = (const float*)d_in[6];
  const float* svar   = (const float*)d_in[7];
  const float* wq1    = (const float*)d_in[8];
  const float* wq2    = (const float*)d_in[9];
  // d_in[10..15]: v1 conv_block params -> dead code, unused
  const float* v2w    = (const float*)d_in[16];
  const float* v2bias = (const float*)d_in[17];
  const float* v2g    = (const float*)d_in[18];
  const float* v2beta = (const float*)d_in[19];
  const float* v2mean = (const float*)d_in[20];
  const float* v2var  = (const float*)d_in[21];

  char* ws = (char*)d_ws;
  auto al = [](size_t x){ return (x + 255) & ~(size_t)255; };

  const size_t sz_nc    = al((size_t)1605632*2);
  const size_t sz_x2bf  = al((size_t)6422528*2);
  const size_t sz_Lm    = al((size_t)12544*4);
  const size_t sz_lsep  = al((size_t)16*12544*4);
  const size_t sz_rp    = al((size_t)28*12544*4);
  const size_t sz_cst   = al((size_t)768*4);
  const size_t sz_part  = al((size_t)7*1605632*4);
  const size_t sz_wsbf  = al((size_t)589824*2);
  const size_t sz_wv2   = al((size_t)147456*2);
  const size_t sz_wq    = al((size_t)16384*2);

  short *x2bf, *x1T, *wsbf, *wv2a, *wv2b, *wq1b, *wq2b;
  short *x2s, *x2sT, *q1t, *q2t, *v2t, *x2v;
  float *consts, *Lm;
  float *pmax = nullptr, *psum = nullptr, *part = nullptr;
  float *rpart = nullptr, *rinv = nullptr, *pbuf = nullptr;

  size_t off = 0;
  const size_t o_x2v = off;  off += sz_nc;
  const size_t o_q1t = off;  off += sz_nc;
  const size_t o_q2t = off;  off += sz_nc;
  const size_t o_Lm  = off;  off += sz_Lm;
  const size_t o_pmx = off;  off += sz_lsep;
  const size_t o_psm = off;  off += sz_lsep;
  const size_t o_rp  = off;  off += sz_rp;
  const size_t o_ri  = off;  off += sz_Lm;
  const size_t o_cst = off;  off += sz_cst;
  const size_t o_prt = off;  off += sz_part;   // pbuf overlays part
  const size_t o_x2b = off;  off += sz_x2bf;
  const size_t o_x1T = off;  off += sz_nc;
  const size_t o_xsT = off;  off += sz_nc;
  const size_t o_x2s = off;  off += sz_nc;
  const size_t o_v2t = off;  off += sz_nc;
  const size_t o_wsb = off;  off += sz_wsbf;
  const size_t o_wva = off;  off += sz_wv2;
  const size_t o_wvb = off;  off += sz_wv2;
  const size_t o_wq1 = off;  off += sz_wq;
  const size_t o_wq2 = off;  off += sz_wq;
  const size_t fast_need = off;
  const bool fast = (ws_size >= fast_need);

  if (fast){
    x2v    = (short*)(ws + o_x2v);
    q1t    = (short*)(ws + o_q1t);
    q2t    = (short*)(ws + o_q2t);
    Lm     = (float*)(ws + o_Lm);
    pmax   = (float*)(ws + o_pmx);
    psum   = (float*)(ws + o_psm);
    rpart  = (float*)(ws + o_rp);
    rinv   = (float*)(ws + o_ri);
    consts = (float*)(ws + o_cst);
    part   = (float*)(ws + o_prt);
    pbuf   = (float*)(ws + o_prt);
    x2bf   = (short*)(ws + o_x2b);
    x1T    = (short*)(ws + o_x1T);
    x2sT   = (short*)(ws + o_xsT);
    x2s    = (short*)(ws + o_x2s);
    v2t    = (short*)(ws + o_v2t);
    wsbf   = (short*)(ws + o_wsb);
    wv2a   = (short*)(ws + o_wva);
    wv2b   = (short*)(ws + o_wvb);
    wq1b   = (short*)(ws + o_wq1);
    wq2b   = (short*)(ws + o_wq2);
  } else {
    size_t o = 0;
    auto bump = [&](size_t bytes)->char*{ char* p = ws + o; o += al(bytes); return p; };
    x2bf   = (short*)bump((size_t)6422528*2);
    x1T    = (short*)bump((size_t)1605632*2);
    wsbf   = (short*)bump((size_t)589824*2);
    wv2a   = (short*)bump((size_t)147456*2);
    wv2b   = (short*)bump((size_t)147456*2);
    wq1b   = (short*)bump((size_t)16384*2);
    wq2b   = (short*)bump((size_t)16384*2);
    consts = (float*)bump((size_t)768*4);
    x2s    = (short*)bump((size_t)1605632*2);
    x2sT   = (short*)bump((size_t)1605632*2);
    q1t    = (short*)bump((size_t)1605632*2);
    q2t    = (short*)bump((size_t)1605632*2);
    v2t    = (short*)bump((size_t)1605632*2);
    x2v    = (short*)bump((size_t)1605632*2);
    Lm     = (float*)bump((size_t)12544*4);
  }

  float* out0 = (float*)d_out;
  float* out1 = out0 + 1605632;

  prep_kernel<<<2048, 256, 0, stream>>>(x1, x2, wsw, bs, sg, sbeta, smean, svar,
      wq1, wq2, v2w, v2bias, v2g, v2beta, v2mean, v2var,
      x2bf, x1T, wsbf, wv2a, wv2b, wq1b, wq2b, consts, out1);

  if (fast){
    conv3x3_split_kernel<512, 4><<<dim3(224,4), 256, 0, stream>>>(x2bf, wsbf, pbuf);
    conv_combine_kernel<4, true ><<<392, 256, 0, stream>>>(pbuf, consts,       consts + 128, x2s, x2sT);
    qproj_kernel<<<784, 256, 0, stream>>>(x1T,  wq1b, q1t);
    qproj_kernel<<<784, 256, 0, stream>>>(x2sT, wq2b, q2t);
    conv3x3_split_kernel<128, 2><<<dim3(224,2), 256, 0, stream>>>(x2s, wv2a, pbuf);
    conv_combine_kernel<2, false><<<392, 256, 0, stream>>>(pbuf, consts + 256, consts + 384, v2t, nullptr);
    conv3x3_split_kernel<128, 2><<<dim3(224,2), 256, 0, stream>>>(v2t, wv2b, pbuf);
    conv_combine_kernel<2, false><<<392, 256, 0, stream>>>(pbuf, consts + 512, consts + 640, x2v, nullptr);
    lse_kernel<<<784, 256, 0, stream>>>(q1t, q2t, pmax, psum);
    lse_merge_kernel<<<49, 256, 0, stream>>>(pmax, psum, Lm);
    attn3_kernel<<<1372, 256, 0, stream>>>(q1t, q2t, x2v, Lm, part, rpart);
    rtot_kernel<<<49, 256, 0, stream>>>(rpart, rinv);
    attn_combine_kernel<<<1568, 256, 0, stream>>>(part, rinv, x1, out0);
  } else {
    conv3x3_kernel<512, true ><<<224, 256, 0, stream>>>(x2bf, wsbf, consts, consts + 128, x2s, x2sT);
    qproj_kernel<<<784, 256, 0, stream>>>(x1T,  wq1b, q1t);
    qproj_kernel<<<784, 256, 0, stream>>>(x2sT, wq2b, q2t);
    conv3x3_kernel<128, false><<<224, 256, 0, stream>>>(x2s, wv2a, consts + 256, consts + 384, v2t, nullptr);
    conv3x3_kernel<128, false><<<224, 256, 0, stream>>>(v2t, wv2b, consts + 512, consts + 640, x2v, nullptr);
    colstats_kernel<<<784, 256, 0, stream>>>(q1t, q2t, Lm);
    attn_kernel<<<784, 256, 0, stream>>>(q1t, q2t, x2v, Lm, x1, out0);
  }
}

// Round 8
// 210.272 us; speedup vs baseline: 2.4414x; 1.0279x over previous
//
#include <hip/hip_runtime.h>
#include <cstdint>
#include <cstddef>

using bfr8 = __attribute__((ext_vector_type(8))) short;   // 8 bf16 (4 VGPRs)
using sh4  = __attribute__((ext_vector_type(4))) short;
using fx4  = __attribute__((ext_vector_type(4))) float;

#define DI __device__ __forceinline__
#define MFMA16(a,b,c) __builtin_amdgcn_mfma_f32_16x16x32_bf16((a),(b),(c),0,0,0)

DI short f2bf(float f){
  unsigned u = __float_as_uint(f);
  return (short)((u + 0x7fffu + ((u >> 16) & 1u)) >> 16);
}
DI float bf2f(short s){
  return __uint_as_float(((unsigned)(unsigned short)s) << 16);
}
DI fx4 fzero(){ fx4 z; z[0]=0.f; z[1]=0.f; z[2]=0.f; z[3]=0.f; return z; }
DI bfr8 bzero(){ bfr8 z; 
  z[0]=0; z[1]=0; z[2]=0; z[3]=0; z[4]=0; z[5]=0; z[6]=0; z[7]=0; return z; }

// ---------------------------------------------------------------------------
// prep: weight re-layout [co][tap][ci] bf16, BN folding, out1 = x2 copy.
// legacy!=0 additionally builds [c][n] x2bf and x1T (fallback path only).
// ---------------------------------------------------------------------------
__global__ void prep_kernel(
    const float* __restrict__ x1, const float* __restrict__ x2,
    const float* __restrict__ wsw, const float* __restrict__ bs,
    const float* __restrict__ sg, const float* __restrict__ sbeta,
    const float* __restrict__ smean, const float* __restrict__ svar,
    const float* __restrict__ wq1, const float* __restrict__ wq2,
    const float* __restrict__ v2w, const float* __restrict__ v2bias,
    const float* __restrict__ v2g, const float* __restrict__ v2beta,
    const float* __restrict__ v2mean, const float* __restrict__ v2var,
    short* __restrict__ x2bf, short* __restrict__ x1T,
    short* __restrict__ wsbf, short* __restrict__ wv2a, short* __restrict__ wv2b,
    short* __restrict__ wq1b, short* __restrict__ wq2b,
    float* __restrict__ consts, float* __restrict__ out1copy, int legacy)
{
  const int gsz = gridDim.x * blockDim.x;
  const int gid = blockIdx.x * blockDim.x + threadIdx.x;

  // out1 = x2 (and legacy x2bf)
  for (int i = gid; i < 1605632; i += gsz){
    float4 v = ((const float4*)x2)[i];
    ((float4*)out1copy)[i] = v;
    if (legacy){
      sh4 o; o[0]=f2bf(v.x); o[1]=f2bf(v.y); o[2]=f2bf(v.z); o[3]=f2bf(v.w);
      ((sh4*)x2bf)[i] = o;
    }
  }
  if (legacy){
    for (int t = gid; t < 200704; t += gsz){
      int g = t & 15; int nn = t >> 4;
      int b = nn / 3136, n = nn - b*3136;
      bfr8 o;
      #pragma unroll
      for (int k = 0; k < 8; ++k)
        o[k] = f2bf(x1[(size_t)(b*128 + g*8 + k)*3136 + n]);
      *(bfr8*)&x1T[((size_t)(b*3136) + n)*128 + g*8] = o;
    }
  }
  for (int i = gid; i < 589824; i += gsz){
    int ci = i & 511; int tap = (i >> 9) % 9; int co = i / 4608;
    wsbf[i] = f2bf(wsw[(size_t)(co*512 + ci)*9 + tap]);
  }
  for (int i = gid; i < 294912; i += gsz){
    int s = i / 147456; int r = i - s*147456;
    int ci = r & 127; int tap = (r >> 7) % 9; int co = r / 1152;
    float v = v2w[(size_t)((s*128 + co)*128 + ci)*9 + tap];
    (s ? wv2b : wv2a)[r] = f2bf(v);
  }
  for (int i = gid; i < 16384; i += gsz){
    wq1b[i] = f2bf(wq1[i]); wq2b[i] = f2bf(wq2[i]);
  }
  for (int c = gid; c < 128; c += gsz){
    float a = sg[c] * rsqrtf(svar[c] + 1e-5f);
    consts[c]       = a;
    consts[128 + c] = (bs[c] - smean[c]) * a + sbeta[c];
    float a0 = v2g[c] * rsqrtf(v2var[c] + 1e-5f);
    consts[256 + c] = a0;
    consts[384 + c] = (v2bias[c] - v2mean[c]) * a0 + v2beta[c];
    float a1 = v2g[128+c] * rsqrtf(v2var[128+c] + 1e-5f);
    consts[512 + c] = a1;
    consts[640 + c] = (v2bias[128+c] - v2mean[128+c]) * a1 + v2beta[128+c];
  }
}

// ---------------------------------------------------------------------------
// NCHW f32 -> [b][n][C] bf16 tiled transpose (32c x 64n tiles via LDS).
// Grid: b(4) x C/32 x 49.
// ---------------------------------------------------------------------------
template<int C>
__global__ __launch_bounds__(256, 4) void transpose_cn_kernel(
    const float* __restrict__ in, short* __restrict__ out)
{
  __shared__ float t[32][65];
  const int tid = threadIdx.x, bid = blockIdx.x;
  const int nt = bid % 49, cg = (bid / 49) % (C/32), b = bid / (49*(C/32));
  const int n0 = nt*64, c0 = cg*32;

  #pragma unroll
  for (int j = 0; j < 2; ++j){
    int u = tid + 256*j;
    int row = u >> 4, col4 = u & 15;
    float4 v = *(const float4*)&in[((size_t)(b*C) + c0 + row)*3136 + n0 + col4*4];
    t[row][col4*4+0] = v.x; t[row][col4*4+1] = v.y;
    t[row][col4*4+2] = v.z; t[row][col4*4+3] = v.w;
  }
  __syncthreads();
  {
    int n = tid >> 2, cg8 = tid & 3;
    bfr8 o;
    #pragma unroll
    for (int k = 0; k < 8; ++k) o[k] = f2bf(t[cg8*8 + k][n]);
    *(bfr8*)&out[((size_t)(b*3136) + n0 + n)*C + c0 + cg8*8] = o;
  }
}

// ---------------------------------------------------------------------------
// FAST conv: split-K conv3x3 (pad=1), channel-last input [b][n][CIN] bf16,
// hoisted staging addresses, raw f32 partials out [split][b][co][n].
// Grid: (224, NSPLIT).
// ---------------------------------------------------------------------------
template<int CIN, int NCIB>
__global__ __launch_bounds__(256, 2) void conv3x3_split_kernel(
    const short* __restrict__ xin,   // [4][3136][CIN]
    const short* __restrict__ wt,    // [128][9][CIN]
    float* __restrict__ pout)
{
  __shared__ short xs[4*58*40];
  __shared__ short wsh[9*64*40];

  const int tid = threadIdx.x;
  const int w = tid >> 6, lane = tid & 63, l15 = lane & 15, blk = lane >> 4;
  const int bid = blockIdx.x;
  const int rt = bid % 28, cog = (bid / 28) & 1, b = bid / 56;
  const int r0 = rt * 2;
  const int cib0 = blockIdx.y * NCIB;
  float* pbase = pout + (size_t)blockIdx.y * 1605632;

  int pixoff[7];
  #pragma unroll
  for (int pf = 0; pf < 7; ++pf){
    int p = pf*16 + l15;
    int pr = (p >= 56) ? 1 : 0;
    int pc = p - pr*56;
    pixoff[pf] = (pr*58 + pc)*40 + 8*blk;
  }
  const int wlo = (w*16 + l15)*40 + 8*blk;

  // hoisted input-staging descriptors (cg8 fastest for coalescing)
  int in_act[4], in_val[4], in_lds[4], in_go[4];
  #pragma unroll
  for (int it = 0; it < 4; ++it){
    int q = it*256 + tid;
    int cg8 = q & 3, col = (q >> 2) % 58, r = q / 232;
    int grow = r0 - 1 + r, gcol = col - 1;
    in_act[it] = (q < 928);
    in_val[it] = in_act[it] && grow >= 0 && grow < 56 && gcol >= 0 && gcol < 56;
    in_lds[it] = (r*58 + col)*40 + cg8*8;
    int gr = in_val[it] ? grow : 0, gc = in_val[it] ? gcol : 0;
    in_go[it] = (b*3136 + gr*56 + gc)*CIN + cib0*32 + cg8*8;
  }
  // hoisted weight-staging descriptors
  int wt_lds[9], wt_go[9];
  #pragma unroll
  for (int it = 0; it < 9; ++it){
    int q = it*256 + tid;
    int jj = q & 3, tap = (q >> 2) % 9, co = q / 36;
    wt_lds[it] = (tap*64 + co)*40 + jj*8;
    wt_go[it] = ((cog*64 + co)*9 + tap)*CIN + cib0*32 + jj*8;
  }

  fx4 acc[7];
  #pragma unroll
  for (int pf = 0; pf < 7; ++pf) acc[pf] = fzero();

  for (int ci = 0; ci < NCIB; ++ci){
    __syncthreads();
    #pragma unroll
    for (int it = 0; it < 4; ++it){
      if (in_act[it]){
        bfr8 v = bzero();
        if (in_val[it]) v = *(const bfr8*)&xin[in_go[it]];
        *(bfr8*)&xs[in_lds[it]] = v;
        in_go[it] += 32;
      }
    }
    #pragma unroll
    for (int it = 0; it < 9; ++it){
      *(bfr8*)&wsh[wt_lds[it]] = *(const bfr8*)&wt[wt_go[it]];
      wt_go[it] += 32;
    }
    __syncthreads();
    #pragma unroll
    for (int tap = 0; tap < 9; ++tap){
      bfr8 af = *(const bfr8*)&wsh[tap*64*40 + wlo];
      const int toff = ((tap/3)*58 + (tap%3))*40;
      #pragma unroll
      for (int pf = 0; pf < 7; ++pf){
        bfr8 bf = *(const bfr8*)&xs[pixoff[pf] + toff];
        acc[pf] = MFMA16(af, bf, acc[pf]);
      }
    }
  }
  #pragma unroll
  for (int rr = 0; rr < 4; ++rr){
    int co = cog*64 + w*16 + 4*blk + rr;
    #pragma unroll
    for (int pf = 0; pf < 7; ++pf){
      int n = r0*56 + pf*16 + l15;
      pbase[(size_t)(b*128 + co)*3136 + n] = acc[pf][rr];
    }
  }
}

// ---------------------------------------------------------------------------
// combine: y = relu((sum_sp p)*alpha + bc) -> bf16.
// MODE 0: write [c][n].  MODE 1: write [n][c] (LDS transpose).
// ---------------------------------------------------------------------------
template<int NS, int MODE>
__global__ __launch_bounds__(256, 4) void conv_combine_kernel(
    const float* __restrict__ p, const float* __restrict__ alpha,
    const float* __restrict__ bconst, short* __restrict__ yout)
{
  __shared__ short lt[64][66];
  const int t = threadIdx.x;
  const int bid = blockIdx.x;
  const int nt = bid % 49, cog = (bid / 49) & 1, b = bid / 98;
  const int co0 = cog*64, n0 = nt*64;
  const int coL = t >> 4, ncL = (t & 15) * 4;

  #pragma unroll
  for (int rep = 0; rep < 4; ++rep){
    int co = co0 + rep*16 + coL;
    size_t base = ((size_t)(b*128) + co)*3136 + n0 + ncL;
    float4 s = *(const float4*)&p[base];
    #pragma unroll
    for (int sp = 1; sp < NS; ++sp){
      float4 a = *(const float4*)&p[(size_t)sp*1605632 + base];
      s.x += a.x; s.y += a.y; s.z += a.z; s.w += a.w;
    }
    float al = alpha[co], bc = bconst[co];
    sh4 o;
    o[0] = f2bf(fmaxf(s.x*al + bc, 0.f));
    o[1] = f2bf(fmaxf(s.y*al + bc, 0.f));
    o[2] = f2bf(fmaxf(s.z*al + bc, 0.f));
    o[3] = f2bf(fmaxf(s.w*al + bc, 0.f));
    if (MODE == 0) *(sh4*)&yout[base] = o;
    else           *(sh4*)&lt[rep*16 + coL][ncL] = o;
  }
  if (MODE == 1){
    __syncthreads();
    #pragma unroll
    for (int rep = 0; rep < 4; ++rep){
      int nn = rep*16 + (t >> 4);
      int coc = (t & 15) * 4;
      sh4 v;
      #pragma unroll
      for (int j = 0; j < 4; ++j) v[j] = lt[coc + j][nn];
      *(sh4*)&yout[((size_t)(b*3136) + n0 + nn)*128 + co0 + coc] = v;
    }
  }
}

// ---------------------------------------------------------------------------
// FALLBACK conv (legacy [c][n] input): conv3x3 + BN + ReLU fused.
// ---------------------------------------------------------------------------
template<int CIN, bool TSTORE>
__global__ __launch_bounds__(256, 2) void conv3x3_kernel(
    const short* __restrict__ xin, const short* __restrict__ wt,
    const float* __restrict__ alpha, const float* __restrict__ bconst,
    short* __restrict__ yout, short* __restrict__ youtT)
{
  __shared__ short xs[4*58*40];
  __shared__ short wsh[9*64*40];

  const int tid = threadIdx.x;
  const int w = tid >> 6, lane = tid & 63, l15 = lane & 15, blk = lane >> 4;
  const int bid = blockIdx.x;
  const int rt = bid % 28, cog = (bid / 28) & 1, b = bid / 56;
  const int r0 = rt * 2;

  int pixoff[7];
  #pragma unroll
  for (int pf = 0; pf < 7; ++pf){
    int p = pf*16 + l15;
    int pr = (p >= 56) ? 1 : 0;
    int pc = p - pr*56;
    pixoff[pf] = (pr*58 + pc)*40 + 8*blk;
  }
  const int wlo = (w*16 + l15)*40 + 8*blk;

  fx4 acc[7];
  #pragma unroll
  for (int pf = 0; pf < 7; ++pf) acc[pf] = fzero();

  for (int cib = 0; cib < CIN/32; ++cib){
    __syncthreads();
    #pragma unroll
    for (int it = 0; it < 4; ++it){
      int q = it*256 + tid;
      if (q < 928){
        int col = q % 58; int cg8 = (q/58) & 3; int r = q / 232;
        int grow = r0 - 1 + r;
        int gcol = col - 1;
        bfr8 v = bzero();
        if (grow >= 0 && grow < 56 && gcol >= 0 && gcol < 56){
          #pragma unroll
          for (int k = 0; k < 8; ++k)
            v[k] = xin[(size_t)(b*CIN + cib*32 + cg8*8 + k)*3136 + grow*56 + gcol];
        }
        *(bfr8*)&xs[(r*58 + col)*40 + cg8*8] = v;
      }
    }
    #pragma unroll
    for (int it = 0; it < 9; ++it){
      int q = it*256 + tid;
      int jj = q & 3; int tap = (q >> 2) % 9; int co = q / 36;
      bfr8 wv = *(const bfr8*)&wt[(size_t)((cog*64 + co)*9 + tap)*CIN + cib*32 + jj*8];
      *(bfr8*)&wsh[(tap*64 + co)*40 + jj*8] = wv;
    }
    __syncthreads();
    #pragma unroll
    for (int tap = 0; tap < 9; ++tap){
      bfr8 af = *(const bfr8*)&wsh[tap*64*40 + wlo];
      const int toff = ((tap/3)*58 + (tap%3))*40;
      #pragma unroll
      for (int pf = 0; pf < 7; ++pf){
        bfr8 bf = *(const bfr8*)&xs[pixoff[pf] + toff];
        acc[pf] = MFMA16(af, bf, acc[pf]);
      }
    }
  }
  #pragma unroll
  for (int rr = 0; rr < 4; ++rr){
    int co = cog*64 + w*16 + 4*blk + rr;
    float al = alpha[co], bc = bconst[co];
    #pragma unroll
    for (int pf = 0; pf < 7; ++pf){
      float v = fmaxf(acc[pf][rr]*al + bc, 0.f);
      short sv = f2bf(v);
      int n = r0*56 + pf*16 + l15;
      yout[(size_t)(b*128 + co)*3136 + n] = sv;
      if (TSTORE) youtT[((size_t)(b*3136) + n)*128 + co] = sv;
    }
  }
}

// ---------------------------------------------------------------------------
// 1x1 conv: qt[b][n][co] = sum_ci wq[co][ci] * xT[b][n][ci]
// ---------------------------------------------------------------------------
__global__ __launch_bounds__(256, 4) void qproj_kernel(
    const short* __restrict__ xT, const short* __restrict__ wq,
    short* __restrict__ qt)
{
  const int tid = threadIdx.x, w = tid >> 6, lane = tid & 63;
  const int l15 = lane & 15, blk = lane >> 4;
  const int b = blockIdx.x / 196, n0 = (blockIdx.x % 196) * 16;

  fx4 acc[2];
  acc[0] = fzero(); acc[1] = fzero();

  #pragma unroll
  for (int ks = 0; ks < 4; ++ks){
    bfr8 af = *(const bfr8*)&xT[((size_t)(b*3136) + n0 + l15)*128 + ks*32 + 8*blk];
    #pragma unroll
    for (int i = 0; i < 2; ++i){
      bfr8 bf = *(const bfr8*)&wq[(size_t)((w*2 + i)*16 + l15)*128 + ks*32 + 8*blk];
      acc[i] = MFMA16(af, bf, acc[i]);
    }
  }
  #pragma unroll
  for (int i = 0; i < 2; ++i){
    #pragma unroll
    for (int rr = 0; rr < 4; ++rr){
      int n = n0 + 4*blk + rr;
      qt[((size_t)(b*3136) + n)*128 + (w*2 + i)*16 + l15] = f2bf(acc[i][rr]);
    }
  }
}

// ---------------------------------------------------------------------------
// FAST pass 1: per-(m, ns, wave) online lse with branchless single-exp
// defer-style update. s[m][n]: A=q2 rows m, B=q1 cols n.
// ---------------------------------------------------------------------------
__global__ __launch_bounds__(256, 3) void lse_kernel(
    const short* __restrict__ q1t, const short* __restrict__ q2t,
    float* __restrict__ pmax, float* __restrict__ psum)
{
  const int tid = threadIdx.x, w = tid >> 6, lane = tid & 63;
  const int l15 = lane & 15, blk = lane >> 4;
  const int bid = blockIdx.x;
  const int ns = bid & 3, mt = (bid >> 2) % 49, b = bid / 196;
  const int m0 = mt*64;

  bfr8 qa[4][4];
  #pragma unroll
  for (int mf = 0; mf < 4; ++mf)
    #pragma unroll
    for (int ks = 0; ks < 4; ++ks)
      qa[mf][ks] = *(const bfr8*)&q2t[((size_t)(b*3136) + m0 + mf*16 + l15)*128 + ks*32 + 8*blk];

  float vmax[4][4], vsum[4][4];
  #pragma unroll
  for (int mf = 0; mf < 4; ++mf)
    #pragma unroll
    for (int rr = 0; rr < 4; ++rr){ vmax[mf][rr] = -1e30f; vsum[mf][rr] = 0.f; }

  bfr8 qb[4], qbn[4];
  #pragma unroll
  for (int ks = 0; ks < 4; ++ks)
    qb[ks] = *(const bfr8*)&q1t[((size_t)(b*3136) + ns*784 + w*16 + l15)*128 + ks*32 + 8*blk];

  for (int c = w; c < 49; c += 4){
    const int cn = c + 4;
    if (cn < 49){
      #pragma unroll
      for (int ks = 0; ks < 4; ++ks)
        qbn[ks] = *(const bfr8*)&q1t[((size_t)(b*3136) + ns*784 + cn*16 + l15)*128 + ks*32 + 8*blk];
    }
    fx4 acc[4];
    #pragma unroll
    for (int mf = 0; mf < 4; ++mf) acc[mf] = fzero();
    #pragma unroll
    for (int ks = 0; ks < 4; ++ks)
      #pragma unroll
      for (int mf = 0; mf < 4; ++mf)
        acc[mf] = MFMA16(qa[mf][ks], qb[ks], acc[mf]);
    #pragma unroll
    for (int mf = 0; mf < 4; ++mf)
      #pragma unroll
      for (int rr = 0; rr < 4; ++rr){
        float s = acc[mf][rr];
        float d = s - vmax[mf][rr];
        float e = __expf(-fabsf(d));          // exp(-|s-vmax|): serves both cases
        bool up = d > 0.f;
        float mlt = up ? e : 1.f;
        float add = up ? 1.f : e;
        vsum[mf][rr] = vsum[mf][rr]*mlt + add;
        vmax[mf][rr] = fmaxf(vmax[mf][rr], s);
      }
    #pragma unroll
    for (int ks = 0; ks < 4; ++ks) qb[ks] = qbn[ks];
  }
  #pragma unroll
  for (int d = 1; d < 16; d <<= 1){
    #pragma unroll
    for (int mf = 0; mf < 4; ++mf)
      #pragma unroll
      for (int rr = 0; rr < 4; ++rr){
        float om = __shfl_xor(vmax[mf][rr], d);
        float os = __shfl_xor(vsum[mf][rr], d);
        float M = fmaxf(vmax[mf][rr], om);
        vsum[mf][rr] = vsum[mf][rr]*__expf(vmax[mf][rr]-M) + os*__expf(om-M);
        vmax[mf][rr] = M;
      }
  }
  if (l15 == 0){
    const size_t base = ((size_t)(b*16 + ns*4 + w))*3136 + m0;
    #pragma unroll
    for (int mf = 0; mf < 4; ++mf)
      #pragma unroll
      for (int rr = 0; rr < 4; ++rr){
        pmax[base + mf*16 + 4*blk + rr] = vmax[mf][rr];
        psum[base + mf*16 + 4*blk + rr] = vsum[mf][rr];
      }
  }
}

// ---------------------------------------------------------------------------
__global__ void lse_merge_kernel(
    const float* __restrict__ pmax, const float* __restrict__ psum,
    float* __restrict__ Lm)
{
  int t = blockIdx.x*256 + threadIdx.x;
  if (t >= 12544) return;
  int b = t / 3136, m = t - b*3136;
  float M = -1e30f;
  #pragma unroll
  for (int r = 0; r < 16; ++r)
    M = fmaxf(M, pmax[((size_t)(b*16 + r))*3136 + m]);
  float S = 0.f;
  #pragma unroll
  for (int r = 0; r < 16; ++r){
    size_t i = ((size_t)(b*16 + r))*3136 + m;
    S += psum[i]*__expf(pmax[i] - M);
  }
  Lm[t] = M + __logf(S);
}

// ---------------------------------------------------------------------------
// FAST pass 2 v3: 32-m chunks (LDS ~23 KB -> higher residency); q2+x2v staged
// in XOR-swizzled LDS; plds rows 80B (conflict-free, 16B aligned); bf16
// partials. Grid: 4b x 49nt x 7ms = 1372.
// ---------------------------------------------------------------------------
__global__ __launch_bounds__(256, 4) void attn3_kernel(
    const short* __restrict__ q1t, const short* __restrict__ q2t,
    const short* __restrict__ x2v, const float* __restrict__ Lm,
    short* __restrict__ part, float* __restrict__ rpart)
{
  __shared__ short q2sh[32*128];      // 8 KB [32m][128c], swizzled
  __shared__ short xsh[128*32];       // 8 KB [128c][32m], swizzled
  __shared__ short plds[4*16*40];     // 5.1 KB per-wave P tile [16n][32m+pad]
  __shared__ float lmsh[448];
  const int tid = threadIdx.x, w = tid >> 6, lane = tid & 63;
  const int l15 = lane & 15, blk = lane >> 4;
  const int bid = blockIdx.x;
  const int ms = bid % 7, nt = (bid / 7) % 49, b = bid / 343;
  const int m0 = ms*448;
  const int n0w = nt*64 + w*16;

  if (tid < 112)
    ((float4*)lmsh)[tid] = ((const float4*)(Lm + b*3136 + m0))[tid];

  bfr8 qb[4];
  #pragma unroll
  for (int ks = 0; ks < 4; ++ks)
    qb[ks] = *(const bfr8*)&q1t[((size_t)(b*3136) + n0w + l15)*128 + ks*32 + 8*blk];

  bfr8 stq[2], stx[2];
  auto issue = [&](int m0c){
    #pragma unroll
    for (int j = 0; j < 2; ++j){
      int u = tid + 256*j;
      stq[j] = *(const bfr8*)&q2t[((size_t)(b*3136) + m0c + (u>>4))*128 + (u&15)*8];
      stx[j] = *(const bfr8*)&x2v[((size_t)(b*128) + (u>>2))*3136 + m0c + (u&3)*8];
    }
  };
  auto write_stage = [&](){
    #pragma unroll
    for (int j = 0; j < 2; ++j){
      int u = tid + 256*j;
      int qrow = u >> 4;
      *(bfr8*)((char*)q2sh + ((qrow*256 + (u&15)*16) ^ ((qrow&7)<<4))) = stq[j];
      int xrow = u >> 2;
      *(bfr8*)((char*)xsh + ((xrow*64 + (u&3)*16) ^ ((xrow&7)<<4))) = stx[j];
    }
  };

  fx4 pacc[8];
  #pragma unroll
  for (int cf = 0; cf < 8; ++cf) pacc[cf] = fzero();
  float rsum = 0.f;

  issue(m0);

  for (int c = 0; c < 14; ++c){
    __syncthreads();
    write_stage();
    if (c < 13) issue(m0 + (c+1)*32);
    __syncthreads();

    // QK: A = q2 (32 m rows, LDS), B = q1 (16 n, regs)
    fx4 acc[2];
    acc[0] = fzero(); acc[1] = fzero();
    #pragma unroll
    for (int ks = 0; ks < 4; ++ks){
      #pragma unroll
      for (int mf = 0; mf < 2; ++mf){
        const int row = mf*16 + l15;
        bfr8 qv = *(const bfr8*)((const char*)q2sh +
                    ((row*256 + ks*64 + 16*blk) ^ ((row&7)<<4)));
        acc[mf] = MFMA16(qv, qb[ks], acc[mf]);
      }
    }

    // softmax: p = exp(exp(s - Lm)), P^T tile to per-wave plds
    #pragma unroll
    for (int mf = 0; mf < 2; ++mf){
      fx4 lv = *(const fx4*)&lmsh[c*32 + mf*16 + 4*blk];
      sh4 pk;
      #pragma unroll
      for (int rr = 0; rr < 4; ++rr){
        float a1 = __expf(acc[mf][rr] - lv[rr]);   // in (0,1]
        float p  = __expf(a1);                     // in (1,e]
        rsum += p;
        pk[rr] = f2bf(p);
      }
      *(sh4*)&plds[(w*16 + l15)*40 + mf*16 + 4*blk] = pk;
    }
    // PV: A = x2v rows (LDS, swizzled), B = P (plds), K = 32
    bfr8 pb = *(const bfr8*)&plds[(w*16 + l15)*40 + 8*blk];
    #pragma unroll
    for (int cf = 0; cf < 8; ++cf){
      const int row = cf*16 + l15;
      bfr8 av = *(const bfr8*)((const char*)xsh +
                  ((row*64 + 16*blk) ^ ((row&7)<<4)));
      pacc[cf] = MFMA16(av, pb, pacc[cf]);
    }
  }

  rsum += __shfl_xor(rsum, 16);
  rsum += __shfl_xor(rsum, 32);
  if (lane < 16)
    rpart[((size_t)(ms*4 + b))*3136 + n0w + l15] = rsum;

  #pragma unroll
  for (int cf = 0; cf < 8; ++cf)
    #pragma unroll
    for (int rr = 0; rr < 4; ++rr){
      int cc = cf*16 + 4*blk + rr;
      part[(((size_t)(ms*4 + b))*128 + cc)*3136 + n0w + l15] = f2bf(pacc[cf][rr]);
    }
}

// ---------------------------------------------------------------------------
__global__ void rtot_kernel(const float* __restrict__ rpart,
                            float* __restrict__ rinv)
{
  int t = blockIdx.x*256 + threadIdx.x;
  if (t >= 12544) return;
  int b = t / 3136, n = t - b*3136;
  float s = 0.f;
  #pragma unroll
  for (int ms = 0; ms < 7; ++ms)
    s += rpart[((size_t)(ms*4 + b))*3136 + n];
  rinv[t] = 1.0f / s;
}

// ---------------------------------------------------------------------------
// attn combine: out0 = (sum_ms part)*rinv + x1   (part is bf16)
// ---------------------------------------------------------------------------
__global__ __launch_bounds__(256, 8) void attn_combine_kernel(
    const short* __restrict__ part, const float* __restrict__ rinv,
    const float* __restrict__ x1, float* __restrict__ out0)
{
  int t = blockIdx.x*256 + threadIdx.x;     // < 401408 4-wide units
  int n4 = t % 784; int rest = t / 784;
  int cc = rest & 127; int b = rest >> 7;
  float4 s = {0.f,0.f,0.f,0.f};
  #pragma unroll
  for (int ms = 0; ms < 7; ++ms){
    sh4 v = *(const sh4*)&part[((((size_t)(ms*4 + b))*128 + cc)*3136) + n4*4];
    s.x += bf2f(v[0]); s.y += bf2f(v[1]); s.z += bf2f(v[2]); s.w += bf2f(v[3]);
  }
  float4 rv = ((const float4*)rinv)[b*784 + n4];
  size_t xi = ((size_t)(b*128) + cc)*784 + n4;
  float4 xv = ((const float4*)x1)[xi];
  float4 o;
  o.x = s.x*rv.x + xv.x; o.y = s.y*rv.y + xv.y;
  o.z = s.z*rv.z + xv.z; o.w = s.w*rv.w + xv.w;
  ((float4*)out0)[xi] = o;
}

// ---------------------------------------------------------------------------
// FALLBACK PATH kernels (legacy layouts)
// ---------------------------------------------------------------------------
__global__ __launch_bounds__(256, 2) void colstats_kernel(
    const short* __restrict__ q1t, const short* __restrict__ q2t,
    float* __restrict__ Lm)
{
  __shared__ float smax[4][16];
  __shared__ float ssum[4][16];
  const int tid = threadIdx.x, w = tid >> 6, lane = tid & 63;
  const int l15 = lane & 15, blk = lane >> 4;
  const int b = blockIdx.x / 196, m0 = (blockIdx.x % 196) * 16;

  bfr8 bfr[4];
  #pragma unroll
  for (int ks = 0; ks < 4; ++ks)
    bfr[ks] = *(const bfr8*)&q2t[((size_t)(b*3136) + m0 + l15)*128 + ks*32 + 8*blk];

  float vmax = -1e30f, vsum = 0.f;

  for (int nc = w; nc < 196; nc += 4){
    fx4 acc = fzero();
    #pragma unroll
    for (int ks = 0; ks < 4; ++ks){
      bfr8 af = *(const bfr8*)&q1t[((size_t)(b*3136) + nc*16 + l15)*128 + ks*32 + 8*blk];
      acc = MFMA16(af, bfr[ks], acc);
    }
    float cm = fmaxf(fmaxf(acc[0], acc[1]), fmaxf(acc[2], acc[3]));
    float nm = fmaxf(vmax, cm);
    float cs = __expf(acc[0]-nm) + __expf(acc[1]-nm)
             + __expf(acc[2]-nm) + __expf(acc[3]-nm);
    vsum = vsum*__expf(vmax-nm) + cs;
    vmax = nm;
  }
  #pragma unroll
  for (int d = 16; d < 64; d <<= 1){
    float om = __shfl_xor(vmax, d);
    float os = __shfl_xor(vsum, d);
    float M = fmaxf(vmax, om);
    vsum = vsum*__expf(vmax - M) + os*__expf(om - M);
    vmax = M;
  }
  if (lane < 16){ smax[w][lane] = vmax; ssum[w][lane] = vsum; }
  __syncthreads();
  if (tid < 16){
    float M = fmaxf(fmaxf(smax[0][tid], smax[1][tid]), fmaxf(smax[2][tid], smax[3][tid]));
    float S = ssum[0][tid]*__expf(smax[0][tid]-M) + ssum[1][tid]*__expf(smax[1][tid]-M)
            + ssum[2][tid]*__expf(smax[2][tid]-M) + ssum[3][tid]*__expf(smax[3][tid]-M);
    Lm[b*3136 + m0 + tid] = M + __logf(S);
  }
}

__global__ __launch_bounds__(256, 2) void attn_kernel(
    const short* __restrict__ q1t, const short* __restrict__ q2t,
    const short* __restrict__ x2v, const float* __restrict__ Lm,
    const float* __restrict__ x1, float* __restrict__ out0)
{
  __shared__ float part[8][4][4][64];
  __shared__ short plds[4][16][72];
  __shared__ float rl[4][16];
  const int tid = threadIdx.x, w = tid >> 6, lane = tid & 63;
  const int l15 = lane & 15, blk = lane >> 4;
  const int b = blockIdx.x / 196, n0 = (blockIdx.x % 196) * 16;

  bfr8 qa[4];
  #pragma unroll
  for (int ks = 0; ks < 4; ++ks)
    qa[ks] = *(const bfr8*)&q1t[((size_t)(b*3136) + n0 + l15)*128 + ks*32 + 8*blk];

  fx4 pacc[8];
  #pragma unroll
  for (int cf = 0; cf < 8; ++cf) pacc[cf] = fzero();
  float rsum[4] = {0.f, 0.f, 0.f, 0.f};

  for (int s = w; s < 49; s += 4){
    const int m0m = s*64;
    fx4 s4[4];
    #pragma unroll
    for (int mf = 0; mf < 4; ++mf) s4[mf] = fzero();
    #pragma unroll
    for (int ks = 0; ks < 4; ++ks){
      #pragma unroll
      for (int mf = 0; mf < 4; ++mf){
        bfr8 bq = *(const bfr8*)&q2t[((size_t)(b*3136) + m0m + mf*16 + l15)*128 + ks*32 + 8*blk];
        s4[mf] = MFMA16(qa[ks], bq, s4[mf]);
      }
    }
    #pragma unroll
    for (int mf = 0; mf < 4; ++mf){
      float Lv = Lm[b*3136 + m0m + mf*16 + l15];
      #pragma unroll
      for (int rr = 0; rr < 4; ++rr){
        float a1 = __expf(s4[mf][rr] - Lv);
        float p  = __expf(a1);
        rsum[rr] += p;
        plds[w][4*blk + rr][mf*16 + l15] = f2bf(p);
      }
    }
    #pragma unroll
    for (int ks2 = 0; ks2 < 2; ++ks2){
      bfr8 pb = *(const bfr8*)&plds[w][l15][ks2*32 + 8*blk];
      #pragma unroll
      for (int cf = 0; cf < 8; ++cf){
        bfr8 av = *(const bfr8*)&x2v[((size_t)(b*128) + cf*16 + l15)*3136 + m0m + ks2*32 + 8*blk];
        pacc[cf] = MFMA16(av, pb, pacc[cf]);
      }
    }
  }
  #pragma unroll
  for (int d = 1; d < 16; d <<= 1){
    #pragma unroll
    for (int rr = 0; rr < 4; ++rr) rsum[rr] += __shfl_xor(rsum[rr], d);
  }
  if (l15 == 0){
    #pragma unroll
    for (int rr = 0; rr < 4; ++rr) rl[w][4*blk + rr] = rsum[rr];
  }
  #pragma unroll
  for (int cf = 0; cf < 8; ++cf)
    #pragma unroll
    for (int rr = 0; rr < 4; ++rr)
      part[cf][rr][w][lane] = pacc[cf][rr];
  __syncthreads();

  float rtot = rl[0][l15] + rl[1][l15] + rl[2][l15] + rl[3][l15];
  float rinv = 1.0f / rtot;
  const int n = n0 + l15;
  #pragma unroll
  for (int i = 0; i < 2; ++i){
    int cf = 2*w + i;
    #pragma unroll
    for (int rr = 0; rr < 4; ++rr){
      float v = part[cf][rr][0][lane] + part[cf][rr][1][lane]
              + part[cf][rr][2][lane] + part[cf][rr][3][lane];
      int c = cf*16 + 4*blk + rr;
      size_t idx = (size_t)(b*128 + c)*3136 + n;
      out0[idx] = v*rinv + x1[idx];
    }
  }
}

// ---------------------------------------------------------------------------
extern "C" void kernel_launch(void* const* d_in, const int* in_sizes, int n_in,
                              void* d_out, int out_size, void* d_ws, size_t ws_size,
                              hipStream_t stream)
{
  (void)in_sizes; (void)n_in; (void)out_size;
  const float* x1     = (const float*)d_in[0];
  const float* x2     = (const float*)d_in[1];
  const float* wsw    = (const float*)d_in[2];
  const float* bs     = (const float*)d_in[3];
  const float* sg     = (const float*)d_in[4];
  const float* sbeta  = (const float*)d_in[5];
  const float* smean  = (const float*)d_in[6];
  const float* svar   = (const float*)d_in[7];
  const float* wq1    = (const float*)d_in[8];
  const float* wq2    = (const float*)d_in[9];
  // d_in[10..15]: v1 conv_block params -> dead code, unused
  const float* v2w    = (const float*)d_in[16];
  const float* v2bias = (const float*)d_in[17];
  const float* v2g    = (const float*)d_in[18];
  const float* v2beta = (const float*)d_in[19];
  const float* v2mean = (const float*)d_in[20];
  const float* v2var  = (const float*)d_in[21];

  char* ws = (char*)d_ws;
  auto al = [](size_t x){ return (x + 255) & ~(size_t)255; };

  const size_t sz_nc    = al((size_t)1605632*2);          // [4][3136][128] bf16
  const size_t sz_x2T   = al((size_t)6422528*2);          // [4][3136][512] bf16
  const size_t sz_Lm    = al((size_t)12544*4);
  const size_t sz_lsep  = al((size_t)16*12544*4);
  const size_t sz_rp    = al((size_t)28*12544*4);
  const size_t sz_cst   = al((size_t)768*4);
  const size_t sz_part  = al((size_t)7*1605632*2);        // bf16 partials
  const size_t sz_pbuf  = al((size_t)4*1605632*4);        // conv f32 partials (4 splits)
  const size_t sz_wsbf  = al((size_t)589824*2);
  const size_t sz_wv2   = al((size_t)147456*2);
  const size_t sz_wq    = al((size_t)16384*2);

  // fast layout
  size_t off = 0;
  const size_t o_x2v = off;  off += sz_nc;      // [c][n]
  const size_t o_q1t = off;  off += sz_nc;
  const size_t o_q2t = off;  off += sz_nc;
  const size_t o_x1T = off;  off += sz_nc;      // [n][c]
  const size_t o_x2s = off;  off += sz_nc;      // [n][c]
  const size_t o_v2t = off;  off += sz_nc;      // [n][c]
  const size_t o_Lm  = off;  off += sz_Lm;
  const size_t o_pmx = off;  off += sz_lsep;
  const size_t o_psm = off;  off += sz_lsep;
  const size_t o_rp  = off;  off += sz_rp;
  const size_t o_ri  = off;  off += sz_Lm;
  const size_t o_cst = off;  off += sz_cst;
  const size_t o_wsb = off;  off += sz_wsbf;
  const size_t o_wva = off;  off += sz_wv2;
  const size_t o_wvb = off;  off += sz_wv2;
  const size_t o_wq1 = off;  off += sz_wq;
  const size_t o_wq2 = off;  off += sz_wq;
  const size_t o_x2T = off;  off += sz_x2T;
  const size_t o_prt = off;  off += (sz_part > sz_pbuf ? sz_part : sz_pbuf);
  const size_t fast_need = off;
  const bool fast = (ws_size >= fast_need);

  float* out0 = (float*)d_out;
  float* out1 = out0 + 1605632;

  if (fast){
    short* x2v  = (short*)(ws + o_x2v);
    short* q1t  = (short*)(ws + o_q1t);
    short* q2t  = (short*)(ws + o_q2t);
    short* x1T  = (short*)(ws + o_x1T);
    short* x2s  = (short*)(ws + o_x2s);
    short* v2t  = (short*)(ws + o_v2t);
    float* Lm   = (float*)(ws + o_Lm);
    float* pmax = (float*)(ws + o_pmx);
    float* psum = (float*)(ws + o_psm);
    float* rpart= (float*)(ws + o_rp);
    float* rinv = (float*)(ws + o_ri);
    float* consts = (float*)(ws + o_cst);
    short* wsbf = (short*)(ws + o_wsb);
    short* wv2a = (short*)(ws + o_wva);
    short* wv2b = (short*)(ws + o_wvb);
    short* wq1b = (short*)(ws + o_wq1);
    short* wq2b = (short*)(ws + o_wq2);
    short* x2T  = (short*)(ws + o_x2T);
    short* part = (short*)(ws + o_prt);
    float* pbuf = (float*)(ws + o_prt);

    prep_kernel<<<2048, 256, 0, stream>>>(x1, x2, wsw, bs, sg, sbeta, smean, svar,
        wq1, wq2, v2w, v2bias, v2g, v2beta, v2mean, v2var,
        nullptr, nullptr, wsbf, wv2a, wv2b, wq1b, wq2b, consts, out1, 0);
    transpose_cn_kernel<512><<<3136, 256, 0, stream>>>(x2, x2T);
    transpose_cn_kernel<128><<<784, 256, 0, stream>>>(x1, x1T);

    conv3x3_split_kernel<512, 4><<<dim3(224,4), 256, 0, stream>>>(x2T, wsbf, pbuf);
    conv_combine_kernel<4, 1><<<392, 256, 0, stream>>>(pbuf, consts,       consts + 128, x2s);
    qproj_kernel<<<784, 256, 0, stream>>>(x1T, wq1b, q1t);
    qproj_kernel<<<784, 256, 0, stream>>>(x2s, wq2b, q2t);
    conv3x3_split_kernel<128, 2><<<dim3(224,2), 256, 0, stream>>>(x2s, wv2a, pbuf);
    conv_combine_kernel<2, 1><<<392, 256, 0, stream>>>(pbuf, consts + 256, consts + 384, v2t);
    conv3x3_split_kernel<128, 2><<<dim3(224,2), 256, 0, stream>>>(v2t, wv2b, pbuf);
    conv_combine_kernel<2, 0><<<392, 256, 0, stream>>>(pbuf, consts + 512, consts + 640, x2v);

    lse_kernel<<<784, 256, 0, stream>>>(q1t, q2t, pmax, psum);
    lse_merge_kernel<<<49, 256, 0, stream>>>(pmax, psum, Lm);
    attn3_kernel<<<1372, 256, 0, stream>>>(q1t, q2t, x2v, Lm, part, rpart);
    rtot_kernel<<<49, 256, 0, stream>>>(rpart, rinv);
    attn_combine_kernel<<<1568, 256, 0, stream>>>(part, rinv, x1, out0);
  } else {
    size_t o = 0;
    auto bump = [&](size_t bytes)->char*{ char* p = ws + o; o += al(bytes); return p; };
    short* x2bf   = (short*)bump((size_t)6422528*2);
    short* x1T    = (short*)bump((size_t)1605632*2);
    short* wsbf   = (short*)bump((size_t)589824*2);
    short* wv2a   = (short*)bump((size_t)147456*2);
    short* wv2b   = (short*)bump((size_t)147456*2);
    short* wq1b   = (short*)bump((size_t)16384*2);
    short* wq2b   = (short*)bump((size_t)16384*2);
    float* consts = (float*)bump((size_t)768*4);
    short* x2s    = (short*)bump((size_t)1605632*2);
    short* x2sT   = (short*)bump((size_t)1605632*2);
    short* q1t    = (short*)bump((size_t)1605632*2);
    short* q2t    = (short*)bump((size_t)1605632*2);
    short* v2t    = (short*)bump((size_t)1605632*2);
    short* x2v    = (short*)bump((size_t)1605632*2);
    float* Lm     = (float*)bump((size_t)12544*4);

    prep_kernel<<<2048, 256, 0, stream>>>(x1, x2, wsw, bs, sg, sbeta, smean, svar,
        wq1, wq2, v2w, v2bias, v2g, v2beta, v2mean, v2var,
        x2bf, x1T, wsbf, wv2a, wv2b, wq1b, wq2b, consts, out1, 1);
    conv3x3_kernel<512, true ><<<224, 256, 0, stream>>>(x2bf, wsbf, consts, consts + 128, x2s, x2sT);
    qproj_kernel<<<784, 256, 0, stream>>>(x1T,  wq1b, q1t);
    qproj_kernel<<<784, 256, 0, stream>>>(x2sT, wq2b, q2t);
    conv3x3_kernel<128, false><<<224, 256, 0, stream>>>(x2s, wv2a, consts + 256, consts + 384, v2t, nullptr);
    conv3x3_kernel<128, false><<<224, 256, 0, stream>>>(v2t, wv2b, consts + 512, consts + 640, x2v, nullptr);
    colstats_kernel<<<784, 256, 0, stream>>>(q1t, q2t, Lm);
    attn_kernel<<<784, 256, 0, stream>>>(q1t, q2t, x2v, Lm, x1, out0);
  }
}

// Round 9
// 200.215 us; speedup vs baseline: 2.5640x; 1.0502x over previous
//
#include <hip/hip_runtime.h>
#include <cstdint>
#include <cstddef>

using bfr8 = __attribute__((ext_vector_type(8))) short;   // 8 bf16 (4 VGPRs)
using sh4  = __attribute__((ext_vector_type(4))) short;
using fx4  = __attribute__((ext_vector_type(4))) float;

#define DI __device__ __forceinline__
#define MFMA16(a,b,c) __builtin_amdgcn_mfma_f32_16x16x32_bf16((a),(b),(c),0,0,0)

DI short f2bf(float f){
  unsigned u = __float_as_uint(f);
  return (short)((u + 0x7fffu + ((u >> 16) & 1u)) >> 16);
}
DI float bf2f(short s){
  return __uint_as_float(((unsigned)(unsigned short)s) << 16);
}
// pack hi16(lo),hi16(hi) -> one u32 (truncation; 1 v_perm)
DI unsigned pk2(float lo, float hi){
  return __builtin_amdgcn_perm(__float_as_uint(hi), __float_as_uint(lo), 0x07060302u);
}
DI fx4 fzero(){ fx4 z; z[0]=0.f; z[1]=0.f; z[2]=0.f; z[3]=0.f; return z; }
DI bfr8 bzero(){ bfr8 z;
  z[0]=0; z[1]=0; z[2]=0; z[3]=0; z[4]=0; z[5]=0; z[6]=0; z[7]=0; return z; }

// ---------------------------------------------------------------------------
// prep: weight re-layout [co][tap][ci] bf16, BN folding.
// legacy!=0 additionally: out1 copy, [c][n] x2bf, x1T (fallback only).
// ---------------------------------------------------------------------------
__global__ void prep_kernel(
    const float* __restrict__ x1, const float* __restrict__ x2,
    const float* __restrict__ wsw, const float* __restrict__ bs,
    const float* __restrict__ sg, const float* __restrict__ sbeta,
    const float* __restrict__ smean, const float* __restrict__ svar,
    const float* __restrict__ wq1, const float* __restrict__ wq2,
    const float* __restrict__ v2w, const float* __restrict__ v2bias,
    const float* __restrict__ v2g, const float* __restrict__ v2beta,
    const float* __restrict__ v2mean, const float* __restrict__ v2var,
    short* __restrict__ x2bf, short* __restrict__ x1T,
    short* __restrict__ wsbf, short* __restrict__ wv2a, short* __restrict__ wv2b,
    short* __restrict__ wq1b, short* __restrict__ wq2b,
    float* __restrict__ consts, float* __restrict__ out1copy, int legacy)
{
  const int gsz = gridDim.x * blockDim.x;
  const int gid = blockIdx.x * blockDim.x + threadIdx.x;

  if (legacy){
    for (int i = gid; i < 1605632; i += gsz){
      float4 v = ((const float4*)x2)[i];
      ((float4*)out1copy)[i] = v;
      sh4 o; o[0]=f2bf(v.x); o[1]=f2bf(v.y); o[2]=f2bf(v.z); o[3]=f2bf(v.w);
      ((sh4*)x2bf)[i] = o;
    }
    for (int t = gid; t < 200704; t += gsz){
      int g = t & 15; int nn = t >> 4;
      int b = nn / 3136, n = nn - b*3136;
      bfr8 o;
      #pragma unroll
      for (int k = 0; k < 8; ++k)
        o[k] = f2bf(x1[(size_t)(b*128 + g*8 + k)*3136 + n]);
      *(bfr8*)&x1T[((size_t)(b*3136) + n)*128 + g*8] = o;
    }
  }
  for (int i = gid; i < 589824; i += gsz){
    int ci = i & 511; int tap = (i >> 9) % 9; int co = i / 4608;
    wsbf[i] = f2bf(wsw[(size_t)(co*512 + ci)*9 + tap]);
  }
  for (int i = gid; i < 294912; i += gsz){
    int s = i / 147456; int r = i - s*147456;
    int ci = r & 127; int tap = (r >> 7) % 9; int co = r / 1152;
    float v = v2w[(size_t)((s*128 + co)*128 + ci)*9 + tap];
    (s ? wv2b : wv2a)[r] = f2bf(v);
  }
  for (int i = gid; i < 16384; i += gsz){
    wq1b[i] = f2bf(wq1[i]); wq2b[i] = f2bf(wq2[i]);
  }
  for (int c = gid; c < 128; c += gsz){
    float a = sg[c] * rsqrtf(svar[c] + 1e-5f);
    consts[c]       = a;
    consts[128 + c] = (bs[c] - smean[c]) * a + sbeta[c];
    float a0 = v2g[c] * rsqrtf(v2var[c] + 1e-5f);
    consts[256 + c] = a0;
    consts[384 + c] = (v2bias[c] - v2mean[c]) * a0 + v2beta[c];
    float a1 = v2g[128+c] * rsqrtf(v2var[128+c] + 1e-5f);
    consts[512 + c] = a1;
    consts[640 + c] = (v2bias[128+c] - v2mean[128+c]) * a1 + v2beta[128+c];
  }
}

// ---------------------------------------------------------------------------
// NCHW f32 -> [b][n][C] bf16 tiled transpose; OC: also emit out1 = x2 copy.
// Grid: b(4) x C/32 x 49.
// ---------------------------------------------------------------------------
template<int C, bool OC>
__global__ __launch_bounds__(256, 4) void transpose_cn_kernel(
    const float* __restrict__ in, short* __restrict__ out,
    float* __restrict__ out1copy)
{
  __shared__ float t[32][65];
  const int tid = threadIdx.x, bid = blockIdx.x;
  const int nt = bid % 49, cg = (bid / 49) % (C/32), b = bid / (49*(C/32));
  const int n0 = nt*64, c0 = cg*32;

  #pragma unroll
  for (int j = 0; j < 2; ++j){
    int u = tid + 256*j;
    int row = u >> 4, col4 = u & 15;
    size_t gi = ((size_t)(b*C) + c0 + row)*3136 + n0 + col4*4;
    float4 v = *(const float4*)&in[gi];
    if (OC) *(float4*)&out1copy[gi] = v;
    t[row][col4*4+0] = v.x; t[row][col4*4+1] = v.y;
    t[row][col4*4+2] = v.z; t[row][col4*4+3] = v.w;
  }
  __syncthreads();
  {
    int n = tid >> 2, cg8 = tid & 3;
    bfr8 o;
    #pragma unroll
    for (int k = 0; k < 8; ++k) o[k] = f2bf(t[cg8*8 + k][n]);
    *(bfr8*)&out[((size_t)(b*3136) + n0 + n)*C + c0 + cg8*8] = o;
  }
}

// ---------------------------------------------------------------------------
// FAST conv: split-K conv3x3 (pad=1), channel-last input [b][n][CIN] bf16.
// Weights per-wave DIRECT to registers (no LDS staging); input tile LDS with
// register prefetch. Raw f32 partials out [split][b][co][n]. Grid: (224, NS).
// ---------------------------------------------------------------------------
template<int CIN, int NCIB>
__global__ __launch_bounds__(256, 3) void conv3x3_split_kernel(
    const short* __restrict__ xin,   // [4][3136][CIN]
    const short* __restrict__ wt,    // [128][9][CIN]
    float* __restrict__ pout)
{
  __shared__ short xs[4*58*40];

  const int tid = threadIdx.x;
  const int w = tid >> 6, lane = tid & 63, l15 = lane & 15, blk = lane >> 4;
  const int bid = blockIdx.x;
  const int rt = bid % 28, cog = (bid / 28) & 1, b = bid / 56;
  const int r0 = rt * 2;
  const int cib0 = blockIdx.y * NCIB;
  float* pbase = pout + (size_t)blockIdx.y * 1605632;

  int pixoff[7];
  #pragma unroll
  for (int pf = 0; pf < 7; ++pf){
    int p = pf*16 + l15;
    int pr = (p >= 56) ? 1 : 0;
    int pc = p - pr*56;
    pixoff[pf] = (pr*58 + pc)*40 + 8*blk;
  }

  // hoisted input-staging descriptors (cg8 fastest for coalescing)
  int in_act[4], in_val[4], in_lds[4], in_go[4];
  #pragma unroll
  for (int it = 0; it < 4; ++it){
    int q = it*256 + tid;
    int cg8 = q & 3, col = (q >> 2) % 58, r = q / 232;
    int grow = r0 - 1 + r, gcol = col - 1;
    in_act[it] = (q < 928);
    in_val[it] = in_act[it] && grow >= 0 && grow < 56 && gcol >= 0 && gcol < 56;
    in_lds[it] = (r*58 + col)*40 + cg8*8;
    int gr = in_val[it] ? grow : 0, gc = in_val[it] ? gcol : 0;
    in_go[it] = (b*3136 + gr*56 + gc)*CIN + cib0*32 + cg8*8;
  }
  // per-wave weight base: co = cog*64 + w*16 + l15, ci-part = 8*blk
  int wb = (cog*64 + w*16 + l15)*9*CIN + cib0*32 + 8*blk;

  fx4 acc[7];
  #pragma unroll
  for (int pf = 0; pf < 7; ++pf) acc[pf] = fzero();

  bfr8 sv[4];
  #pragma unroll
  for (int it = 0; it < 4; ++it) sv[it] = bzero();
  #pragma unroll
  for (int it = 0; it < 4; ++it){
    if (in_val[it]){ sv[it] = *(const bfr8*)&xin[in_go[it]]; in_go[it] += 32; }
  }

  for (int ci = 0; ci < NCIB; ++ci){
    __syncthreads();                  // xs from prev iter consumed
    #pragma unroll
    for (int it = 0; it < 4; ++it){
      if (in_act[it]) *(bfr8*)&xs[in_lds[it]] = sv[it];
    }
    if (ci + 1 < NCIB){
      #pragma unroll
      for (int it = 0; it < 4; ++it){
        if (in_val[it]){ sv[it] = *(const bfr8*)&xin[in_go[it]]; in_go[it] += 32; }
      }
    }
    bfr8 af[9];
    #pragma unroll
    for (int tap = 0; tap < 9; ++tap)
      af[tap] = *(const bfr8*)&wt[wb + tap*CIN];
    wb += 32;
    __syncthreads();                  // xs ready
    #pragma unroll
    for (int tap = 0; tap < 9; ++tap){
      const int toff = ((tap/3)*58 + (tap%3))*40;
      #pragma unroll
      for (int pf = 0; pf < 7; ++pf){
        bfr8 bf = *(const bfr8*)&xs[pixoff[pf] + toff];
        acc[pf] = MFMA16(af[tap], bf, acc[pf]);
      }
    }
  }
  #pragma unroll
  for (int rr = 0; rr < 4; ++rr){
    int co = cog*64 + w*16 + 4*blk + rr;
    #pragma unroll
    for (int pf = 0; pf < 7; ++pf){
      int n = r0*56 + pf*16 + l15;
      pbase[(size_t)(b*128 + co)*3136 + n] = acc[pf][rr];
    }
  }
}

// ---------------------------------------------------------------------------
// combine: y = relu((sum_sp p)*alpha + bc) -> bf16.
// MODE 0: write [c][n].  MODE 1: write [n][c] (LDS transpose).
// ---------------------------------------------------------------------------
template<int NS, int MODE>
__global__ __launch_bounds__(256, 4) void conv_combine_kernel(
    const float* __restrict__ p, const float* __restrict__ alpha,
    const float* __restrict__ bconst, short* __restrict__ yout)
{
  __shared__ short lt[64][66];
  const int t = threadIdx.x;
  const int bid = blockIdx.x;
  const int nt = bid % 49, cog = (bid / 49) & 1, b = bid / 98;
  const int co0 = cog*64, n0 = nt*64;
  const int coL = t >> 4, ncL = (t & 15) * 4;

  #pragma unroll
  for (int rep = 0; rep < 4; ++rep){
    int co = co0 + rep*16 + coL;
    size_t base = ((size_t)(b*128) + co)*3136 + n0 + ncL;
    float4 s = *(const float4*)&p[base];
    #pragma unroll
    for (int sp = 1; sp < NS; ++sp){
      float4 a = *(const float4*)&p[(size_t)sp*1605632 + base];
      s.x += a.x; s.y += a.y; s.z += a.z; s.w += a.w;
    }
    float al = alpha[co], bc = bconst[co];
    sh4 o;
    o[0] = f2bf(fmaxf(s.x*al + bc, 0.f));
    o[1] = f2bf(fmaxf(s.y*al + bc, 0.f));
    o[2] = f2bf(fmaxf(s.z*al + bc, 0.f));
    o[3] = f2bf(fmaxf(s.w*al + bc, 0.f));
    if (MODE == 0) *(sh4*)&yout[base] = o;
    else           *(sh4*)&lt[rep*16 + coL][ncL] = o;
  }
  if (MODE == 1){
    __syncthreads();
    #pragma unroll
    for (int rep = 0; rep < 4; ++rep){
      int nn = rep*16 + (t >> 4);
      int coc = (t & 15) * 4;
      sh4 v;
      #pragma unroll
      for (int j = 0; j < 4; ++j) v[j] = lt[coc + j][nn];
      *(sh4*)&yout[((size_t)(b*3136) + n0 + nn)*128 + co0 + coc] = v;
    }
  }
}

// ---------------------------------------------------------------------------
// FALLBACK conv (legacy [c][n] input): conv3x3 + BN + ReLU fused.
// ---------------------------------------------------------------------------
template<int CIN, bool TSTORE>
__global__ __launch_bounds__(256, 2) void conv3x3_kernel(
    const short* __restrict__ xin, const short* __restrict__ wt,
    const float* __restrict__ alpha, const float* __restrict__ bconst,
    short* __restrict__ yout, short* __restrict__ youtT)
{
  __shared__ short xs[4*58*40];
  __shared__ short wsh[9*64*40];

  const int tid = threadIdx.x;
  const int w = tid >> 6, lane = tid & 63, l15 = lane & 15, blk = lane >> 4;
  const int bid = blockIdx.x;
  const int rt = bid % 28, cog = (bid / 28) & 1, b = bid / 56;
  const int r0 = rt * 2;

  int pixoff[7];
  #pragma unroll
  for (int pf = 0; pf < 7; ++pf){
    int p = pf*16 + l15;
    int pr = (p >= 56) ? 1 : 0;
    int pc = p - pr*56;
    pixoff[pf] = (pr*58 + pc)*40 + 8*blk;
  }
  const int wlo = (w*16 + l15)*40 + 8*blk;

  fx4 acc[7];
  #pragma unroll
  for (int pf = 0; pf < 7; ++pf) acc[pf] = fzero();

  for (int cib = 0; cib < CIN/32; ++cib){
    __syncthreads();
    #pragma unroll
    for (int it = 0; it < 4; ++it){
      int q = it*256 + tid;
      if (q < 928){
        int col = q % 58; int cg8 = (q/58) & 3; int r = q / 232;
        int grow = r0 - 1 + r;
        int gcol = col - 1;
        bfr8 v = bzero();
        if (grow >= 0 && grow < 56 && gcol >= 0 && gcol < 56){
          #pragma unroll
          for (int k = 0; k < 8; ++k)
            v[k] = xin[(size_t)(b*CIN + cib*32 + cg8*8 + k)*3136 + grow*56 + gcol];
        }
        *(bfr8*)&xs[(r*58 + col)*40 + cg8*8] = v;
      }
    }
    #pragma unroll
    for (int it = 0; it < 9; ++it){
      int q = it*256 + tid;
      int jj = q & 3; int tap = (q >> 2) % 9; int co = q / 36;
      bfr8 wv = *(const bfr8*)&wt[(size_t)((cog*64 + co)*9 + tap)*CIN + cib*32 + jj*8];
      *(bfr8*)&wsh[(tap*64 + co)*40 + jj*8] = wv;
    }
    __syncthreads();
    #pragma unroll
    for (int tap = 0; tap < 9; ++tap){
      bfr8 af = *(const bfr8*)&wsh[tap*64*40 + wlo];
      const int toff = ((tap/3)*58 + (tap%3))*40;
      #pragma unroll
      for (int pf = 0; pf < 7; ++pf){
        bfr8 bf = *(const bfr8*)&xs[pixoff[pf] + toff];
        acc[pf] = MFMA16(af, bf, acc[pf]);
      }
    }
  }
  #pragma unroll
  for (int rr = 0; rr < 4; ++rr){
    int co = cog*64 + w*16 + 4*blk + rr;
    float al = alpha[co], bc = bconst[co];
    #pragma unroll
    for (int pf = 0; pf < 7; ++pf){
      float v = fmaxf(acc[pf][rr]*al + bc, 0.f);
      short sv = f2bf(v);
      int n = r0*56 + pf*16 + l15;
      yout[(size_t)(b*128 + co)*3136 + n] = sv;
      if (TSTORE) youtT[((size_t)(b*3136) + n)*128 + co] = sv;
    }
  }
}

// ---------------------------------------------------------------------------
// 1x1 conv: qt[b][n][co] = sum_ci wq[co][ci] * xT[b][n][ci]
// ---------------------------------------------------------------------------
__global__ __launch_bounds__(256, 4) void qproj_kernel(
    const short* __restrict__ xT, const short* __restrict__ wq,
    short* __restrict__ qt)
{
  const int tid = threadIdx.x, w = tid >> 6, lane = tid & 63;
  const int l15 = lane & 15, blk = lane >> 4;
  const int b = blockIdx.x / 196, n0 = (blockIdx.x % 196) * 16;

  fx4 acc[2];
  acc[0] = fzero(); acc[1] = fzero();

  #pragma unroll
  for (int ks = 0; ks < 4; ++ks){
    bfr8 af = *(const bfr8*)&xT[((size_t)(b*3136) + n0 + l15)*128 + ks*32 + 8*blk];
    #pragma unroll
    for (int i = 0; i < 2; ++i){
      bfr8 bf = *(const bfr8*)&wq[(size_t)((w*2 + i)*16 + l15)*128 + ks*32 + 8*blk];
      acc[i] = MFMA16(af, bf, acc[i]);
    }
  }
  #pragma unroll
  for (int i = 0; i < 2; ++i){
    #pragma unroll
    for (int rr = 0; rr < 4; ++rr){
      int n = n0 + 4*blk + rr;
      qt[((size_t)(b*3136) + n)*128 + (w*2 + i)*16 + l15] = f2bf(acc[i][rr]);
    }
  }
}

// ---------------------------------------------------------------------------
// FAST pass 1: QK GEMM. Stores S[b][n][m] bf16 (rounded) AND computes
// per-(m, ns, wave) online lse from the ROUNDED values (so a1 <= 1 exactly
// in attn4). s[m][n]: A=q2 rows m, B=q1 cols n.
// ---------------------------------------------------------------------------
__global__ __launch_bounds__(256, 3) void lse_kernel(
    const short* __restrict__ q1t, const short* __restrict__ q2t,
    short* __restrict__ Sbuf,
    float* __restrict__ pmax, float* __restrict__ psum)
{
  const int tid = threadIdx.x, w = tid >> 6, lane = tid & 63;
  const int l15 = lane & 15, blk = lane >> 4;
  const int bid = blockIdx.x;
  const int ns = bid & 3, mt = (bid >> 2) % 49, b = bid / 196;
  const int m0 = mt*64;

  bfr8 qa[4][4];
  #pragma unroll
  for (int mf = 0; mf < 4; ++mf)
    #pragma unroll
    for (int ks = 0; ks < 4; ++ks)
      qa[mf][ks] = *(const bfr8*)&q2t[((size_t)(b*3136) + m0 + mf*16 + l15)*128 + ks*32 + 8*blk];

  float vmax[4][4], vsum[4][4];
  #pragma unroll
  for (int mf = 0; mf < 4; ++mf)
    #pragma unroll
    for (int rr = 0; rr < 4; ++rr){ vmax[mf][rr] = -1e30f; vsum[mf][rr] = 0.f; }

  bfr8 qb[4], qbn[4];
  #pragma unroll
  for (int ks = 0; ks < 4; ++ks)
    qb[ks] = *(const bfr8*)&q1t[((size_t)(b*3136) + ns*784 + w*16 + l15)*128 + ks*32 + 8*blk];

  for (int c = w; c < 49; c += 4){
    const int cn = c + 4;
    if (cn < 49){
      #pragma unroll
      for (int ks = 0; ks < 4; ++ks)
        qbn[ks] = *(const bfr8*)&q1t[((size_t)(b*3136) + ns*784 + cn*16 + l15)*128 + ks*32 + 8*blk];
    }
    fx4 acc[4];
    #pragma unroll
    for (int mf = 0; mf < 4; ++mf) acc[mf] = fzero();
    #pragma unroll
    for (int ks = 0; ks < 4; ++ks)
      #pragma unroll
      for (int mf = 0; mf < 4; ++mf)
        acc[mf] = MFMA16(qa[mf][ks], qb[ks], acc[mf]);
    // store rounded S + online lse on rounded values
    const size_t srow = ((size_t)(b*3136) + ns*784 + c*16 + l15)*3136 + m0;
    #pragma unroll
    for (int mf = 0; mf < 4; ++mf){
      sh4 rv;
      #pragma unroll
      for (int rr = 0; rr < 4; ++rr) rv[rr] = f2bf(acc[mf][rr]);
      *(sh4*)&Sbuf[srow + mf*16 + 4*blk] = rv;
      #pragma unroll
      for (int rr = 0; rr < 4; ++rr){
        float s = bf2f(rv[rr]);
        float d = s - vmax[mf][rr];
        float e = __expf(-fabsf(d));
        bool up = d > 0.f;
        float mlt = up ? e : 1.f;
        float add = up ? 1.f : e;
        vsum[mf][rr] = vsum[mf][rr]*mlt + add;
        vmax[mf][rr] = fmaxf(vmax[mf][rr], s);
      }
    }
    #pragma unroll
    for (int ks = 0; ks < 4; ++ks) qb[ks] = qbn[ks];
  }
  #pragma unroll
  for (int d = 1; d < 16; d <<= 1){
    #pragma unroll
    for (int mf = 0; mf < 4; ++mf)
      #pragma unroll
      for (int rr = 0; rr < 4; ++rr){
        float om = __shfl_xor(vmax[mf][rr], d);
        float os = __shfl_xor(vsum[mf][rr], d);
        float M = fmaxf(vmax[mf][rr], om);
        vsum[mf][rr] = vsum[mf][rr]*__expf(vmax[mf][rr]-M) + os*__expf(om-M);
        vmax[mf][rr] = M;
      }
  }
  if (l15 == 0){
    const size_t base = ((size_t)(b*16 + ns*4 + w))*3136 + m0;
    #pragma unroll
    for (int mf = 0; mf < 4; ++mf)
      #pragma unroll
      for (int rr = 0; rr < 4; ++rr){
        pmax[base + mf*16 + 4*blk + rr] = vmax[mf][rr];
        psum[base + mf*16 + 4*blk + rr] = vsum[mf][rr];
      }
  }
}

// ---------------------------------------------------------------------------
__global__ void lse_merge_kernel(
    const float* __restrict__ pmax, const float* __restrict__ psum,
    float* __restrict__ Lm)
{
  int t = blockIdx.x*256 + threadIdx.x;
  if (t >= 12544) return;
  int b = t / 3136, m = t - b*3136;
  float M = -1e30f;
  #pragma unroll
  for (int r = 0; r < 16; ++r)
    M = fmaxf(M, pmax[((size_t)(b*16 + r))*3136 + m]);
  float S = 0.f;
  #pragma unroll
  for (int r = 0; r < 16; ++r){
    size_t i = ((size_t)(b*16 + r))*3136 + m;
    S += psum[i]*__expf(pmax[i] - M);
  }
  Lm[t] = M + __logf(S);
}

// ---------------------------------------------------------------------------
// FAST pass 2 v4: NO QK recompute — the S[b][n][m] row load IS the PV
// B-fragment. Per 32-m chunk: 1 S load + softmax (perm-pack) + 8 LDS reads +
// 8 MFMA; x2v tile double-buffered in swizzled LDS -> 1 barrier/chunk.
// Grid: 4b x 49nt x 7ms = 1372.
// ---------------------------------------------------------------------------
__global__ __launch_bounds__(256, 4) void attn4_kernel(
    const short* __restrict__ S, const short* __restrict__ x2v,
    const float* __restrict__ Lm,
    short* __restrict__ part, float* __restrict__ rpart)
{
  __shared__ short xshA[128*32];      // 8 KB [128c][32m], swizzled
  __shared__ short xshB[128*32];
  __shared__ float lmsh[448];
  const int tid = threadIdx.x, w = tid >> 6, lane = tid & 63;
  const int l15 = lane & 15, blk = lane >> 4;
  const int bid = blockIdx.x;
  const int ms = bid % 7, nt = (bid / 7) % 49, b = bid / 343;
  const int m0 = ms*448;
  const int n0w = nt*64 + w*16;
  const size_t srow = ((size_t)(b*3136) + n0w + l15)*3136 + m0 + 8*blk;

  if (tid < 112)
    ((float4*)lmsh)[tid] = ((const float4*)(Lm + b*3136 + m0))[tid];

  // x2v stage descriptors: u = tid + 256*j -> row (128), m-col (u&3)*8
  bfr8 stx[2];
  int sg[2], sl[2];
  #pragma unroll
  for (int j = 0; j < 2; ++j){
    int u = tid + 256*j;
    int row = u >> 2, mc = (u & 3)*16;     // mc = byte offset within row (64 B)
    sg[j] = (b*128 + row)*3136 + m0 + (u & 3)*8;
    sl[j] = (row*64 + mc) ^ ((row&7)<<4);
  }

  fx4 pacc[8];
  #pragma unroll
  for (int cf = 0; cf < 8; ++cf) pacc[cf] = fzero();
  float rsum = 0.f;

  // prologue: chunk0 staged + written, chunk1 staged, S depth-2 prefetch
  bfr8 svc = *(const bfr8*)&S[srow];
  bfr8 svn = *(const bfr8*)&S[srow + 32];
  #pragma unroll
  for (int j = 0; j < 2; ++j) stx[j] = *(const bfr8*)&x2v[sg[j]];
  #pragma unroll
  for (int j = 0; j < 2; ++j) *(bfr8*)((char*)xshA + sl[j]) = stx[j];
  #pragma unroll
  for (int j = 0; j < 2; ++j) stx[j] = *(const bfr8*)&x2v[sg[j] + 32];
  __syncthreads();                    // lmsh + xshA ready

  for (int c = 0; c < 14; ++c){
    short* xcur = (c & 1) ? xshB : xshA;
    short* xnxt = (c & 1) ? xshA : xshB;

    // softmax: p = exp(exp(s - Lm)) from the S row in registers
    fx4 l0 = *(const fx4*)&lmsh[c*32 + 8*blk];
    fx4 l1 = *(const fx4*)&lmsh[c*32 + 8*blk + 4];
    float p0 = __expf(__expf(bf2f(svc[0]) - l0[0]));
    float p1 = __expf(__expf(bf2f(svc[1]) - l0[1]));
    float p2 = __expf(__expf(bf2f(svc[2]) - l0[2]));
    float p3 = __expf(__expf(bf2f(svc[3]) - l0[3]));
    float p4 = __expf(__expf(bf2f(svc[4]) - l1[0]));
    float p5 = __expf(__expf(bf2f(svc[5]) - l1[1]));
    float p6 = __expf(__expf(bf2f(svc[6]) - l1[2]));
    float p7 = __expf(__expf(bf2f(svc[7]) - l1[3]));
    rsum += ((p0+p1)+(p2+p3)) + ((p4+p5)+(p6+p7));
    int4 pi;
    pi.x = (int)pk2(p0, p1); pi.y = (int)pk2(p2, p3);
    pi.z = (int)pk2(p4, p5); pi.w = (int)pk2(p6, p7);
    bfr8 pb = *(bfr8*)&pi;

    // PV: A = x2v rows (LDS, swizzled), B = P (regs), K = 32
    #pragma unroll
    for (int cf = 0; cf < 8; ++cf){
      const int row = cf*16 + l15;
      bfr8 av = *(const bfr8*)((const char*)xcur +
                  ((row*64 + 16*blk) ^ ((row&7)<<4)));
      pacc[cf] = MFMA16(av, pb, pacc[cf]);
    }

    if (c < 13){
      #pragma unroll
      for (int j = 0; j < 2; ++j) *(bfr8*)((char*)xnxt + sl[j]) = stx[j];
      svc = svn;
      if (c < 12){
        svn = *(const bfr8*)&S[srow + (size_t)(c+2)*32];
        #pragma unroll
        for (int j = 0; j < 2; ++j)
          stx[j] = *(const bfr8*)&x2v[sg[j] + (c+2)*32];
      }
    }
    __syncthreads();
  }

  rsum += __shfl_xor(rsum, 16);
  rsum += __shfl_xor(rsum, 32);
  if (lane < 16)
    rpart[((size_t)(ms*4 + b))*3136 + n0w + l15] = rsum;

  #pragma unroll
  for (int cf = 0; cf < 8; ++cf)
    #pragma unroll
    for (int rr = 0; rr < 4; ++rr){
      int cc = cf*16 + 4*blk + rr;
      part[(((size_t)(ms*4 + b))*128 + cc)*3136 + n0w + l15] = f2bf(pacc[cf][rr]);
    }
}

// ---------------------------------------------------------------------------
__global__ void rtot_kernel(const float* __restrict__ rpart,
                            float* __restrict__ rinv)
{
  int t = blockIdx.x*256 + threadIdx.x;
  if (t >= 12544) return;
  int b = t / 3136, n = t - b*3136;
  float s = 0.f;
  #pragma unroll
  for (int ms = 0; ms < 7; ++ms)
    s += rpart[((size_t)(ms*4 + b))*3136 + n];
  rinv[t] = 1.0f / s;
}

// ---------------------------------------------------------------------------
// attn combine: out0 = (sum_ms part)*rinv + x1   (part is bf16)
// ---------------------------------------------------------------------------
__global__ __launch_bounds__(256, 8) void attn_combine_kernel(
    const short* __restrict__ part, const float* __restrict__ rinv,
    const float* __restrict__ x1, float* __restrict__ out0)
{
  int t = blockIdx.x*256 + threadIdx.x;
  int n4 = t % 784; int rest = t / 784;
  int cc = rest & 127; int b = rest >> 7;
  float4 s = {0.f,0.f,0.f,0.f};
  #pragma unroll
  for (int ms = 0; ms < 7; ++ms){
    sh4 v = *(const sh4*)&part[((((size_t)(ms*4 + b))*128 + cc)*3136) + n4*4];
    s.x += bf2f(v[0]); s.y += bf2f(v[1]); s.z += bf2f(v[2]); s.w += bf2f(v[3]);
  }
  float4 rv = ((const float4*)rinv)[b*784 + n4];
  size_t xi = ((size_t)(b*128) + cc)*784 + n4;
  float4 xv = ((const float4*)x1)[xi];
  float4 o;
  o.x = s.x*rv.x + xv.x; o.y = s.y*rv.y + xv.y;
  o.z = s.z*rv.z + xv.z; o.w = s.w*rv.w + xv.w;
  ((float4*)out0)[xi] = o;
}

// ---------------------------------------------------------------------------
// FALLBACK PATH kernels (legacy layouts)
// ---------------------------------------------------------------------------
__global__ __launch_bounds__(256, 2) void colstats_kernel(
    const short* __restrict__ q1t, const short* __restrict__ q2t,
    float* __restrict__ Lm)
{
  __shared__ float smax[4][16];
  __shared__ float ssum[4][16];
  const int tid = threadIdx.x, w = tid >> 6, lane = tid & 63;
  const int l15 = lane & 15, blk = lane >> 4;
  const int b = blockIdx.x / 196, m0 = (blockIdx.x % 196) * 16;

  bfr8 bfr[4];
  #pragma unroll
  for (int ks = 0; ks < 4; ++ks)
    bfr[ks] = *(const bfr8*)&q2t[((size_t)(b*3136) + m0 + l15)*128 + ks*32 + 8*blk];

  float vmax = -1e30f, vsum = 0.f;

  for (int nc = w; nc < 196; nc += 4){
    fx4 acc = fzero();
    #pragma unroll
    for (int ks = 0; ks < 4; ++ks){
      bfr8 af = *(const bfr8*)&q1t[((size_t)(b*3136) + nc*16 + l15)*128 + ks*32 + 8*blk];
      acc = MFMA16(af, bfr[ks], acc);
    }
    float cm = fmaxf(fmaxf(acc[0], acc[1]), fmaxf(acc[2], acc[3]));
    float nm = fmaxf(vmax, cm);
    float cs = __expf(acc[0]-nm) + __expf(acc[1]-nm)
             + __expf(acc[2]-nm) + __expf(acc[3]-nm);
    vsum = vsum*__expf(vmax-nm) + cs;
    vmax = nm;
  }
  #pragma unroll
  for (int d = 16; d < 64; d <<= 1){
    float om = __shfl_xor(vmax, d);
    float os = __shfl_xor(vsum, d);
    float M = fmaxf(vmax, om);
    vsum = vsum*__expf(vmax - M) + os*__expf(om - M);
    vmax = M;
  }
  if (lane < 16){ smax[w][lane] = vmax; ssum[w][lane] = vsum; }
  __syncthreads();
  if (tid < 16){
    float M = fmaxf(fmaxf(smax[0][tid], smax[1][tid]), fmaxf(smax[2][tid], smax[3][tid]));
    float S = ssum[0][tid]*__expf(smax[0][tid]-M) + ssum[1][tid]*__expf(smax[1][tid]-M)
            + ssum[2][tid]*__expf(smax[2][tid]-M) + ssum[3][tid]*__expf(smax[3][tid]-M);
    Lm[b*3136 + m0 + tid] = M + __logf(S);
  }
}

__global__ __launch_bounds__(256, 2) void attn_kernel(
    const short* __restrict__ q1t, const short* __restrict__ q2t,
    const short* __restrict__ x2v, const float* __restrict__ Lm,
    const float* __restrict__ x1, float* __restrict__ out0)
{
  __shared__ float part[8][4][4][64];
  __shared__ short plds[4][16][72];
  __shared__ float rl[4][16];
  const int tid = threadIdx.x, w = tid >> 6, lane = tid & 63;
  const int l15 = lane & 15, blk = lane >> 4;
  const int b = blockIdx.x / 196, n0 = (blockIdx.x % 196) * 16;

  bfr8 qa[4];
  #pragma unroll
  for (int ks = 0; ks < 4; ++ks)
    qa[ks] = *(const bfr8*)&q1t[((size_t)(b*3136) + n0 + l15)*128 + ks*32 + 8*blk];

  fx4 pacc[8];
  #pragma unroll
  for (int cf = 0; cf < 8; ++cf) pacc[cf] = fzero();
  float rsum[4] = {0.f, 0.f, 0.f, 0.f};

  for (int s = w; s < 49; s += 4){
    const int m0m = s*64;
    fx4 s4[4];
    #pragma unroll
    for (int mf = 0; mf < 4; ++mf) s4[mf] = fzero();
    #pragma unroll
    for (int ks = 0; ks < 4; ++ks){
      #pragma unroll
      for (int mf = 0; mf < 4; ++mf){
        bfr8 bq = *(const bfr8*)&q2t[((size_t)(b*3136) + m0m + mf*16 + l15)*128 + ks*32 + 8*blk];
        s4[mf] = MFMA16(qa[ks], bq, s4[mf]);
      }
    }
    #pragma unroll
    for (int mf = 0; mf < 4; ++mf){
      float Lv = Lm[b*3136 + m0m + mf*16 + l15];
      #pragma unroll
      for (int rr = 0; rr < 4; ++rr){
        float a1 = __expf(s4[mf][rr] - Lv);
        float p  = __expf(a1);
        rsum[rr] += p;
        plds[w][4*blk + rr][mf*16 + l15] = f2bf(p);
      }
    }
    #pragma unroll
    for (int ks2 = 0; ks2 < 2; ++ks2){
      bfr8 pb = *(const bfr8*)&plds[w][l15][ks2*32 + 8*blk];
      #pragma unroll
      for (int cf = 0; cf < 8; ++cf){
        bfr8 av = *(const bfr8*)&x2v[((size_t)(b*128) + cf*16 + l15)*3136 + m0m + ks2*32 + 8*blk];
        pacc[cf] = MFMA16(av, pb, pacc[cf]);
      }
    }
  }
  #pragma unroll
  for (int d = 1; d < 16; d <<= 1){
    #pragma unroll
    for (int rr = 0; rr < 4; ++rr) rsum[rr] += __shfl_xor(rsum[rr], d);
  }
  if (l15 == 0){
    #pragma unroll
    for (int rr = 0; rr < 4; ++rr) rl[w][4*blk + rr] = rsum[rr];
  }
  #pragma unroll
  for (int cf = 0; cf < 8; ++cf)
    #pragma unroll
    for (int rr = 0; rr < 4; ++rr)
      part[cf][rr][w][lane] = pacc[cf][rr];
  __syncthreads();

  float rtot = rl[0][l15] + rl[1][l15] + rl[2][l15] + rl[3][l15];
  float rinv = 1.0f / rtot;
  const int n = n0 + l15;
  #pragma unroll
  for (int i = 0; i < 2; ++i){
    int cf = 2*w + i;
    #pragma unroll
    for (int rr = 0; rr < 4; ++rr){
      float v = part[cf][rr][0][lane] + part[cf][rr][1][lane]
              + part[cf][rr][2][lane] + part[cf][rr][3][lane];
      int c = cf*16 + 4*blk + rr;
      size_t idx = (size_t)(b*128 + c)*3136 + n;
      out0[idx] = v*rinv + x1[idx];
    }
  }
}

// ---------------------------------------------------------------------------
extern "C" void kernel_launch(void* const* d_in, const int* in_sizes, int n_in,
                              void* d_out, int out_size, void* d_ws, size_t ws_size,
                              hipStream_t stream)
{
  (void)in_sizes; (void)n_in; (void)out_size;
  const float* x1     = (const float*)d_in[0];
  const float* x2     = (const float*)d_in[1];
  const float* wsw    = (const float*)d_in[2];
  const float* bs     = (const float*)d_in[3];
  const float* sg     = (const float*)d_in[4];
  const float* sbeta  = (const float*)d_in[5];
  const float* smean  = (const float*)d_in[6];
  const float* svar   = (const float*)d_in[7];
  const float* wq1    = (const float*)d_in[8];
  const float* wq2    = (const float*)d_in[9];
  // d_in[10..15]: v1 conv_block params -> dead code, unused
  const float* v2w    = (const float*)d_in[16];
  const float* v2bias = (const float*)d_in[17];
  const float* v2g    = (const float*)d_in[18];
  const float* v2beta = (const float*)d_in[19];
  const float* v2mean = (const float*)d_in[20];
  const float* v2var  = (const float*)d_in[21];

  char* ws = (char*)d_ws;
  auto al = [](size_t x){ return (x + 255) & ~(size_t)255; };

  const size_t sz_nc    = al((size_t)1605632*2);          // [4][3136][128] bf16
  const size_t sz_x2T   = al((size_t)6422528*2);          // [4][3136][512] bf16
  const size_t sz_S     = al((size_t)4*3136*3136*2);      // 78.7 MB
  const size_t sz_Lm    = al((size_t)12544*4);
  const size_t sz_lsep  = al((size_t)16*12544*4);
  const size_t sz_rp    = al((size_t)28*12544*4);
  const size_t sz_cst   = al((size_t)768*4);
  const size_t sz_part  = al((size_t)7*1605632*2);        // bf16 attn partials
  const size_t sz_pbuf  = al((size_t)4*1605632*4);        // conv f32 partials
  const size_t sz_wsbf  = al((size_t)589824*2);
  const size_t sz_wv2   = al((size_t)147456*2);
  const size_t sz_wq    = al((size_t)16384*2);

  // fast layout; big region shared: x2T (dead after conv512) overlaid by S
  size_t off = 0;
  const size_t o_x2v = off;  off += sz_nc;      // [c][n]
  const size_t o_q1t = off;  off += sz_nc;
  const size_t o_q2t = off;  off += sz_nc;
  const size_t o_x1T = off;  off += sz_nc;      // [n][c]
  const size_t o_x2s = off;  off += sz_nc;      // [n][c]
  const size_t o_v2t = off;  off += sz_nc;      // [n][c]
  const size_t o_Lm  = off;  off += sz_Lm;
  const size_t o_pmx = off;  off += sz_lsep;
  const size_t o_psm = off;  off += sz_lsep;
  const size_t o_rp  = off;  off += sz_rp;
  const size_t o_ri  = off;  off += sz_Lm;
  const size_t o_cst = off;  off += sz_cst;
  const size_t o_wsb = off;  off += sz_wsbf;
  const size_t o_wva = off;  off += sz_wv2;
  const size_t o_wvb = off;  off += sz_wv2;
  const size_t o_wq1 = off;  off += sz_wq;
  const size_t o_wq2 = off;  off += sz_wq;
  const size_t o_prt = off;  off += (sz_part > sz_pbuf ? sz_part : sz_pbuf);
  const size_t o_big = off;  off += (sz_x2T > sz_S ? sz_x2T : sz_S);
  const size_t fast_need = off;
  const bool fast = (ws_size >= fast_need);

  float* out0 = (float*)d_out;
  float* out1 = out0 + 1605632;

  if (fast){
    short* x2v  = (short*)(ws + o_x2v);
    short* q1t  = (short*)(ws + o_q1t);
    short* q2t  = (short*)(ws + o_q2t);
    short* x1T  = (short*)(ws + o_x1T);
    short* x2s  = (short*)(ws + o_x2s);
    short* v2t  = (short*)(ws + o_v2t);
    float* Lm   = (float*)(ws + o_Lm);
    float* pmax = (float*)(ws + o_pmx);
    float* psum = (float*)(ws + o_psm);
    float* rpart= (float*)(ws + o_rp);
    float* rinv = (float*)(ws + o_ri);
    float* consts = (float*)(ws + o_cst);
    short* wsbf = (short*)(ws + o_wsb);
    short* wv2a = (short*)(ws + o_wva);
    short* wv2b = (short*)(ws + o_wvb);
    short* wq1b = (short*)(ws + o_wq1);
    short* wq2b = (short*)(ws + o_wq2);
    short* part = (short*)(ws + o_prt);
    float* pbuf = (float*)(ws + o_prt);
    short* x2T  = (short*)(ws + o_big);
    short* Sbuf = (short*)(ws + o_big);

    prep_kernel<<<2048, 256, 0, stream>>>(x1, x2, wsw, bs, sg, sbeta, smean, svar,
        wq1, wq2, v2w, v2bias, v2g, v2beta, v2mean, v2var,
        nullptr, nullptr, wsbf, wv2a, wv2b, wq1b, wq2b, consts, out1, 0);
    transpose_cn_kernel<512, true ><<<3136, 256, 0, stream>>>(x2, x2T, out1);
    transpose_cn_kernel<128, false><<<784, 256, 0, stream>>>(x1, x1T, nullptr);

    conv3x3_split_kernel<512, 4><<<dim3(224,4), 256, 0, stream>>>(x2T, wsbf, pbuf);
    conv_combine_kernel<4, 1><<<392, 256, 0, stream>>>(pbuf, consts,       consts + 128, x2s);
    qproj_kernel<<<784, 256, 0, stream>>>(x1T, wq1b, q1t);
    qproj_kernel<<<784, 256, 0, stream>>>(x2s, wq2b, q2t);
    conv3x3_split_kernel<128, 2><<<dim3(224,2), 256, 0, stream>>>(x2s, wv2a, pbuf);
    conv_combine_kernel<2, 1><<<392, 256, 0, stream>>>(pbuf, consts + 256, consts + 384, v2t);
    conv3x3_split_kernel<128, 2><<<dim3(224,2), 256, 0, stream>>>(v2t, wv2b, pbuf);
    conv_combine_kernel<2, 0><<<392, 256, 0, stream>>>(pbuf, consts + 512, consts + 640, x2v);

    lse_kernel<<<784, 256, 0, stream>>>(q1t, q2t, Sbuf, pmax, psum);
    lse_merge_kernel<<<49, 256, 0, stream>>>(pmax, psum, Lm);
    attn4_kernel<<<1372, 256, 0, stream>>>(Sbuf, x2v, Lm, part, rpart);
    rtot_kernel<<<49, 256, 0, stream>>>(rpart, rinv);
    attn_combine_kernel<<<1568, 256, 0, stream>>>(part, rinv, x1, out0);
  } else {
    size_t o = 0;
    auto bump = [&](size_t bytes)->char*{ char* p = ws + o; o += al(bytes); return p; };
    short* x2bf   = (short*)bump((size_t)6422528*2);
    short* x1T    = (short*)bump((size_t)1605632*2);
    short* wsbf   = (short*)bump((size_t)589824*2);
    short* wv2a   = (short*)bump((size_t)147456*2);
    short* wv2b   = (short*)bump((size_t)147456*2);
    short* wq1b   = (short*)bump((size_t)16384*2);
    short* wq2b   = (short*)bump((size_t)16384*2);
    float* consts = (float*)bump((size_t)768*4);
    short* x2s    = (short*)bump((size_t)1605632*2);
    short* x2sT   = (short*)bump((size_t)1605632*2);
    short* q1t    = (short*)bump((size_t)1605632*2);
    short* q2t    = (short*)bump((size_t)1605632*2);
    short* v2t    = (short*)bump((size_t)1605632*2);
    short* x2v    = (short*)bump((size_t)1605632*2);
    float* Lm     = (float*)bump((size_t)12544*4);

    prep_kernel<<<2048, 256, 0, stream>>>(x1, x2, wsw, bs, sg, sbeta, smean, svar,
        wq1, wq2, v2w, v2bias, v2g, v2beta, v2mean, v2var,
        x2bf, x1T, wsbf, wv2a, wv2b, wq1b, wq2b, consts, out1, 1);
    conv3x3_kernel<512, true ><<<224, 256, 0, stream>>>(x2bf, wsbf, consts, consts + 128, x2s, x2sT);
    qproj_kernel<<<784, 256, 0, stream>>>(x1T,  wq1b, q1t);
    qproj_kernel<<<784, 256, 0, stream>>>(x2sT, wq2b, q2t);
    conv3x3_kernel<128, false><<<224, 256, 0, stream>>>(x2s, wv2a, consts + 256, consts + 384, v2t, nullptr);
    conv3x3_kernel<128, false><<<224, 256, 0, stream>>>(v2t, wv2b, consts + 512, consts + 640, x2v, nullptr);
    colstats_kernel<<<784, 256, 0, stream>>>(q1t, q2t, Lm);
    attn_kernel<<<784, 256, 0, stream>>>(q1t, q2t, x2v, Lm, x1, out0);
  }
}